// Round 1
// baseline (4599.847 us; speedup 1.0000x reference)
//
#include <hip/hip_runtime.h>
#include <math.h>

#define NPTS 1024
#define BATCH 16
#define KNN 20

// ---------------------------------------------------------------------------
// knn top-k: one block per (64 queries, batch). Tiled 64x64 distance subtiles
// via LDS, 4x4 register micro-tile, then per-query insertion into a sorted
// top-20 list kept in LDS. Ranking value: 2*inner - sq[m] (query-constant
// -sq[n] dropped; ordering identical to reference neg_dist).
// ---------------------------------------------------------------------------
template<int C>
__global__ __launch_bounds__(256) void knn_kernel(const float* __restrict__ X,
                                                  long batchStride,
                                                  int* __restrict__ idxOut) {
  constexpr int CT = (C < 64) ? C : 64;
  __shared__ float qbuf[CT][64];
  __shared__ float pbuf[CT][64];
  __shared__ float Dbuf[64][68];     // [point][query], padded for fp4 stores
  __shared__ float sqall[NPTS];
  __shared__ float topv[64][KNN];
  __shared__ int   topi[64][KNN];

  const int b   = blockIdx.y;
  const int q0  = blockIdx.x * 64;
  const int tid = threadIdx.x;
  const int ty  = tid >> 4, tx = tid & 15;
  const float* Xb = X + (long)b * batchStride;

  // per-point squared norms (coalesced across lanes per channel)
  for (int m = tid; m < NPTS; m += 256) {
    float s = 0.f;
    for (int c = 0; c < C; ++c) { float v = Xb[(long)c * NPTS + m]; s += v * v; }
    sqall[m] = s;
  }
  if (tid < 64) {
    for (int j = 0; j < KNN; ++j) { topv[tid][j] = -INFINITY; topi[tid][j] = 0; }
  }
  __syncthreads();

  for (int pc = 0; pc < NPTS; pc += 64) {
    float acc[4][4] = {};
    for (int cc = 0; cc < C; cc += CT) {
      __syncthreads();  // protect bufs vs previous compute/selection
      for (int t = tid; t < 64 * CT; t += 256) {
        int c = t >> 6, m = t & 63;
        qbuf[c][m] = Xb[(long)(cc + c) * NPTS + q0 + m];
        pbuf[c][m] = Xb[(long)(cc + c) * NPTS + pc + m];
      }
      __syncthreads();
      #pragma unroll
      for (int c = 0; c < CT; ++c) {
        const float4 qv = *(const float4*)&qbuf[c][ty * 4];
        const float4 pv = *(const float4*)&pbuf[c][tx * 4];
        acc[0][0] += qv.x * pv.x; acc[0][1] += qv.x * pv.y; acc[0][2] += qv.x * pv.z; acc[0][3] += qv.x * pv.w;
        acc[1][0] += qv.y * pv.x; acc[1][1] += qv.y * pv.y; acc[1][2] += qv.y * pv.z; acc[1][3] += qv.y * pv.w;
        acc[2][0] += qv.z * pv.x; acc[2][1] += qv.z * pv.y; acc[2][2] += qv.z * pv.z; acc[2][3] += qv.z * pv.w;
        acc[3][0] += qv.w * pv.x; acc[3][1] += qv.w * pv.y; acc[3][2] += qv.w * pv.z; acc[3][3] += qv.w * pv.w;
      }
    }
    // D[p][q] = 2*inner - sq[p]
    #pragma unroll
    for (int j = 0; j < 4; ++j) {
      const int p = pc + tx * 4 + j;
      const float sq = sqall[p];
      float4 dv;
      dv.x = 2.f * acc[0][j] - sq;
      dv.y = 2.f * acc[1][j] - sq;
      dv.z = 2.f * acc[2][j] - sq;
      dv.w = 2.f * acc[3][j] - sq;
      *(float4*)&Dbuf[tx * 4 + j][ty * 4] = dv;
    }
    __syncthreads();
    // selection by query-owner threads (wave 0); strict > keeps lower index on ties
    if (tid < 64) {
      float vmin = topv[tid][KNN - 1];
      for (int m = 0; m < 64; ++m) {
        float v = Dbuf[m][tid];
        if (v > vmin) {
          int pos = KNN - 1;
          while (pos > 0 && topv[tid][pos - 1] < v) {
            topv[tid][pos] = topv[tid][pos - 1];
            topi[tid][pos] = topi[tid][pos - 1];
            --pos;
          }
          topv[tid][pos] = v;
          topi[tid][pos] = pc + m;
          vmin = topv[tid][KNN - 1];
        }
      }
    }
  }
  __syncthreads();
  if (tid < 64) {
    int* op = idxOut + ((long)(b * NPTS + q0 + tid)) * KNN;
    for (int j = 0; j < KNN; ++j) op[j] = topi[tid][j];
  }
}

// ---------------------------------------------------------------------------
// gather + sum over k neighbors: agg[b,c,n] = sum_j X[b,c,idx[b,n,j]]
// ---------------------------------------------------------------------------
__global__ __launch_bounds__(256) void gather_sum_kernel(const float* __restrict__ X,
    long batchStride, int C, const int* __restrict__ idx, float* __restrict__ agg) {
  __shared__ int sidx[256][KNN + 1];
  const int b   = blockIdx.y;
  const int n0  = blockIdx.x * 256;
  const int tid = threadIdx.x;
  const int* ib = idx + ((long)(b * NPTS + n0)) * KNN;
  for (int t = tid; t < 256 * KNN; t += 256) {
    sidx[t / KNN][t % KNN] = ib[t];
  }
  __syncthreads();
  const float* Xb = X + (long)b * batchStride;
  float* ab = agg + (long)b * C * NPTS;
  for (int c = 0; c < C; ++c) {
    const float* row = Xb + (long)c * NPTS;
    float s = 0.f;
    #pragma unroll
    for (int j = 0; j < KNN; ++j) s += row[sidx[tid][j]];
    ab[(long)c * NPTS + n0 + tid] = s;
  }
}

// ---------------------------------------------------------------------------
// 1x1 conv as per-batch GEMM: Y[b,o,n] = sum_c W[o,c] * Xin[b,c,n]
// 64(o) x 64(n) tile, K-chunks of 32, 4x4 micro-tile, float4 LDS reads.
// ---------------------------------------------------------------------------
__global__ __launch_bounds__(256) void conv_kernel(const float* __restrict__ Xin, long inBatchStride,
    const float* __restrict__ W, int C, int O,
    float* __restrict__ Yout, long outBatchStride, int outChanOffset) {
  __shared__ float Wt[32][68];   // [k][o]
  __shared__ float Xt[32][68];   // [k][n]
  const int b   = blockIdx.z;
  const int o0  = blockIdx.y * 64;
  const int n0  = blockIdx.x * 64;
  const int tid = threadIdx.x;
  const int ty  = tid >> 4, tx = tid & 15;
  const float* Xb = Xin + (long)b * inBatchStride;
  float acc[4][4] = {};
  for (int cc = 0; cc < C; cc += 32) {
    const int cw = min(32, C - cc);
    __syncthreads();
    for (int t = tid; t < 64 * 32; t += 256) {
      int oo = t >> 5, kk = t & 31;
      Wt[kk][oo] = (kk < cw) ? W[(long)(o0 + oo) * C + cc + kk] : 0.f;
    }
    for (int t = tid; t < 32 * 64; t += 256) {
      int kk = t >> 6, nn = t & 63;
      Xt[kk][nn] = (kk < cw) ? Xb[(long)(cc + kk) * NPTS + n0 + nn] : 0.f;
    }
    __syncthreads();
    #pragma unroll
    for (int kk = 0; kk < 32; ++kk) {
      const float4 wv = *(const float4*)&Wt[kk][ty * 4];
      const float4 xv = *(const float4*)&Xt[kk][tx * 4];
      acc[0][0] += wv.x * xv.x; acc[0][1] += wv.x * xv.y; acc[0][2] += wv.x * xv.z; acc[0][3] += wv.x * xv.w;
      acc[1][0] += wv.y * xv.x; acc[1][1] += wv.y * xv.y; acc[1][2] += wv.y * xv.z; acc[1][3] += wv.y * xv.w;
      acc[2][0] += wv.z * xv.x; acc[2][1] += wv.z * xv.y; acc[2][2] += wv.z * xv.z; acc[2][3] += wv.z * xv.w;
      acc[3][0] += wv.w * xv.x; acc[3][1] += wv.w * xv.y; acc[3][2] += wv.w * xv.z; acc[3][3] += wv.w * xv.w;
    }
  }
  #pragma unroll
  for (int i = 0; i < 4; ++i) {
    float4 v = make_float4(acc[i][0], acc[i][1], acc[i][2], acc[i][3]);
    *(float4*)&Yout[(long)b * outBatchStride + (long)(outChanOffset + o0 + ty * 4 + i) * NPTS + n0 + tx * 4] = v;
  }
}

// ---------------------------------------------------------------------------
// BN training stats over (batch, N) per channel
// ---------------------------------------------------------------------------
__global__ __launch_bounds__(256) void bn_stats_kernel(const float* __restrict__ Y, long batchStride,
    int chanOffset, float* __restrict__ meanOut, float* __restrict__ rstdOut) {
  const int o   = blockIdx.x;
  const int tid = threadIdx.x;
  const float* base = Y + (long)(chanOffset + o) * NPTS;
  float s = 0.f, s2 = 0.f;
  for (int b = 0; b < BATCH; ++b) {
    const float* p = base + (long)b * batchStride;
    for (int t = tid; t < NPTS; t += 256) { float v = p[t]; s += v; s2 += v * v; }
  }
  for (int off = 32; off > 0; off >>= 1) { s += __shfl_down(s, off); s2 += __shfl_down(s2, off); }
  __shared__ float r1[4], r2[4];
  const int wid = tid >> 6;
  if ((tid & 63) == 0) { r1[wid] = s; r2[wid] = s2; }
  __syncthreads();
  if (tid == 0) {
    s  = r1[0] + r1[1] + r1[2] + r1[3];
    s2 = r2[0] + r2[1] + r2[2] + r2[3];
    float m   = s * (1.f / 16384.f);
    float var = s2 * (1.f / 16384.f) - m * m;
    meanOut[o] = m;
    rstdOut[o] = rsqrtf(var + 1e-5f);
  }
}

// ---------------------------------------------------------------------------
// BN normalize + LeakyReLU, in place
// ---------------------------------------------------------------------------
__global__ __launch_bounds__(256) void bn_apply_kernel(float* __restrict__ Y, long batchStride, int chanOffset,
    const float* __restrict__ meanB, const float* __restrict__ rstdB,
    const float* __restrict__ g, const float* __restrict__ beta) {
  const int n = blockIdx.x * 256 + threadIdx.x;
  const int o = blockIdx.y;
  const int b = blockIdx.z;
  float* p = Y + (long)b * batchStride + (long)(chanOffset + o) * NPTS;
  const float sc = rstdB[o] * g[o];
  float v = (p[n] - meanB[o]) * sc + beta[o];
  p[n] = (v > 0.f) ? v : 0.2f * v;
}

// ---------------------------------------------------------------------------
// fused BN + LeakyReLU + max/mean pooling over N for layer 5
// z[b, o] = max_n h, z[b, 1024+o] = mean_n h
// ---------------------------------------------------------------------------
__global__ __launch_bounds__(256) void bn_pool_kernel(const float* __restrict__ H,
    const float* __restrict__ meanB, const float* __restrict__ rstdB,
    const float* __restrict__ g, const float* __restrict__ beta,
    float* __restrict__ Z) {
  const int o   = blockIdx.x;
  const int b   = blockIdx.y;
  const int tid = threadIdx.x;
  const float* p = H + (long)b * (1024L * NPTS) + (long)o * NPTS;
  const float sc = rstdB[o] * g[o], mu = meanB[o], bb = beta[o];
  float mx = -INFINITY, s = 0.f;
  for (int t = tid; t < NPTS; t += 256) {
    float v = (p[t] - mu) * sc + bb;
    v = (v > 0.f) ? v : 0.2f * v;
    mx = fmaxf(mx, v);
    s += v;
  }
  for (int off = 32; off > 0; off >>= 1) { mx = fmaxf(mx, __shfl_down(mx, off)); s += __shfl_down(s, off); }
  __shared__ float rm[4], rs[4];
  const int wid = tid >> 6;
  if ((tid & 63) == 0) { rm[wid] = mx; rs[wid] = s; }
  __syncthreads();
  if (tid == 0) {
    mx = fmaxf(fmaxf(rm[0], rm[1]), fmaxf(rm[2], rm[3]));
    s  = rs[0] + rs[1] + rs[2] + rs[3];
    Z[(long)b * 2048 + o]        = mx;
    Z[(long)b * 2048 + 1024 + o] = s * (1.f / 1024.f);
  }
}

// ---------------------------------------------------------------------------
// small FC: out[b,o] = sum_c in[b,c]*W[o,c] (+bias)
// ---------------------------------------------------------------------------
__global__ void fc_kernel(const float* __restrict__ in, const float* __restrict__ Wm,
    const float* __restrict__ bias, float* __restrict__ out, int Cin, int Oout) {
  const int idx = blockIdx.x * 256 + threadIdx.x;
  if (idx >= BATCH * Oout) return;
  const int b = idx / Oout, o = idx - b * Oout;
  const float* ip = in + (long)b * Cin;
  const float* wp = Wm + (long)o * Cin;
  float s = bias ? bias[o] : 0.f;
  for (int c = 0; c < Cin; ++c) s += ip[c] * wp[c];
  out[idx] = s;
}

// ---------------------------------------------------------------------------
// BN over batch axis (16 samples) + LeakyReLU, in place
// ---------------------------------------------------------------------------
__global__ void bn_small_kernel(float* __restrict__ buf, const float* __restrict__ g,
    const float* __restrict__ beta, int O) {
  const int o = blockIdx.x * 256 + threadIdx.x;
  if (o >= O) return;
  float s = 0.f, s2 = 0.f;
  for (int b = 0; b < BATCH; ++b) { float v = buf[b * O + o]; s += v; s2 += v * v; }
  const float m   = s * (1.f / 16.f);
  const float var = s2 * (1.f / 16.f) - m * m;
  const float sc  = rsqrtf(var + 1e-5f) * g[o];
  const float bb  = beta[o];
  for (int b = 0; b < BATCH; ++b) {
    float v = (buf[b * O + o] - m) * sc + bb;
    buf[b * O + o] = (v > 0.f) ? v : 0.2f * v;
  }
}

extern "C" void kernel_launch(void* const* d_in, const int* in_sizes, int n_in,
                              void* d_out, int out_size, void* d_ws, size_t ws_size,
                              hipStream_t stream) {
  const float* x   = (const float*)d_in[0];
  const float* W1  = (const float*)d_in[1];
  const float* g1  = (const float*)d_in[2];
  const float* b1  = (const float*)d_in[3];
  const float* W2  = (const float*)d_in[4];
  const float* g2  = (const float*)d_in[5];
  const float* b2  = (const float*)d_in[6];
  const float* W3  = (const float*)d_in[7];
  const float* g3  = (const float*)d_in[8];
  const float* b3  = (const float*)d_in[9];
  const float* W4  = (const float*)d_in[10];
  const float* g4  = (const float*)d_in[11];
  const float* b4  = (const float*)d_in[12];
  const float* W5  = (const float*)d_in[13];
  const float* g5  = (const float*)d_in[14];
  const float* b5  = (const float*)d_in[15];
  const float* l1W = (const float*)d_in[16];
  const float* g6  = (const float*)d_in[17];
  const float* b6  = (const float*)d_in[18];
  const float* l2W = (const float*)d_in[19];
  const float* l2b = (const float*)d_in[20];
  const float* g7  = (const float*)d_in[21];
  const float* b7  = (const float*)d_in[22];
  const float* l3W = (const float*)d_in[23];
  const float* l3b = (const float*)d_in[24];

  float* ws   = (float*)d_ws;
  float* Xcat = ws;                      // (B,512,N)  8,388,608 f
  float* H    = Xcat + 8388608;          // (B,1024,N) 16,777,216 f
  float* AGG  = H + 16777216;            // (B,<=128,N) 2,097,152 f
  int*   IDX  = (int*)(AGG + 2097152);   // (B,N,20)   327,680 i
  float* MEAN = (float*)(IDX + 327680);  // 1024
  float* RSTD = MEAN + 1024;             // 1024
  float* Z    = RSTD + 1024;             // (B,2048)
  float* Z1   = Z + 32768;               // (B,512)
  float* Z2   = Z1 + 8192;               // (B,256)

  const long XS = 512L * 1024;   // Xcat batch stride
  const long HS = 1024L * 1024;  // H batch stride

  // ---- edge block 1: x (C=3) -> Xcat ch [0,64) ----
  knn_kernel<3><<<dim3(16, 16), 256, 0, stream>>>(x, 3L * 1024, IDX);
  gather_sum_kernel<<<dim3(4, 16), 256, 0, stream>>>(x, 3L * 1024, 3, IDX, AGG);
  conv_kernel<<<dim3(16, 1, 16), 256, 0, stream>>>(AGG, 3L * 1024, W1, 3, 64, Xcat, XS, 0);
  bn_stats_kernel<<<64, 256, 0, stream>>>(Xcat, XS, 0, MEAN, RSTD);
  bn_apply_kernel<<<dim3(4, 64, 16), 256, 0, stream>>>(Xcat, XS, 0, MEAN, RSTD, g1, b1);

  // ---- edge block 2: ch[0,64) C=64 -> ch [64,128) ----
  knn_kernel<64><<<dim3(16, 16), 256, 0, stream>>>(Xcat, XS, IDX);
  gather_sum_kernel<<<dim3(4, 16), 256, 0, stream>>>(Xcat, XS, 64, IDX, AGG);
  conv_kernel<<<dim3(16, 1, 16), 256, 0, stream>>>(AGG, 64L * 1024, W2, 64, 64, Xcat, XS, 64);
  bn_stats_kernel<<<64, 256, 0, stream>>>(Xcat, XS, 64, MEAN, RSTD);
  bn_apply_kernel<<<dim3(4, 64, 16), 256, 0, stream>>>(Xcat, XS, 64, MEAN, RSTD, g2, b2);

  // ---- edge block 3: ch[64,128) C=64 -> ch [128,256) O=128 ----
  knn_kernel<64><<<dim3(16, 16), 256, 0, stream>>>(Xcat + 64L * 1024, XS, IDX);
  gather_sum_kernel<<<dim3(4, 16), 256, 0, stream>>>(Xcat + 64L * 1024, XS, 64, IDX, AGG);
  conv_kernel<<<dim3(16, 2, 16), 256, 0, stream>>>(AGG, 64L * 1024, W3, 64, 128, Xcat, XS, 128);
  bn_stats_kernel<<<128, 256, 0, stream>>>(Xcat, XS, 128, MEAN, RSTD);
  bn_apply_kernel<<<dim3(4, 128, 16), 256, 0, stream>>>(Xcat, XS, 128, MEAN, RSTD, g3, b3);

  // ---- edge block 4: ch[128,256) C=128 -> ch [256,512) O=256 ----
  knn_kernel<128><<<dim3(16, 16), 256, 0, stream>>>(Xcat + 128L * 1024, XS, IDX);
  gather_sum_kernel<<<dim3(4, 16), 256, 0, stream>>>(Xcat + 128L * 1024, XS, 128, IDX, AGG);
  conv_kernel<<<dim3(16, 4, 16), 256, 0, stream>>>(AGG, 128L * 1024, W4, 128, 256, Xcat, XS, 256);
  bn_stats_kernel<<<256, 256, 0, stream>>>(Xcat, XS, 256, MEAN, RSTD);
  bn_apply_kernel<<<dim3(4, 256, 16), 256, 0, stream>>>(Xcat, XS, 256, MEAN, RSTD, g4, b4);

  // ---- layer 5: conv 512->1024 over concat, BN stats, fused norm+pool ----
  conv_kernel<<<dim3(16, 16, 16), 256, 0, stream>>>(Xcat, XS, W5, 512, 1024, H, HS, 0);
  bn_stats_kernel<<<1024, 256, 0, stream>>>(H, HS, 0, MEAN, RSTD);
  bn_pool_kernel<<<dim3(1024, 16), 256, 0, stream>>>(H, MEAN, RSTD, g5, b5, Z);

  // ---- MLP head ----
  fc_kernel<<<32, 256, 0, stream>>>(Z, l1W, nullptr, Z1, 2048, 512);
  bn_small_kernel<<<2, 256, 0, stream>>>(Z1, g6, b6, 512);
  fc_kernel<<<16, 256, 0, stream>>>(Z1, l2W, l2b, Z2, 512, 256);
  bn_small_kernel<<<1, 256, 0, stream>>>(Z2, g7, b7, 256);
  fc_kernel<<<3, 256, 0, stream>>>(Z2, l3W, l3b, (float*)d_out, 256, 40);
}

// Round 2
// 2163.196 us; speedup vs baseline: 2.1264x; 2.1264x over previous
//
#include <hip/hip_runtime.h>
#include <math.h>

#define NPTS 1024
#define BATCH 16
#define KNN 20

// ---------------------------------------------------------------------------
// knn top-k v2: one block per (64 queries, batch). 64x64 distance subtiles via
// LDS GEMM (4x4 register micro-tile). Selection: 4 threads per query (sub =
// tid>>6 scans rows [sub*16, sub*16+16) of each tile), top-20 kept in
// REGISTERS via predicated carry-insert (no divergent while, no LDS top-k).
// Final 4-way merge with (value desc, index asc) lexicographic compare
// reproduces lax.top_k boundary tie-break. Ranking value: 2*inner - sq[m].
// ---------------------------------------------------------------------------
template<int C>
__global__ __launch_bounds__(256) void knn_kernel(const float* __restrict__ X,
                                                  long batchStride,
                                                  int* __restrict__ idxOut) {
  constexpr int CT = (C < 64) ? C : 64;
  __shared__ float sqall[NPTS];        //  4 KB
  __shared__ float Dbuf[64][68];       // 17.4 KB [point][query]
  __shared__ float region3[10240];     // 40 KB: qbuf/pbuf during compute, merge lists after

  float* qbuf = region3;               // [CT][64]
  float* pbuf = region3 + CT * 64;     // [CT][64]

  const int b   = blockIdx.y;
  const int q0  = blockIdx.x * 64;
  const int tid = threadIdx.x;
  const int ty  = tid >> 4, tx = tid & 15;
  const int q   = tid & 63;            // query owned for selection
  const int sub = tid >> 6;            // strip within tile (== wave id)
  const float* Xb = X + (long)b * batchStride;

  // per-point squared norms
  for (int m = tid; m < NPTS; m += 256) {
    float s = 0.f;
    for (int c = 0; c < C; ++c) { float v = Xb[(long)c * NPTS + m]; s += v * v; }
    sqall[m] = s;
  }
  __syncthreads();

  // register top-k (sorted descending; ties keep earlier/lower index on top)
  float topv[KNN];
  int   topi[KNN];
  #pragma unroll
  for (int j = 0; j < KNN; ++j) { topv[j] = -INFINITY; topi[j] = 0x7fffffff; }
  float vmin = -INFINITY;

  for (int pc = 0; pc < NPTS; pc += 64) {
    float acc[4][4] = {};
    for (int cc = 0; cc < C; cc += CT) {
      __syncthreads();  // qbuf/pbuf (+Dbuf from prev tile) free to overwrite
      for (int t = tid; t < 64 * CT; t += 256) {
        int c = t >> 6, m = t & 63;
        qbuf[c * 64 + m] = Xb[(long)(cc + c) * NPTS + q0 + m];
        pbuf[c * 64 + m] = Xb[(long)(cc + c) * NPTS + pc + m];
      }
      __syncthreads();
      #pragma unroll
      for (int c = 0; c < CT; ++c) {
        const float4 qv = *(const float4*)&qbuf[c * 64 + ty * 4];
        const float4 pv = *(const float4*)&pbuf[c * 64 + tx * 4];
        acc[0][0] += qv.x * pv.x; acc[0][1] += qv.x * pv.y; acc[0][2] += qv.x * pv.z; acc[0][3] += qv.x * pv.w;
        acc[1][0] += qv.y * pv.x; acc[1][1] += qv.y * pv.y; acc[1][2] += qv.y * pv.z; acc[1][3] += qv.y * pv.w;
        acc[2][0] += qv.z * pv.x; acc[2][1] += qv.z * pv.y; acc[2][2] += qv.z * pv.z; acc[2][3] += qv.z * pv.w;
        acc[3][0] += qv.w * pv.x; acc[3][1] += qv.w * pv.y; acc[3][2] += qv.w * pv.z; acc[3][3] += qv.w * pv.w;
      }
    }
    // D[p][q] = 2*inner - sq[p]
    #pragma unroll
    for (int j = 0; j < 4; ++j) {
      const int p = pc + tx * 4 + j;
      const float sq = sqall[p];
      float4 dv;
      dv.x = 2.f * acc[0][j] - sq;
      dv.y = 2.f * acc[1][j] - sq;
      dv.z = 2.f * acc[2][j] - sq;
      dv.w = 2.f * acc[3][j] - sq;
      *(float4*)&Dbuf[tx * 4 + j][ty * 4] = dv;
    }
    __syncthreads();

    // selection: thread (q, sub) scans rows [sub*16, sub*16+16)
    #pragma unroll 4
    for (int i = 0; i < 16; ++i) {
      const float v = Dbuf[sub * 16 + i][q];   // consecutive q across lanes: conflict-free
      if (v > vmin) {
        float cv = v; int ci = pc + sub * 16 + i;
        bool ins = false;
        #pragma unroll
        for (int j = 0; j < KNN; ++j) {
          const float tv = topv[j]; const int ti = topi[j];
          const bool gt = ins || (cv > tv);
          topv[j] = gt ? cv : tv;
          topi[j] = gt ? ci : ti;
          cv = gt ? tv : cv;
          ci = gt ? ti : ci;
          ins = gt;
        }
        vmin = topv[KNN - 1];
      }
    }
  }

  // merge 4 sorted sub-lists per query (lists transposed in LDS: [j][q*4+sub])
  __syncthreads();
  {
    float* mv = region3;                       // [20][256]
    int*   mi = (int*)(region3 + 5120);        // [20][256]
    const int slot = q * 4 + sub;
    #pragma unroll
    for (int j = 0; j < KNN; ++j) { mv[j * 256 + slot] = topv[j]; mi[j * 256 + slot] = topi[j]; }
  }
  __syncthreads();
  if (tid < 64) {
    const float* mv = region3;
    const int*   mi = (const int*)(region3 + 5120);
    int p0 = 0, p1 = 0, p2 = 0, p3 = 0;
    int* op = idxOut + ((long)(b * NPTS + q0 + tid)) * KNN;
    for (int j = 0; j < KNN; ++j) {
      float bv = -INFINITY; int bi = 0x7fffffff; int bs = 0;
      {
        if (p0 < KNN) { float v = mv[p0 * 256 + tid * 4 + 0]; int i = mi[p0 * 256 + tid * 4 + 0];
          if (v > bv || (v == bv && i < bi)) { bv = v; bi = i; bs = 0; } }
        if (p1 < KNN) { float v = mv[p1 * 256 + tid * 4 + 1]; int i = mi[p1 * 256 + tid * 4 + 1];
          if (v > bv || (v == bv && i < bi)) { bv = v; bi = i; bs = 1; } }
        if (p2 < KNN) { float v = mv[p2 * 256 + tid * 4 + 2]; int i = mi[p2 * 256 + tid * 4 + 2];
          if (v > bv || (v == bv && i < bi)) { bv = v; bi = i; bs = 2; } }
        if (p3 < KNN) { float v = mv[p3 * 256 + tid * 4 + 3]; int i = mi[p3 * 256 + tid * 4 + 3];
          if (v > bv || (v == bv && i < bi)) { bv = v; bi = i; bs = 3; } }
      }
      p0 += (bs == 0); p1 += (bs == 1); p2 += (bs == 2); p3 += (bs == 3);
      op[j] = bi;
    }
  }
}

// ---------------------------------------------------------------------------
// gather + sum over k neighbors: agg[b,c,n] = sum_j X[b,c,idx[b,n,j]]
// ---------------------------------------------------------------------------
__global__ __launch_bounds__(256) void gather_sum_kernel(const float* __restrict__ X,
    long batchStride, int C, const int* __restrict__ idx, float* __restrict__ agg) {
  __shared__ int sidx[256][KNN + 1];
  const int b   = blockIdx.y;
  const int n0  = blockIdx.x * 256;
  const int tid = threadIdx.x;
  const int* ib = idx + ((long)(b * NPTS + n0)) * KNN;
  for (int t = tid; t < 256 * KNN; t += 256) {
    sidx[t / KNN][t % KNN] = ib[t];
  }
  __syncthreads();
  const float* Xb = X + (long)b * batchStride;
  float* ab = agg + (long)b * C * NPTS;
  for (int c = 0; c < C; ++c) {
    const float* row = Xb + (long)c * NPTS;
    float s = 0.f;
    #pragma unroll
    for (int j = 0; j < KNN; ++j) s += row[sidx[tid][j]];
    ab[(long)c * NPTS + n0 + tid] = s;
  }
}

// ---------------------------------------------------------------------------
// 1x1 conv as per-batch GEMM: Y[b,o,n] = sum_c W[o,c] * Xin[b,c,n]
// ---------------------------------------------------------------------------
__global__ __launch_bounds__(256) void conv_kernel(const float* __restrict__ Xin, long inBatchStride,
    const float* __restrict__ W, int C, int O,
    float* __restrict__ Yout, long outBatchStride, int outChanOffset) {
  __shared__ float Wt[32][68];   // [k][o]
  __shared__ float Xt[32][68];   // [k][n]
  const int b   = blockIdx.z;
  const int o0  = blockIdx.y * 64;
  const int n0  = blockIdx.x * 64;
  const int tid = threadIdx.x;
  const int ty  = tid >> 4, tx = tid & 15;
  const float* Xb = Xin + (long)b * inBatchStride;
  float acc[4][4] = {};
  for (int cc = 0; cc < C; cc += 32) {
    const int cw = min(32, C - cc);
    __syncthreads();
    for (int t = tid; t < 64 * 32; t += 256) {
      int oo = t >> 5, kk = t & 31;
      Wt[kk][oo] = (kk < cw) ? W[(long)(o0 + oo) * C + cc + kk] : 0.f;
    }
    for (int t = tid; t < 32 * 64; t += 256) {
      int kk = t >> 6, nn = t & 63;
      Xt[kk][nn] = (kk < cw) ? Xb[(long)(cc + kk) * NPTS + n0 + nn] : 0.f;
    }
    __syncthreads();
    #pragma unroll
    for (int kk = 0; kk < 32; ++kk) {
      const float4 wv = *(const float4*)&Wt[kk][ty * 4];
      const float4 xv = *(const float4*)&Xt[kk][tx * 4];
      acc[0][0] += wv.x * xv.x; acc[0][1] += wv.x * xv.y; acc[0][2] += wv.x * xv.z; acc[0][3] += wv.x * xv.w;
      acc[1][0] += wv.y * xv.x; acc[1][1] += wv.y * xv.y; acc[1][2] += wv.y * xv.z; acc[1][3] += wv.y * xv.w;
      acc[2][0] += wv.z * xv.x; acc[2][1] += wv.z * xv.y; acc[2][2] += wv.z * xv.z; acc[2][3] += wv.z * xv.w;
      acc[3][0] += wv.w * xv.x; acc[3][1] += wv.w * xv.y; acc[3][2] += wv.w * xv.z; acc[3][3] += wv.w * xv.w;
    }
  }
  #pragma unroll
  for (int i = 0; i < 4; ++i) {
    float4 v = make_float4(acc[i][0], acc[i][1], acc[i][2], acc[i][3]);
    *(float4*)&Yout[(long)b * outBatchStride + (long)(outChanOffset + o0 + ty * 4 + i) * NPTS + n0 + tx * 4] = v;
  }
}

// ---------------------------------------------------------------------------
// BN training stats over (batch, N) per channel
// ---------------------------------------------------------------------------
__global__ __launch_bounds__(256) void bn_stats_kernel(const float* __restrict__ Y, long batchStride,
    int chanOffset, float* __restrict__ meanOut, float* __restrict__ rstdOut) {
  const int o   = blockIdx.x;
  const int tid = threadIdx.x;
  const float* base = Y + (long)(chanOffset + o) * NPTS;
  float s = 0.f, s2 = 0.f;
  for (int b = 0; b < BATCH; ++b) {
    const float* p = base + (long)b * batchStride;
    for (int t = tid; t < NPTS; t += 256) { float v = p[t]; s += v; s2 += v * v; }
  }
  for (int off = 32; off > 0; off >>= 1) { s += __shfl_down(s, off); s2 += __shfl_down(s2, off); }
  __shared__ float r1[4], r2[4];
  const int wid = tid >> 6;
  if ((tid & 63) == 0) { r1[wid] = s; r2[wid] = s2; }
  __syncthreads();
  if (tid == 0) {
    s  = r1[0] + r1[1] + r1[2] + r1[3];
    s2 = r2[0] + r2[1] + r2[2] + r2[3];
    float m   = s * (1.f / 16384.f);
    float var = s2 * (1.f / 16384.f) - m * m;
    meanOut[o] = m;
    rstdOut[o] = rsqrtf(var + 1e-5f);
  }
}

// ---------------------------------------------------------------------------
// BN normalize + LeakyReLU, in place
// ---------------------------------------------------------------------------
__global__ __launch_bounds__(256) void bn_apply_kernel(float* __restrict__ Y, long batchStride, int chanOffset,
    const float* __restrict__ meanB, const float* __restrict__ rstdB,
    const float* __restrict__ g, const float* __restrict__ beta) {
  const int n = blockIdx.x * 256 + threadIdx.x;
  const int o = blockIdx.y;
  const int b = blockIdx.z;
  float* p = Y + (long)b * batchStride + (long)(chanOffset + o) * NPTS;
  const float sc = rstdB[o] * g[o];
  float v = (p[n] - meanB[o]) * sc + beta[o];
  p[n] = (v > 0.f) ? v : 0.2f * v;
}

// ---------------------------------------------------------------------------
// fused BN + LeakyReLU + max/mean pooling over N for layer 5
// ---------------------------------------------------------------------------
__global__ __launch_bounds__(256) void bn_pool_kernel(const float* __restrict__ H,
    const float* __restrict__ meanB, const float* __restrict__ rstdB,
    const float* __restrict__ g, const float* __restrict__ beta,
    float* __restrict__ Z) {
  const int o   = blockIdx.x;
  const int b   = blockIdx.y;
  const int tid = threadIdx.x;
  const float* p = H + (long)b * (1024L * NPTS) + (long)o * NPTS;
  const float sc = rstdB[o] * g[o], mu = meanB[o], bb = beta[o];
  float mx = -INFINITY, s = 0.f;
  for (int t = tid; t < NPTS; t += 256) {
    float v = (p[t] - mu) * sc + bb;
    v = (v > 0.f) ? v : 0.2f * v;
    mx = fmaxf(mx, v);
    s += v;
  }
  for (int off = 32; off > 0; off >>= 1) { mx = fmaxf(mx, __shfl_down(mx, off)); s += __shfl_down(s, off); }
  __shared__ float rm[4], rs[4];
  const int wid = tid >> 6;
  if ((tid & 63) == 0) { rm[wid] = mx; rs[wid] = s; }
  __syncthreads();
  if (tid == 0) {
    mx = fmaxf(fmaxf(rm[0], rm[1]), fmaxf(rm[2], rm[3]));
    s  = rs[0] + rs[1] + rs[2] + rs[3];
    Z[(long)b * 2048 + o]        = mx;
    Z[(long)b * 2048 + 1024 + o] = s * (1.f / 1024.f);
  }
}

// ---------------------------------------------------------------------------
// small FC: out[b,o] = sum_c in[b,c]*W[o,c] (+bias)
// ---------------------------------------------------------------------------
__global__ void fc_kernel(const float* __restrict__ in, const float* __restrict__ Wm,
    const float* __restrict__ bias, float* __restrict__ out, int Cin, int Oout) {
  const int idx = blockIdx.x * 256 + threadIdx.x;
  if (idx >= BATCH * Oout) return;
  const int b = idx / Oout, o = idx - b * Oout;
  const float* ip = in + (long)b * Cin;
  const float* wp = Wm + (long)o * Cin;
  float s = bias ? bias[o] : 0.f;
  for (int c = 0; c < Cin; ++c) s += ip[c] * wp[c];
  out[idx] = s;
}

// ---------------------------------------------------------------------------
// BN over batch axis (16 samples) + LeakyReLU, in place
// ---------------------------------------------------------------------------
__global__ void bn_small_kernel(float* __restrict__ buf, const float* __restrict__ g,
    const float* __restrict__ beta, int O) {
  const int o = blockIdx.x * 256 + threadIdx.x;
  if (o >= O) return;
  float s = 0.f, s2 = 0.f;
  for (int b = 0; b < BATCH; ++b) { float v = buf[b * O + o]; s += v; s2 += v * v; }
  const float m   = s * (1.f / 16.f);
  const float var = s2 * (1.f / 16.f) - m * m;
  const float sc  = rsqrtf(var + 1e-5f) * g[o];
  const float bb  = beta[o];
  for (int b = 0; b < BATCH; ++b) {
    float v = (buf[b * O + o] - m) * sc + bb;
    buf[b * O + o] = (v > 0.f) ? v : 0.2f * v;
  }
}

extern "C" void kernel_launch(void* const* d_in, const int* in_sizes, int n_in,
                              void* d_out, int out_size, void* d_ws, size_t ws_size,
                              hipStream_t stream) {
  const float* x   = (const float*)d_in[0];
  const float* W1  = (const float*)d_in[1];
  const float* g1  = (const float*)d_in[2];
  const float* b1  = (const float*)d_in[3];
  const float* W2  = (const float*)d_in[4];
  const float* g2  = (const float*)d_in[5];
  const float* b2  = (const float*)d_in[6];
  const float* W3  = (const float*)d_in[7];
  const float* g3  = (const float*)d_in[8];
  const float* b3  = (const float*)d_in[9];
  const float* W4  = (const float*)d_in[10];
  const float* g4  = (const float*)d_in[11];
  const float* b4  = (const float*)d_in[12];
  const float* W5  = (const float*)d_in[13];
  const float* g5  = (const float*)d_in[14];
  const float* b5  = (const float*)d_in[15];
  const float* l1W = (const float*)d_in[16];
  const float* g6  = (const float*)d_in[17];
  const float* b6  = (const float*)d_in[18];
  const float* l2W = (const float*)d_in[19];
  const float* l2b = (const float*)d_in[20];
  const float* g7  = (const float*)d_in[21];
  const float* b7  = (const float*)d_in[22];
  const float* l3W = (const float*)d_in[23];
  const float* l3b = (const float*)d_in[24];

  float* ws   = (float*)d_ws;
  float* Xcat = ws;                      // (B,512,N)
  float* H    = Xcat + 8388608;          // (B,1024,N)
  float* AGG  = H + 16777216;            // (B,<=128,N)
  int*   IDX  = (int*)(AGG + 2097152);   // (B,N,20)
  float* MEAN = (float*)(IDX + 327680);  // 1024
  float* RSTD = MEAN + 1024;             // 1024
  float* Z    = RSTD + 1024;             // (B,2048)
  float* Z1   = Z + 32768;               // (B,512)
  float* Z2   = Z1 + 8192;               // (B,256)

  const long XS = 512L * 1024;
  const long HS = 1024L * 1024;

  // ---- edge block 1 ----
  knn_kernel<3><<<dim3(16, 16), 256, 0, stream>>>(x, 3L * 1024, IDX);
  gather_sum_kernel<<<dim3(4, 16), 256, 0, stream>>>(x, 3L * 1024, 3, IDX, AGG);
  conv_kernel<<<dim3(16, 1, 16), 256, 0, stream>>>(AGG, 3L * 1024, W1, 3, 64, Xcat, XS, 0);
  bn_stats_kernel<<<64, 256, 0, stream>>>(Xcat, XS, 0, MEAN, RSTD);
  bn_apply_kernel<<<dim3(4, 64, 16), 256, 0, stream>>>(Xcat, XS, 0, MEAN, RSTD, g1, b1);

  // ---- edge block 2 ----
  knn_kernel<64><<<dim3(16, 16), 256, 0, stream>>>(Xcat, XS, IDX);
  gather_sum_kernel<<<dim3(4, 16), 256, 0, stream>>>(Xcat, XS, 64, IDX, AGG);
  conv_kernel<<<dim3(16, 1, 16), 256, 0, stream>>>(AGG, 64L * 1024, W2, 64, 64, Xcat, XS, 64);
  bn_stats_kernel<<<64, 256, 0, stream>>>(Xcat, XS, 64, MEAN, RSTD);
  bn_apply_kernel<<<dim3(4, 64, 16), 256, 0, stream>>>(Xcat, XS, 64, MEAN, RSTD, g2, b2);

  // ---- edge block 3 ----
  knn_kernel<64><<<dim3(16, 16), 256, 0, stream>>>(Xcat + 64L * 1024, XS, IDX);
  gather_sum_kernel<<<dim3(4, 16), 256, 0, stream>>>(Xcat + 64L * 1024, XS, 64, IDX, AGG);
  conv_kernel<<<dim3(16, 2, 16), 256, 0, stream>>>(AGG, 64L * 1024, W3, 64, 128, Xcat, XS, 128);
  bn_stats_kernel<<<128, 256, 0, stream>>>(Xcat, XS, 128, MEAN, RSTD);
  bn_apply_kernel<<<dim3(4, 128, 16), 256, 0, stream>>>(Xcat, XS, 128, MEAN, RSTD, g3, b3);

  // ---- edge block 4 ----
  knn_kernel<128><<<dim3(16, 16), 256, 0, stream>>>(Xcat + 128L * 1024, XS, IDX);
  gather_sum_kernel<<<dim3(4, 16), 256, 0, stream>>>(Xcat + 128L * 1024, XS, 128, IDX, AGG);
  conv_kernel<<<dim3(16, 4, 16), 256, 0, stream>>>(AGG, 128L * 1024, W4, 128, 256, Xcat, XS, 256);
  bn_stats_kernel<<<256, 256, 0, stream>>>(Xcat, XS, 256, MEAN, RSTD);
  bn_apply_kernel<<<dim3(4, 256, 16), 256, 0, stream>>>(Xcat, XS, 256, MEAN, RSTD, g4, b4);

  // ---- layer 5 ----
  conv_kernel<<<dim3(16, 16, 16), 256, 0, stream>>>(Xcat, XS, W5, 512, 1024, H, HS, 0);
  bn_stats_kernel<<<1024, 256, 0, stream>>>(H, HS, 0, MEAN, RSTD);
  bn_pool_kernel<<<dim3(1024, 16), 256, 0, stream>>>(H, MEAN, RSTD, g5, b5, Z);

  // ---- MLP head ----
  fc_kernel<<<32, 256, 0, stream>>>(Z, l1W, nullptr, Z1, 2048, 512);
  bn_small_kernel<<<2, 256, 0, stream>>>(Z1, g6, b6, 512);
  fc_kernel<<<16, 256, 0, stream>>>(Z1, l2W, l2b, Z2, 512, 256);
  bn_small_kernel<<<1, 256, 0, stream>>>(Z2, g7, b7, 256);
  fc_kernel<<<3, 256, 0, stream>>>(Z2, l3W, l3b, (float*)d_out, 256, 40);
}

// Round 3
// 1799.737 us; speedup vs baseline: 2.5558x; 1.2020x over previous
//
#include <hip/hip_runtime.h>
#include <hip/hip_bf16.h>
#include <math.h>

#define NPTS 1024
#define BATCH 16
#define KNN 20

typedef __attribute__((ext_vector_type(8))) short short8;
typedef __attribute__((ext_vector_type(4))) float f32x4;

// ---------------------------------------------------------------------------
// knn top-k: register top-20, 4 threads/query, predicated carry-insert.
// fp32 distances (feeds discrete top-k -> must stay exact-ish).
// ---------------------------------------------------------------------------
template<int C>
__global__ __launch_bounds__(256) void knn_kernel(const float* __restrict__ X,
                                                  long batchStride,
                                                  int* __restrict__ idxOut) {
  constexpr int CT = (C < 64) ? C : 64;
  __shared__ float sqall[NPTS];
  __shared__ float Dbuf[64][68];
  __shared__ float region3[10240];

  float* qbuf = region3;
  float* pbuf = region3 + CT * 64;

  const int b   = blockIdx.y;
  const int q0  = blockIdx.x * 64;
  const int tid = threadIdx.x;
  const int ty  = tid >> 4, tx = tid & 15;
  const int q   = tid & 63;
  const int sub = tid >> 6;
  const float* Xb = X + (long)b * batchStride;

  for (int m = tid; m < NPTS; m += 256) {
    float s = 0.f;
    for (int c = 0; c < C; ++c) { float v = Xb[(long)c * NPTS + m]; s += v * v; }
    sqall[m] = s;
  }
  __syncthreads();

  float topv[KNN];
  int   topi[KNN];
  #pragma unroll
  for (int j = 0; j < KNN; ++j) { topv[j] = -INFINITY; topi[j] = 0x7fffffff; }
  float vmin = -INFINITY;

  for (int pc = 0; pc < NPTS; pc += 64) {
    float acc[4][4] = {};
    for (int cc = 0; cc < C; cc += CT) {
      __syncthreads();
      for (int t = tid; t < 64 * CT; t += 256) {
        int c = t >> 6, m = t & 63;
        qbuf[c * 64 + m] = Xb[(long)(cc + c) * NPTS + q0 + m];
        pbuf[c * 64 + m] = Xb[(long)(cc + c) * NPTS + pc + m];
      }
      __syncthreads();
      #pragma unroll
      for (int c = 0; c < CT; ++c) {
        const float4 qv = *(const float4*)&qbuf[c * 64 + ty * 4];
        const float4 pv = *(const float4*)&pbuf[c * 64 + tx * 4];
        acc[0][0] += qv.x * pv.x; acc[0][1] += qv.x * pv.y; acc[0][2] += qv.x * pv.z; acc[0][3] += qv.x * pv.w;
        acc[1][0] += qv.y * pv.x; acc[1][1] += qv.y * pv.y; acc[1][2] += qv.y * pv.z; acc[1][3] += qv.y * pv.w;
        acc[2][0] += qv.z * pv.x; acc[2][1] += qv.z * pv.y; acc[2][2] += qv.z * pv.z; acc[2][3] += qv.z * pv.w;
        acc[3][0] += qv.w * pv.x; acc[3][1] += qv.w * pv.y; acc[3][2] += qv.w * pv.z; acc[3][3] += qv.w * pv.w;
      }
    }
    #pragma unroll
    for (int j = 0; j < 4; ++j) {
      const int p = pc + tx * 4 + j;
      const float sq = sqall[p];
      float4 dv;
      dv.x = 2.f * acc[0][j] - sq;
      dv.y = 2.f * acc[1][j] - sq;
      dv.z = 2.f * acc[2][j] - sq;
      dv.w = 2.f * acc[3][j] - sq;
      *(float4*)&Dbuf[tx * 4 + j][ty * 4] = dv;
    }
    __syncthreads();

    #pragma unroll 4
    for (int i = 0; i < 16; ++i) {
      const float v = Dbuf[sub * 16 + i][q];
      if (v > vmin) {
        float cv = v; int ci = pc + sub * 16 + i;
        bool ins = false;
        #pragma unroll
        for (int j = 0; j < KNN; ++j) {
          const float tv = topv[j]; const int ti = topi[j];
          const bool gt = ins || (cv > tv);
          topv[j] = gt ? cv : tv;
          topi[j] = gt ? ci : ti;
          cv = gt ? tv : cv;
          ci = gt ? ti : ci;
          ins = gt;
        }
        vmin = topv[KNN - 1];
      }
    }
  }

  __syncthreads();
  {
    float* mv = region3;
    int*   mi = (int*)(region3 + 5120);
    const int slot = q * 4 + sub;
    #pragma unroll
    for (int j = 0; j < KNN; ++j) { mv[j * 256 + slot] = topv[j]; mi[j * 256 + slot] = topi[j]; }
  }
  __syncthreads();
  if (tid < 64) {
    const float* mv = region3;
    const int*   mi = (const int*)(region3 + 5120);
    int p0 = 0, p1 = 0, p2 = 0, p3 = 0;
    int* op = idxOut + ((long)(b * NPTS + q0 + tid)) * KNN;
    for (int j = 0; j < KNN; ++j) {
      float bv = -INFINITY; int bi = 0x7fffffff; int bs = 0;
      if (p0 < KNN) { float v = mv[p0 * 256 + tid * 4 + 0]; int i = mi[p0 * 256 + tid * 4 + 0];
        if (v > bv || (v == bv && i < bi)) { bv = v; bi = i; bs = 0; } }
      if (p1 < KNN) { float v = mv[p1 * 256 + tid * 4 + 1]; int i = mi[p1 * 256 + tid * 4 + 1];
        if (v > bv || (v == bv && i < bi)) { bv = v; bi = i; bs = 1; } }
      if (p2 < KNN) { float v = mv[p2 * 256 + tid * 4 + 2]; int i = mi[p2 * 256 + tid * 4 + 2];
        if (v > bv || (v == bv && i < bi)) { bv = v; bi = i; bs = 2; } }
      if (p3 < KNN) { float v = mv[p3 * 256 + tid * 4 + 3]; int i = mi[p3 * 256 + tid * 4 + 3];
        if (v > bv || (v == bv && i < bi)) { bv = v; bi = i; bs = 3; } }
      p0 += (bs == 0); p1 += (bs == 1); p2 += (bs == 2); p3 += (bs == 3);
      op[j] = bi;
    }
  }
}

// ---------------------------------------------------------------------------
// gather + sum over k neighbors
// ---------------------------------------------------------------------------
__global__ __launch_bounds__(256) void gather_sum_kernel(const float* __restrict__ X,
    long batchStride, int C, const int* __restrict__ idx, float* __restrict__ agg) {
  __shared__ int sidx[256][KNN + 1];
  const int b   = blockIdx.y;
  const int n0  = blockIdx.x * 256;
  const int tid = threadIdx.x;
  const int* ib = idx + ((long)(b * NPTS + n0)) * KNN;
  for (int t = tid; t < 256 * KNN; t += 256) {
    sidx[t / KNN][t % KNN] = ib[t];
  }
  __syncthreads();
  const float* Xb = X + (long)b * batchStride;
  float* ab = agg + (long)b * C * NPTS;
  for (int c = 0; c < C; ++c) {
    const float* row = Xb + (long)c * NPTS;
    float s = 0.f;
    #pragma unroll
    for (int j = 0; j < KNN; ++j) s += row[sidx[tid][j]];
    ab[(long)c * NPTS + n0 + tid] = s;
  }
}

// ---------------------------------------------------------------------------
// fp32 conv (kept for conv1-3, which feed knn)
// ---------------------------------------------------------------------------
__global__ __launch_bounds__(256) void conv_kernel(const float* __restrict__ Xin, long inBatchStride,
    const float* __restrict__ W, int C, int O,
    float* __restrict__ Yout, long outBatchStride, int outChanOffset) {
  __shared__ float Wt[32][68];
  __shared__ float Xt[32][68];
  const int b   = blockIdx.z;
  const int o0  = blockIdx.y * 64;
  const int n0  = blockIdx.x * 64;
  const int tid = threadIdx.x;
  const int ty  = tid >> 4, tx = tid & 15;
  const float* Xb = Xin + (long)b * inBatchStride;
  float acc[4][4] = {};
  for (int cc = 0; cc < C; cc += 32) {
    const int cw = min(32, C - cc);
    __syncthreads();
    for (int t = tid; t < 64 * 32; t += 256) {
      int oo = t >> 5, kk = t & 31;
      Wt[kk][oo] = (kk < cw) ? W[(long)(o0 + oo) * C + cc + kk] : 0.f;
    }
    for (int t = tid; t < 32 * 64; t += 256) {
      int kk = t >> 6, nn = t & 63;
      Xt[kk][nn] = (kk < cw) ? Xb[(long)(cc + kk) * NPTS + n0 + nn] : 0.f;
    }
    __syncthreads();
    #pragma unroll
    for (int kk = 0; kk < 32; ++kk) {
      const float4 wv = *(const float4*)&Wt[kk][ty * 4];
      const float4 xv = *(const float4*)&Xt[kk][tx * 4];
      acc[0][0] += wv.x * xv.x; acc[0][1] += wv.x * xv.y; acc[0][2] += wv.x * xv.z; acc[0][3] += wv.x * xv.w;
      acc[1][0] += wv.y * xv.x; acc[1][1] += wv.y * xv.y; acc[1][2] += wv.y * xv.z; acc[1][3] += wv.y * xv.w;
      acc[2][0] += wv.z * xv.x; acc[2][1] += wv.z * xv.y; acc[2][2] += wv.z * xv.z; acc[2][3] += wv.z * xv.w;
      acc[3][0] += wv.w * xv.x; acc[3][1] += wv.w * xv.y; acc[3][2] += wv.w * xv.z; acc[3][3] += wv.w * xv.w;
    }
  }
  #pragma unroll
  for (int i = 0; i < 4; ++i) {
    float4 v = make_float4(acc[i][0], acc[i][1], acc[i][2], acc[i][3]);
    *(float4*)&Yout[(long)b * outBatchStride + (long)(outChanOffset + o0 + ty * 4 + i) * NPTS + n0 + tx * 4] = v;
  }
}

// ---------------------------------------------------------------------------
// fp32 [b][C][1024] -> bf16 [b][1024][C] transpose (k-contiguous for MFMA B)
// ---------------------------------------------------------------------------
__global__ __launch_bounds__(256) void transpose_bf16_kernel(const float* __restrict__ in,
    long inBatchStride, int C, unsigned short* __restrict__ outT) {
  __shared__ float tile[64][65];
  const int b  = blockIdx.z;
  const int n0 = blockIdx.x * 64, c0 = blockIdx.y * 64;
  const int tid = threadIdx.x;
  const float* ib = in + (long)b * inBatchStride;
  for (int i = tid; i < 4096; i += 256) {
    int r = i >> 6, cn = i & 63;   // r: c offset, cn: n offset (coalesced)
    tile[r][cn] = ib[(long)(c0 + r) * NPTS + n0 + cn];
  }
  __syncthreads();
  unsigned short* ob = outT + (long)b * ((long)NPTS * C);
  for (int i = tid; i < 4096; i += 256) {
    int r = i >> 6, cc = i & 63;   // r: n offset, cc: c offset (coalesced out)
    __hip_bfloat16 h = __float2bfloat16(tile[cc][r]);
    ob[(long)(n0 + r) * C + c0 + cc] = *(unsigned short*)&h;
  }
}

// ---------------------------------------------------------------------------
// fp32 -> bf16 elementwise (weights)
// ---------------------------------------------------------------------------
__global__ void convert_bf16_kernel(const float* __restrict__ in,
                                    unsigned short* __restrict__ out, int n) {
  int i = blockIdx.x * 256 + threadIdx.x;
  if (i < n) { __hip_bfloat16 h = __float2bfloat16(in[i]); out[i] = *(unsigned short*)&h; }
}

// ---------------------------------------------------------------------------
// bf16 MFMA conv: Y[b,o,n] = sum_c W[o,c]*X[b,c,n], fp32 accumulate/out.
// A = Wbf [O][C] (k-contig rows), B = XT [b][N][C] (k-contig rows).
// 128(o) x 128(n) tile, K-step 32, 4 waves each 64x64 (4x4 of 16x16x32).
// LDS rows padded to 40 bf16 (80 B): 16B-aligned b128, 2-way banks (free).
// ---------------------------------------------------------------------------
__global__ __launch_bounds__(256) void conv_mfma_kernel(const unsigned short* __restrict__ Wbf,
    const unsigned short* __restrict__ XT, int C,
    float* __restrict__ Yout, long outBatchStride, int outChanOffset) {
  __shared__ unsigned short Wl[128][40];
  __shared__ unsigned short Xl[128][40];
  const int b  = blockIdx.z;
  const int o0 = blockIdx.y * 128;
  const int n0 = blockIdx.x * 128;
  const int tid  = threadIdx.x;
  const int lane = tid & 63, wid = tid >> 6;
  const int wo = (wid >> 1) * 64, wn = (wid & 1) * 64;
  const int l16 = lane & 15, quad = lane >> 4;
  const unsigned short* Wg = Wbf + (long)o0 * C;
  const unsigned short* Xg = XT + (long)b * ((long)NPTS * C) + (long)n0 * C;

  f32x4 acc[4][4];
  #pragma unroll
  for (int i = 0; i < 4; ++i)
    #pragma unroll
    for (int j = 0; j < 4; ++j) acc[i][j] = (f32x4){0.f, 0.f, 0.f, 0.f};

  for (int kk = 0; kk < C; kk += 32) {
    __syncthreads();
    #pragma unroll
    for (int it = 0; it < 2; ++it) {
      const int id = tid + it * 256;
      const int r = id >> 2, qq = id & 3;
      const float4 va = *(const float4*)&Wg[(long)r * C + kk + qq * 8];
      const float4 vb = *(const float4*)&Xg[(long)r * C + kk + qq * 8];
      *(float4*)&Wl[r][qq * 8] = va;
      *(float4*)&Xl[r][qq * 8] = vb;
    }
    __syncthreads();
    short8 af[4], bfr[4];
    #pragma unroll
    for (int i = 0; i < 4; ++i) af[i]  = *(const short8*)&Wl[wo + i * 16 + l16][quad * 8];
    #pragma unroll
    for (int j = 0; j < 4; ++j) bfr[j] = *(const short8*)&Xl[wn + j * 16 + l16][quad * 8];
    #pragma unroll
    for (int i = 0; i < 4; ++i)
      #pragma unroll
      for (int j = 0; j < 4; ++j)
        acc[i][j] = __builtin_amdgcn_mfma_f32_16x16x32_bf16(af[i], bfr[j], acc[i][j], 0, 0, 0);
  }

  float* Yb = Yout + (long)b * outBatchStride + (long)outChanOffset * NPTS;
  #pragma unroll
  for (int i = 0; i < 4; ++i) {
    #pragma unroll
    for (int r = 0; r < 4; ++r) {
      const int o = o0 + wo + i * 16 + quad * 4 + r;
      float* row = Yb + (long)o * NPTS + n0 + wn;
      #pragma unroll
      for (int j = 0; j < 4; ++j) row[j * 16 + l16] = acc[i][j][r];
    }
  }
}

// ---------------------------------------------------------------------------
// BN stats / apply / pool / head (unchanged)
// ---------------------------------------------------------------------------
__global__ __launch_bounds__(256) void bn_stats_kernel(const float* __restrict__ Y, long batchStride,
    int chanOffset, float* __restrict__ meanOut, float* __restrict__ rstdOut) {
  const int o   = blockIdx.x;
  const int tid = threadIdx.x;
  const float* base = Y + (long)(chanOffset + o) * NPTS;
  float s = 0.f, s2 = 0.f;
  for (int b = 0; b < BATCH; ++b) {
    const float* p = base + (long)b * batchStride;
    for (int t = tid; t < NPTS; t += 256) { float v = p[t]; s += v; s2 += v * v; }
  }
  for (int off = 32; off > 0; off >>= 1) { s += __shfl_down(s, off); s2 += __shfl_down(s2, off); }
  __shared__ float r1[4], r2[4];
  const int wid = tid >> 6;
  if ((tid & 63) == 0) { r1[wid] = s; r2[wid] = s2; }
  __syncthreads();
  if (tid == 0) {
    s  = r1[0] + r1[1] + r1[2] + r1[3];
    s2 = r2[0] + r2[1] + r2[2] + r2[3];
    float m   = s * (1.f / 16384.f);
    float var = s2 * (1.f / 16384.f) - m * m;
    meanOut[o] = m;
    rstdOut[o] = rsqrtf(var + 1e-5f);
  }
}

__global__ __launch_bounds__(256) void bn_apply_kernel(float* __restrict__ Y, long batchStride, int chanOffset,
    const float* __restrict__ meanB, const float* __restrict__ rstdB,
    const float* __restrict__ g, const float* __restrict__ beta) {
  const int n = blockIdx.x * 256 + threadIdx.x;
  const int o = blockIdx.y;
  const int b = blockIdx.z;
  float* p = Y + (long)b * batchStride + (long)(chanOffset + o) * NPTS;
  const float sc = rstdB[o] * g[o];
  float v = (p[n] - meanB[o]) * sc + beta[o];
  p[n] = (v > 0.f) ? v : 0.2f * v;
}

__global__ __launch_bounds__(256) void bn_pool_kernel(const float* __restrict__ H,
    const float* __restrict__ meanB, const float* __restrict__ rstdB,
    const float* __restrict__ g, const float* __restrict__ beta,
    float* __restrict__ Z) {
  const int o   = blockIdx.x;
  const int b   = blockIdx.y;
  const int tid = threadIdx.x;
  const float* p = H + (long)b * (1024L * NPTS) + (long)o * NPTS;
  const float sc = rstdB[o] * g[o], mu = meanB[o], bb = beta[o];
  float mx = -INFINITY, s = 0.f;
  for (int t = tid; t < NPTS; t += 256) {
    float v = (p[t] - mu) * sc + bb;
    v = (v > 0.f) ? v : 0.2f * v;
    mx = fmaxf(mx, v);
    s += v;
  }
  for (int off = 32; off > 0; off >>= 1) { mx = fmaxf(mx, __shfl_down(mx, off)); s += __shfl_down(s, off); }
  __shared__ float rm[4], rs[4];
  const int wid = tid >> 6;
  if ((tid & 63) == 0) { rm[wid] = mx; rs[wid] = s; }
  __syncthreads();
  if (tid == 0) {
    mx = fmaxf(fmaxf(rm[0], rm[1]), fmaxf(rm[2], rm[3]));
    s  = rs[0] + rs[1] + rs[2] + rs[3];
    Z[(long)b * 2048 + o]        = mx;
    Z[(long)b * 2048 + 1024 + o] = s * (1.f / 1024.f);
  }
}

__global__ void fc_kernel(const float* __restrict__ in, const float* __restrict__ Wm,
    const float* __restrict__ bias, float* __restrict__ out, int Cin, int Oout) {
  const int idx = blockIdx.x * 256 + threadIdx.x;
  if (idx >= BATCH * Oout) return;
  const int b = idx / Oout, o = idx - b * Oout;
  const float* ip = in + (long)b * Cin;
  const float* wp = Wm + (long)o * Cin;
  float s = bias ? bias[o] : 0.f;
  for (int c = 0; c < Cin; ++c) s += ip[c] * wp[c];
  out[idx] = s;
}

__global__ void bn_small_kernel(float* __restrict__ buf, const float* __restrict__ g,
    const float* __restrict__ beta, int O) {
  const int o = blockIdx.x * 256 + threadIdx.x;
  if (o >= O) return;
  float s = 0.f, s2 = 0.f;
  for (int b = 0; b < BATCH; ++b) { float v = buf[b * O + o]; s += v; s2 += v * v; }
  const float m   = s * (1.f / 16.f);
  const float var = s2 * (1.f / 16.f) - m * m;
  const float sc  = rsqrtf(var + 1e-5f) * g[o];
  const float bb  = beta[o];
  for (int b = 0; b < BATCH; ++b) {
    float v = (buf[b * O + o] - m) * sc + bb;
    buf[b * O + o] = (v > 0.f) ? v : 0.2f * v;
  }
}

extern "C" void kernel_launch(void* const* d_in, const int* in_sizes, int n_in,
                              void* d_out, int out_size, void* d_ws, size_t ws_size,
                              hipStream_t stream) {
  const float* x   = (const float*)d_in[0];
  const float* W1  = (const float*)d_in[1];
  const float* g1  = (const float*)d_in[2];
  const float* b1  = (const float*)d_in[3];
  const float* W2  = (const float*)d_in[4];
  const float* g2  = (const float*)d_in[5];
  const float* b2  = (const float*)d_in[6];
  const float* W3  = (const float*)d_in[7];
  const float* g3  = (const float*)d_in[8];
  const float* b3  = (const float*)d_in[9];
  const float* W4  = (const float*)d_in[10];
  const float* g4  = (const float*)d_in[11];
  const float* b4  = (const float*)d_in[12];
  const float* W5  = (const float*)d_in[13];
  const float* g5  = (const float*)d_in[14];
  const float* b5  = (const float*)d_in[15];
  const float* l1W = (const float*)d_in[16];
  const float* g6  = (const float*)d_in[17];
  const float* b6  = (const float*)d_in[18];
  const float* l2W = (const float*)d_in[19];
  const float* l2b = (const float*)d_in[20];
  const float* g7  = (const float*)d_in[21];
  const float* b7  = (const float*)d_in[22];
  const float* l3W = (const float*)d_in[23];
  const float* l3b = (const float*)d_in[24];

  float* ws   = (float*)d_ws;
  float* Xcat = ws;                        // (B,512,N)  8,388,608 f
  float* H    = Xcat + 8388608;            // (B,1024,N) 16,777,216 f
  float* REG  = H + 16777216;              // 4,194,304 f region (16MB), overlaid:
  float* AGG  = REG;                       //   AGG (B,<=128,N): REG[0 .. 2,097,152)
  unsigned short* AGGT = (unsigned short*)(REG + 2097152); // bf16 (B,N,128): 2M ushort
  unsigned short* XbfT = (unsigned short*)REG;             // bf16 (B,N,512): 8M ushort (after AGG dead)
  int*   IDX  = (int*)(REG + 4194304);     // (B,N,20) 327,680 i
  float* MEAN = (float*)(IDX + 327680);    // 1024
  float* RSTD = MEAN + 1024;               // 1024
  float* Z    = RSTD + 1024;               // (B,2048)
  float* Z1   = Z + 32768;                 // (B,512)
  float* Z2   = Z1 + 8192;                 // (B,256)
  unsigned short* W4bf = (unsigned short*)(Z2 + 4096);     // 32,768 ushort
  unsigned short* W5bf = W4bf + 32768;                     // 524,288 ushort

  const long XS = 512L * 1024;
  const long HS = 1024L * 1024;

  // ---- edge block 1 (fp32 conv: feeds knn) ----
  knn_kernel<3><<<dim3(16, 16), 256, 0, stream>>>(x, 3L * 1024, IDX);
  gather_sum_kernel<<<dim3(4, 16), 256, 0, stream>>>(x, 3L * 1024, 3, IDX, AGG);
  conv_kernel<<<dim3(16, 1, 16), 256, 0, stream>>>(AGG, 3L * 1024, W1, 3, 64, Xcat, XS, 0);
  bn_stats_kernel<<<64, 256, 0, stream>>>(Xcat, XS, 0, MEAN, RSTD);
  bn_apply_kernel<<<dim3(4, 64, 16), 256, 0, stream>>>(Xcat, XS, 0, MEAN, RSTD, g1, b1);

  // ---- edge block 2 ----
  knn_kernel<64><<<dim3(16, 16), 256, 0, stream>>>(Xcat, XS, IDX);
  gather_sum_kernel<<<dim3(4, 16), 256, 0, stream>>>(Xcat, XS, 64, IDX, AGG);
  conv_kernel<<<dim3(16, 1, 16), 256, 0, stream>>>(AGG, 64L * 1024, W2, 64, 64, Xcat, XS, 64);
  bn_stats_kernel<<<64, 256, 0, stream>>>(Xcat, XS, 64, MEAN, RSTD);
  bn_apply_kernel<<<dim3(4, 64, 16), 256, 0, stream>>>(Xcat, XS, 64, MEAN, RSTD, g2, b2);

  // ---- edge block 3 ----
  knn_kernel<64><<<dim3(16, 16), 256, 0, stream>>>(Xcat + 64L * 1024, XS, IDX);
  gather_sum_kernel<<<dim3(4, 16), 256, 0, stream>>>(Xcat + 64L * 1024, XS, 64, IDX, AGG);
  conv_kernel<<<dim3(16, 2, 16), 256, 0, stream>>>(AGG, 64L * 1024, W3, 64, 128, Xcat, XS, 128);
  bn_stats_kernel<<<128, 256, 0, stream>>>(Xcat, XS, 128, MEAN, RSTD);
  bn_apply_kernel<<<dim3(4, 128, 16), 256, 0, stream>>>(Xcat, XS, 128, MEAN, RSTD, g3, b3);

  // ---- edge block 4 (bf16 MFMA conv: x4 never feeds a top-k) ----
  knn_kernel<128><<<dim3(16, 16), 256, 0, stream>>>(Xcat + 128L * 1024, XS, IDX);
  gather_sum_kernel<<<dim3(4, 16), 256, 0, stream>>>(Xcat + 128L * 1024, XS, 128, IDX, AGG);
  convert_bf16_kernel<<<128, 256, 0, stream>>>(W4, W4bf, 256 * 128);
  transpose_bf16_kernel<<<dim3(16, 2, 16), 256, 0, stream>>>(AGG, 128L * 1024, 128, AGGT);
  conv_mfma_kernel<<<dim3(8, 2, 16), 256, 0, stream>>>(W4bf, AGGT, 128, Xcat, XS, 256);
  bn_stats_kernel<<<256, 256, 0, stream>>>(Xcat, XS, 256, MEAN, RSTD);
  bn_apply_kernel<<<dim3(4, 256, 16), 256, 0, stream>>>(Xcat, XS, 256, MEAN, RSTD, g4, b4);

  // ---- layer 5 (bf16 MFMA) ----
  convert_bf16_kernel<<<2048, 256, 0, stream>>>(W5, W5bf, 1024 * 512);
  transpose_bf16_kernel<<<dim3(16, 8, 16), 256, 0, stream>>>(Xcat, XS, 512, XbfT);
  conv_mfma_kernel<<<dim3(8, 8, 16), 256, 0, stream>>>(W5bf, XbfT, 512, H, HS, 0);
  bn_stats_kernel<<<1024, 256, 0, stream>>>(H, HS, 0, MEAN, RSTD);
  bn_pool_kernel<<<dim3(1024, 16), 256, 0, stream>>>(H, MEAN, RSTD, g5, b5, Z);

  // ---- MLP head ----
  fc_kernel<<<32, 256, 0, stream>>>(Z, l1W, nullptr, Z1, 2048, 512);
  bn_small_kernel<<<2, 256, 0, stream>>>(Z1, g6, b6, 512);
  fc_kernel<<<16, 256, 0, stream>>>(Z1, l2W, l2b, Z2, 512, 256);
  bn_small_kernel<<<1, 256, 0, stream>>>(Z2, g7, b7, 256);
  fc_kernel<<<3, 256, 0, stream>>>(Z2, l3W, l3b, (float*)d_out, 256, 40);
}

// Round 5
// 1719.927 us; speedup vs baseline: 2.6744x; 1.0464x over previous
//
#include <hip/hip_runtime.h>
#include <hip/hip_bf16.h>
#include <math.h>

#define NPTS 1024
#define BATCH 16
#define KNN 20

typedef __attribute__((ext_vector_type(8))) short short8;
typedef __attribute__((ext_vector_type(4))) float f32x4;

// ---------------------------------------------------------------------------
// per-point squared norms: sq[b][m] = sum_c X[b,c,m]^2
// ---------------------------------------------------------------------------
__global__ __launch_bounds__(256) void compute_sq_kernel(const float* __restrict__ X,
    long batchStride, int C, float* __restrict__ sq) {
  const int b = blockIdx.y;
  const int m = blockIdx.x * 256 + threadIdx.x;
  const float* Xb = X + (long)b * batchStride;
  float s = 0.f;
  for (int c = 0; c < C; ++c) { float v = Xb[(long)c * NPTS + m]; s += v * v; }
  sq[b * NPTS + m] = s;
}

// ---------------------------------------------------------------------------
// knn partial top-k: block = (64 queries, 256-candidate chunk, batch).
// Grid 16x4x16 = 1024 blocks. Register top-20, predicated carry-insert,
// 4 threads/query. Partial sorted (val, GLOBAL ushort idx) lists to global.
// NOTE: indices in PARTI are global [0,1024) — merge must NOT re-offset.
// ---------------------------------------------------------------------------
template<int C>
__global__ __launch_bounds__(256) void knn_kernel(const float* __restrict__ X,
    long batchStride, const float* __restrict__ sqg,
    float* __restrict__ PARTV, unsigned short* __restrict__ PARTI) {
  constexpr int CT = (C < 64) ? C : 64;
  constexpr int REGF = (2 * CT * 64 > 7680) ? 2 * CT * 64 : 7680;
  __shared__ float Dbuf[64][68];
  __shared__ float region[REGF];

  float* qbuf = region;
  float* pbuf = region + CT * 64;

  const int b     = blockIdx.z;
  const int q0    = blockIdx.x * 64;
  const int p0    = blockIdx.y * 256;
  const int chunk = blockIdx.y;
  const int tid = threadIdx.x;
  const int ty  = tid >> 4, tx = tid & 15;
  const int q   = tid & 63;
  const int sub = tid >> 6;
  const float* Xb = X + (long)b * batchStride;
  const float* sqb = sqg + b * NPTS;

  float topv[KNN];
  int   topi[KNN];
  #pragma unroll
  for (int j = 0; j < KNN; ++j) { topv[j] = -INFINITY; topi[j] = 0x7fffffff; }
  float vmin = -INFINITY;

  for (int pc = p0; pc < p0 + 256; pc += 64) {
    float acc[4][4] = {};
    for (int cc = 0; cc < C; cc += CT) {
      __syncthreads();
      for (int t = tid; t < 64 * CT; t += 256) {
        int c = t >> 6, m = t & 63;
        qbuf[c * 64 + m] = Xb[(long)(cc + c) * NPTS + q0 + m];
        pbuf[c * 64 + m] = Xb[(long)(cc + c) * NPTS + pc + m];
      }
      __syncthreads();
      #pragma unroll
      for (int c = 0; c < CT; ++c) {
        const float4 qv = *(const float4*)&qbuf[c * 64 + ty * 4];
        const float4 pv = *(const float4*)&pbuf[c * 64 + tx * 4];
        acc[0][0] += qv.x * pv.x; acc[0][1] += qv.x * pv.y; acc[0][2] += qv.x * pv.z; acc[0][3] += qv.x * pv.w;
        acc[1][0] += qv.y * pv.x; acc[1][1] += qv.y * pv.y; acc[1][2] += qv.y * pv.z; acc[1][3] += qv.y * pv.w;
        acc[2][0] += qv.z * pv.x; acc[2][1] += qv.z * pv.y; acc[2][2] += qv.z * pv.z; acc[2][3] += qv.z * pv.w;
        acc[3][0] += qv.w * pv.x; acc[3][1] += qv.w * pv.y; acc[3][2] += qv.w * pv.z; acc[3][3] += qv.w * pv.w;
      }
    }
    #pragma unroll
    for (int j = 0; j < 4; ++j) {
      const int p = pc + tx * 4 + j;
      const float sq = sqb[p];
      float4 dv;
      dv.x = 2.f * acc[0][j] - sq;
      dv.y = 2.f * acc[1][j] - sq;
      dv.z = 2.f * acc[2][j] - sq;
      dv.w = 2.f * acc[3][j] - sq;
      *(float4*)&Dbuf[tx * 4 + j][ty * 4] = dv;
    }
    __syncthreads();

    #pragma unroll 4
    for (int i = 0; i < 16; ++i) {
      const float v = Dbuf[sub * 16 + i][q];
      if (v > vmin) {
        float cv = v; int ci = pc + sub * 16 + i;   // GLOBAL candidate index
        bool ins = false;
        #pragma unroll
        for (int j = 0; j < KNN; ++j) {
          const float tv = topv[j]; const int ti = topi[j];
          const bool gt = ins || (cv > tv);
          topv[j] = gt ? cv : tv;
          topi[j] = gt ? ci : ti;
          cv = gt ? tv : cv;
          ci = gt ? ti : ci;
          ins = gt;
        }
        vmin = topv[KNN - 1];
      }
    }
  }

  // in-block 4-way merge of sub-lists -> sorted partial top-20 for this chunk
  __syncthreads();
  {
    float* mv = region;
    unsigned short* mi = (unsigned short*)(region + 5120);
    const int slot = q * 4 + sub;
    #pragma unroll
    for (int j = 0; j < KNN; ++j) { mv[j * 256 + slot] = topv[j]; mi[j * 256 + slot] = (unsigned short)topi[j]; }
  }
  __syncthreads();
  if (tid < 64) {
    const float* mv = region;
    const unsigned short* mi = (const unsigned short*)(region + 5120);
    int p0_ = 0, p1 = 0, p2 = 0, p3 = 0;
    float* opv = PARTV + (((long)(b * NPTS + q0 + tid)) * 4 + chunk) * KNN;
    unsigned short* opi = PARTI + (((long)(b * NPTS + q0 + tid)) * 4 + chunk) * KNN;
    for (int j = 0; j < KNN; ++j) {
      float bv = -INFINITY; int bi = 0x7fffffff; int bs = 0;
      if (p0_ < KNN) { float v = mv[p0_ * 256 + tid * 4 + 0]; int i = mi[p0_ * 256 + tid * 4 + 0];
        if (v > bv || (v == bv && i < bi)) { bv = v; bi = i; bs = 0; } }
      if (p1 < KNN) { float v = mv[p1 * 256 + tid * 4 + 1]; int i = mi[p1 * 256 + tid * 4 + 1];
        if (v > bv || (v == bv && i < bi)) { bv = v; bi = i; bs = 1; } }
      if (p2 < KNN) { float v = mv[p2 * 256 + tid * 4 + 2]; int i = mi[p2 * 256 + tid * 4 + 2];
        if (v > bv || (v == bv && i < bi)) { bv = v; bi = i; bs = 2; } }
      if (p3 < KNN) { float v = mv[p3 * 256 + tid * 4 + 3]; int i = mi[p3 * 256 + tid * 4 + 3];
        if (v > bv || (v == bv && i < bi)) { bv = v; bi = i; bs = 3; } }
      p0_ += (bs == 0); p1 += (bs == 1); p2 += (bs == 2); p3 += (bs == 3);
      opv[j] = bv; opi[j] = (unsigned short)bi;
    }
  }
}

// ---------------------------------------------------------------------------
// merge 4 sorted partial lists per query -> final top-20 indices.
// PARTI holds GLOBAL indices already — no re-offset. (value desc, index asc)
// tournament == lax.top_k tie-break (chunks are index-ordered).
// ---------------------------------------------------------------------------
__global__ __launch_bounds__(256) void knn_merge_kernel(const float* __restrict__ PARTV,
    const unsigned short* __restrict__ PARTI, int* __restrict__ idxOut) {
  const int idx = blockIdx.x * 256 + threadIdx.x;   // 16384 queries
  const float* pv = PARTV + (long)idx * 4 * KNN;
  const unsigned short* pi = PARTI + (long)idx * 4 * KNN;
  int p0 = 0, p1 = 0, p2 = 0, p3 = 0;
  int* op = idxOut + (long)idx * KNN;
  for (int j = 0; j < KNN; ++j) {
    float bv = -INFINITY; int bi = 0x7fffffff; int bs = 0;
    if (p0 < KNN) { float v = pv[0 * KNN + p0]; int i = pi[0 * KNN + p0];
      if (v > bv || (v == bv && i < bi)) { bv = v; bi = i; bs = 0; } }
    if (p1 < KNN) { float v = pv[1 * KNN + p1]; int i = pi[1 * KNN + p1];
      if (v > bv || (v == bv && i < bi)) { bv = v; bi = i; bs = 1; } }
    if (p2 < KNN) { float v = pv[2 * KNN + p2]; int i = pi[2 * KNN + p2];
      if (v > bv || (v == bv && i < bi)) { bv = v; bi = i; bs = 2; } }
    if (p3 < KNN) { float v = pv[3 * KNN + p3]; int i = pi[3 * KNN + p3];
      if (v > bv || (v == bv && i < bi)) { bv = v; bi = i; bs = 3; } }
    p0 += (bs == 0); p1 += (bs == 1); p2 += (bs == 2); p3 += (bs == 3);
    op[j] = bi;
  }
}

// ---------------------------------------------------------------------------
// gather + sum over k neighbors
// ---------------------------------------------------------------------------
__global__ __launch_bounds__(256) void gather_sum_kernel(const float* __restrict__ X,
    long batchStride, int C, const int* __restrict__ idx, float* __restrict__ agg) {
  __shared__ int sidx[256][KNN + 1];
  const int b   = blockIdx.y;
  const int n0  = blockIdx.x * 256;
  const int tid = threadIdx.x;
  const int* ib = idx + ((long)(b * NPTS + n0)) * KNN;
  for (int t = tid; t < 256 * KNN; t += 256) {
    sidx[t / KNN][t % KNN] = ib[t];
  }
  __syncthreads();
  const float* Xb = X + (long)b * batchStride;
  float* ab = agg + (long)b * C * NPTS;
  for (int c = 0; c < C; ++c) {
    const float* row = Xb + (long)c * NPTS;
    float s = 0.f;
    #pragma unroll
    for (int j = 0; j < KNN; ++j) s += row[sidx[tid][j]];
    ab[(long)c * NPTS + n0 + tid] = s;
  }
}

// ---------------------------------------------------------------------------
// fp32 conv (conv1-3: outputs feed knn, stay fp32)
// ---------------------------------------------------------------------------
__global__ __launch_bounds__(256) void conv_kernel(const float* __restrict__ Xin, long inBatchStride,
    const float* __restrict__ W, int C, int O,
    float* __restrict__ Yout, long outBatchStride, int outChanOffset) {
  __shared__ float Wt[32][68];
  __shared__ float Xt[32][68];
  const int b   = blockIdx.z;
  const int o0  = blockIdx.y * 64;
  const int n0  = blockIdx.x * 64;
  const int tid = threadIdx.x;
  const int ty  = tid >> 4, tx = tid & 15;
  const float* Xb = Xin + (long)b * inBatchStride;
  float acc[4][4] = {};
  for (int cc = 0; cc < C; cc += 32) {
    const int cw = min(32, C - cc);
    __syncthreads();
    for (int t = tid; t < 64 * 32; t += 256) {
      int oo = t >> 5, kk = t & 31;
      Wt[kk][oo] = (kk < cw) ? W[(long)(o0 + oo) * C + cc + kk] : 0.f;
    }
    for (int t = tid; t < 32 * 64; t += 256) {
      int kk = t >> 6, nn = t & 63;
      Xt[kk][nn] = (kk < cw) ? Xb[(long)(cc + kk) * NPTS + n0 + nn] : 0.f;
    }
    __syncthreads();
    #pragma unroll
    for (int kk = 0; kk < 32; ++kk) {
      const float4 wv = *(const float4*)&Wt[kk][ty * 4];
      const float4 xv = *(const float4*)&Xt[kk][tx * 4];
      acc[0][0] += wv.x * xv.x; acc[0][1] += wv.x * xv.y; acc[0][2] += wv.x * xv.z; acc[0][3] += wv.x * xv.w;
      acc[1][0] += wv.y * xv.x; acc[1][1] += wv.y * xv.y; acc[1][2] += wv.y * xv.z; acc[1][3] += wv.y * xv.w;
      acc[2][0] += wv.z * xv.x; acc[2][1] += wv.z * xv.y; acc[2][2] += wv.z * xv.z; acc[2][3] += wv.z * xv.w;
      acc[3][0] += wv.w * xv.x; acc[3][1] += wv.w * xv.y; acc[3][2] += wv.w * xv.z; acc[3][3] += wv.w * xv.w;
    }
  }
  #pragma unroll
  for (int i = 0; i < 4; ++i) {
    float4 v = make_float4(acc[i][0], acc[i][1], acc[i][2], acc[i][3]);
    *(float4*)&Yout[(long)b * outBatchStride + (long)(outChanOffset + o0 + ty * 4 + i) * NPTS + n0 + tx * 4] = v;
  }
}

// ---------------------------------------------------------------------------
// fp32 [b][C][1024] -> bf16 [b][1024][C] transpose (k-contiguous for MFMA B)
// ---------------------------------------------------------------------------
__global__ __launch_bounds__(256) void transpose_bf16_kernel(const float* __restrict__ in,
    long inBatchStride, int C, unsigned short* __restrict__ outT) {
  __shared__ float tile[64][65];
  const int b  = blockIdx.z;
  const int n0 = blockIdx.x * 64, c0 = blockIdx.y * 64;
  const int tid = threadIdx.x;
  const float* ib = in + (long)b * inBatchStride;
  for (int i = tid; i < 4096; i += 256) {
    int r = i >> 6, cn = i & 63;
    tile[r][cn] = ib[(long)(c0 + r) * NPTS + n0 + cn];
  }
  __syncthreads();
  unsigned short* ob = outT + (long)b * ((long)NPTS * C);
  for (int i = tid; i < 4096; i += 256) {
    int r = i >> 6, cc = i & 63;
    __hip_bfloat16 h = __float2bfloat16(tile[cc][r]);
    ob[(long)(n0 + r) * C + c0 + cc] = *(unsigned short*)&h;
  }
}

// ---------------------------------------------------------------------------
// fp32 -> bf16 elementwise (weights)
// ---------------------------------------------------------------------------
__global__ void convert_bf16_kernel(const float* __restrict__ in,
                                    unsigned short* __restrict__ out, int n) {
  int i = blockIdx.x * 256 + threadIdx.x;
  if (i < n) { __hip_bfloat16 h = __float2bfloat16(in[i]); out[i] = *(unsigned short*)&h; }
}

// ---------------------------------------------------------------------------
// bf16 MFMA conv (conv4/conv5: outputs never feed top-k)
// ---------------------------------------------------------------------------
__global__ __launch_bounds__(256) void conv_mfma_kernel(const unsigned short* __restrict__ Wbf,
    const unsigned short* __restrict__ XT, int C,
    float* __restrict__ Yout, long outBatchStride, int outChanOffset) {
  __shared__ unsigned short Wl[128][40];
  __shared__ unsigned short Xl[128][40];
  const int b  = blockIdx.z;
  const int o0 = blockIdx.y * 128;
  const int n0 = blockIdx.x * 128;
  const int tid  = threadIdx.x;
  const int lane = tid & 63, wid = tid >> 6;
  const int wo = (wid >> 1) * 64, wn = (wid & 1) * 64;
  const int l16 = lane & 15, quad = lane >> 4;
  const unsigned short* Wg = Wbf + (long)o0 * C;
  const unsigned short* Xg = XT + (long)b * ((long)NPTS * C) + (long)n0 * C;

  f32x4 acc[4][4];
  #pragma unroll
  for (int i = 0; i < 4; ++i)
    #pragma unroll
    for (int j = 0; j < 4; ++j) acc[i][j] = (f32x4){0.f, 0.f, 0.f, 0.f};

  for (int kk = 0; kk < C; kk += 32) {
    __syncthreads();
    #pragma unroll
    for (int it = 0; it < 2; ++it) {
      const int id = tid + it * 256;
      const int r = id >> 2, qq = id & 3;
      const float4 va = *(const float4*)&Wg[(long)r * C + kk + qq * 8];
      const float4 vb = *(const float4*)&Xg[(long)r * C + kk + qq * 8];
      *(float4*)&Wl[r][qq * 8] = va;
      *(float4*)&Xl[r][qq * 8] = vb;
    }
    __syncthreads();
    short8 af[4], bfr[4];
    #pragma unroll
    for (int i = 0; i < 4; ++i) af[i]  = *(const short8*)&Wl[wo + i * 16 + l16][quad * 8];
    #pragma unroll
    for (int j = 0; j < 4; ++j) bfr[j] = *(const short8*)&Xl[wn + j * 16 + l16][quad * 8];
    #pragma unroll
    for (int i = 0; i < 4; ++i)
      #pragma unroll
      for (int j = 0; j < 4; ++j)
        acc[i][j] = __builtin_amdgcn_mfma_f32_16x16x32_bf16(af[i], bfr[j], acc[i][j], 0, 0, 0);
  }

  float* Yb = Yout + (long)b * outBatchStride + (long)outChanOffset * NPTS;
  #pragma unroll
  for (int i = 0; i < 4; ++i) {
    #pragma unroll
    for (int r = 0; r < 4; ++r) {
      const int o = o0 + wo + i * 16 + quad * 4 + r;
      float* row = Yb + (long)o * NPTS + n0 + wn;
      #pragma unroll
      for (int j = 0; j < 4; ++j) row[j * 16 + l16] = acc[i][j][r];
    }
  }
}

// ---------------------------------------------------------------------------
// BN stats / apply / pool / head
// ---------------------------------------------------------------------------
__global__ __launch_bounds__(256) void bn_stats_kernel(const float* __restrict__ Y, long batchStride,
    int chanOffset, float* __restrict__ meanOut, float* __restrict__ rstdOut) {
  const int o   = blockIdx.x;
  const int tid = threadIdx.x;
  const float* base = Y + (long)(chanOffset + o) * NPTS;
  float s = 0.f, s2 = 0.f;
  for (int b = 0; b < BATCH; ++b) {
    const float* p = base + (long)b * batchStride;
    for (int t = tid; t < NPTS; t += 256) { float v = p[t]; s += v; s2 += v * v; }
  }
  for (int off = 32; off > 0; off >>= 1) { s += __shfl_down(s, off); s2 += __shfl_down(s2, off); }
  __shared__ float r1[4], r2[4];
  const int wid = tid >> 6;
  if ((tid & 63) == 0) { r1[wid] = s; r2[wid] = s2; }
  __syncthreads();
  if (tid == 0) {
    s  = r1[0] + r1[1] + r1[2] + r1[3];
    s2 = r2[0] + r2[1] + r2[2] + r2[3];
    float m   = s * (1.f / 16384.f);
    float var = s2 * (1.f / 16384.f) - m * m;
    meanOut[o] = m;
    rstdOut[o] = rsqrtf(var + 1e-5f);
  }
}

__global__ __launch_bounds__(256) void bn_apply_kernel(float* __restrict__ Y, long batchStride, int chanOffset,
    const float* __restrict__ meanB, const float* __restrict__ rstdB,
    const float* __restrict__ g, const float* __restrict__ beta) {
  const int n = blockIdx.x * 256 + threadIdx.x;
  const int o = blockIdx.y;
  const int b = blockIdx.z;
  float* p = Y + (long)b * batchStride + (long)(chanOffset + o) * NPTS;
  const float sc = rstdB[o] * g[o];
  float v = (p[n] - meanB[o]) * sc + beta[o];
  p[n] = (v > 0.f) ? v : 0.2f * v;
}

__global__ __launch_bounds__(256) void bn_pool_kernel(const float* __restrict__ H,
    const float* __restrict__ meanB, const float* __restrict__ rstdB,
    const float* __restrict__ g, const float* __restrict__ beta,
    float* __restrict__ Z) {
  const int o   = blockIdx.x;
  const int b   = blockIdx.y;
  const int tid = threadIdx.x;
  const float* p = H + (long)b * (1024L * NPTS) + (long)o * NPTS;
  const float sc = rstdB[o] * g[o], mu = meanB[o], bb = beta[o];
  float mx = -INFINITY, s = 0.f;
  for (int t = tid; t < NPTS; t += 256) {
    float v = (p[t] - mu) * sc + bb;
    v = (v > 0.f) ? v : 0.2f * v;
    mx = fmaxf(mx, v);
    s += v;
  }
  for (int off = 32; off > 0; off >>= 1) { mx = fmaxf(mx, __shfl_down(mx, off)); s += __shfl_down(s, off); }
  __shared__ float rm[4], rs[4];
  const int wid = tid >> 6;
  if ((tid & 63) == 0) { rm[wid] = mx; rs[wid] = s; }
  __syncthreads();
  if (tid == 0) {
    mx = fmaxf(fmaxf(rm[0], rm[1]), fmaxf(rm[2], rm[3]));
    s  = rs[0] + rs[1] + rs[2] + rs[3];
    Z[(long)b * 2048 + o]        = mx;
    Z[(long)b * 2048 + 1024 + o] = s * (1.f / 1024.f);
  }
}

__global__ void fc_kernel(const float* __restrict__ in, const float* __restrict__ Wm,
    const float* __restrict__ bias, float* __restrict__ out, int Cin, int Oout) {
  const int idx = blockIdx.x * 256 + threadIdx.x;
  if (idx >= BATCH * Oout) return;
  const int b = idx / Oout, o = idx - b * Oout;
  const float* ip = in + (long)b * Cin;
  const float* wp = Wm + (long)o * Cin;
  float s = bias ? bias[o] : 0.f;
  for (int c = 0; c < Cin; ++c) s += ip[c] * wp[c];
  out[idx] = s;
}

__global__ void bn_small_kernel(float* __restrict__ buf, const float* __restrict__ g,
    const float* __restrict__ beta, int O) {
  const int o = blockIdx.x * 256 + threadIdx.x;
  if (o >= O) return;
  float s = 0.f, s2 = 0.f;
  for (int b = 0; b < BATCH; ++b) { float v = buf[b * O + o]; s += v; s2 += v * v; }
  const float m   = s * (1.f / 16.f);
  const float var = s2 * (1.f / 16.f) - m * m;
  const float sc  = rsqrtf(var + 1e-5f) * g[o];
  const float bb  = beta[o];
  for (int b = 0; b < BATCH; ++b) {
    float v = (buf[b * O + o] - m) * sc + bb;
    buf[b * O + o] = (v > 0.f) ? v : 0.2f * v;
  }
}

extern "C" void kernel_launch(void* const* d_in, const int* in_sizes, int n_in,
                              void* d_out, int out_size, void* d_ws, size_t ws_size,
                              hipStream_t stream) {
  const float* x   = (const float*)d_in[0];
  const float* W1  = (const float*)d_in[1];
  const float* g1  = (const float*)d_in[2];
  const float* b1  = (const float*)d_in[3];
  const float* W2  = (const float*)d_in[4];
  const float* g2  = (const float*)d_in[5];
  const float* b2  = (const float*)d_in[6];
  const float* W3  = (const float*)d_in[7];
  const float* g3  = (const float*)d_in[8];
  const float* b3  = (const float*)d_in[9];
  const float* W4  = (const float*)d_in[10];
  const float* g4  = (const float*)d_in[11];
  const float* b4  = (const float*)d_in[12];
  const float* W5  = (const float*)d_in[13];
  const float* g5  = (const float*)d_in[14];
  const float* b5  = (const float*)d_in[15];
  const float* l1W = (const float*)d_in[16];
  const float* g6  = (const float*)d_in[17];
  const float* b6  = (const float*)d_in[18];
  const float* l2W = (const float*)d_in[19];
  const float* l2b = (const float*)d_in[20];
  const float* g7  = (const float*)d_in[21];
  const float* b7  = (const float*)d_in[22];
  const float* l3W = (const float*)d_in[23];
  const float* l3b = (const float*)d_in[24];

  float* ws   = (float*)d_ws;
  float* Xcat = ws;                        // (B,512,N)
  float* H    = Xcat + 8388608;            // (B,1024,N) (layer-5 only)
  float* REG  = H + 16777216;              // overlaid scratch
  float* AGG  = REG;
  unsigned short* AGGT = (unsigned short*)(REG + 2097152);
  unsigned short* XbfT = (unsigned short*)REG;
  int*   IDX  = (int*)(REG + 4194304);
  float* MEAN = (float*)(IDX + 327680);
  float* RSTD = MEAN + 1024;
  float* Z    = RSTD + 1024;
  float* Z1   = Z + 32768;
  float* Z2   = Z1 + 8192;
  unsigned short* W4bf = (unsigned short*)(Z2 + 4096);
  unsigned short* W5bf = W4bf + 32768;

  // knn scratch overlays H (dead until layer 5)
  float* SQ    = H;
  float* PARTV = H + 16384;
  unsigned short* PARTI = (unsigned short*)(PARTV + 1310720);

  const long XS = 512L * 1024;
  const long HS = 1024L * 1024;
  const dim3 knnGrid(16, 4, 16);

  // ---- edge block 1 (C=3) ----
  compute_sq_kernel<<<dim3(4, 16), 256, 0, stream>>>(x, 3L * 1024, 3, SQ);
  knn_kernel<3><<<knnGrid, 256, 0, stream>>>(x, 3L * 1024, SQ, PARTV, PARTI);
  knn_merge_kernel<<<64, 256, 0, stream>>>(PARTV, PARTI, IDX);
  gather_sum_kernel<<<dim3(4, 16), 256, 0, stream>>>(x, 3L * 1024, 3, IDX, AGG);
  conv_kernel<<<dim3(16, 1, 16), 256, 0, stream>>>(AGG, 3L * 1024, W1, 3, 64, Xcat, XS, 0);
  bn_stats_kernel<<<64, 256, 0, stream>>>(Xcat, XS, 0, MEAN, RSTD);
  bn_apply_kernel<<<dim3(4, 64, 16), 256, 0, stream>>>(Xcat, XS, 0, MEAN, RSTD, g1, b1);

  // ---- edge block 2 (C=64) ----
  compute_sq_kernel<<<dim3(4, 16), 256, 0, stream>>>(Xcat, XS, 64, SQ);
  knn_kernel<64><<<knnGrid, 256, 0, stream>>>(Xcat, XS, SQ, PARTV, PARTI);
  knn_merge_kernel<<<64, 256, 0, stream>>>(PARTV, PARTI, IDX);
  gather_sum_kernel<<<dim3(4, 16), 256, 0, stream>>>(Xcat, XS, 64, IDX, AGG);
  conv_kernel<<<dim3(16, 1, 16), 256, 0, stream>>>(AGG, 64L * 1024, W2, 64, 64, Xcat, XS, 64);
  bn_stats_kernel<<<64, 256, 0, stream>>>(Xcat, XS, 64, MEAN, RSTD);
  bn_apply_kernel<<<dim3(4, 64, 16), 256, 0, stream>>>(Xcat, XS, 64, MEAN, RSTD, g2, b2);

  // ---- edge block 3 (C=64 -> O=128) ----
  compute_sq_kernel<<<dim3(4, 16), 256, 0, stream>>>(Xcat + 64L * 1024, XS, 64, SQ);
  knn_kernel<64><<<knnGrid, 256, 0, stream>>>(Xcat + 64L * 1024, XS, SQ, PARTV, PARTI);
  knn_merge_kernel<<<64, 256, 0, stream>>>(PARTV, PARTI, IDX);
  gather_sum_kernel<<<dim3(4, 16), 256, 0, stream>>>(Xcat + 64L * 1024, XS, 64, IDX, AGG);
  conv_kernel<<<dim3(16, 2, 16), 256, 0, stream>>>(AGG, 64L * 1024, W3, 64, 128, Xcat, XS, 128);
  bn_stats_kernel<<<128, 256, 0, stream>>>(Xcat, XS, 128, MEAN, RSTD);
  bn_apply_kernel<<<dim3(4, 128, 16), 256, 0, stream>>>(Xcat, XS, 128, MEAN, RSTD, g3, b3);

  // ---- edge block 4 (C=128 -> O=256, bf16 MFMA conv) ----
  compute_sq_kernel<<<dim3(4, 16), 256, 0, stream>>>(Xcat + 128L * 1024, XS, 128, SQ);
  knn_kernel<128><<<knnGrid, 256, 0, stream>>>(Xcat + 128L * 1024, XS, SQ, PARTV, PARTI);
  knn_merge_kernel<<<64, 256, 0, stream>>>(PARTV, PARTI, IDX);
  gather_sum_kernel<<<dim3(4, 16), 256, 0, stream>>>(Xcat + 128L * 1024, XS, 128, IDX, AGG);
  convert_bf16_kernel<<<128, 256, 0, stream>>>(W4, W4bf, 256 * 128);
  transpose_bf16_kernel<<<dim3(16, 2, 16), 256, 0, stream>>>(AGG, 128L * 1024, 128, AGGT);
  conv_mfma_kernel<<<dim3(8, 2, 16), 256, 0, stream>>>(W4bf, AGGT, 128, Xcat, XS, 256);
  bn_stats_kernel<<<256, 256, 0, stream>>>(Xcat, XS, 256, MEAN, RSTD);
  bn_apply_kernel<<<dim3(4, 256, 16), 256, 0, stream>>>(Xcat, XS, 256, MEAN, RSTD, g4, b4);

  // ---- layer 5 (bf16 MFMA; overwrites H only after knn scratch is dead) ----
  convert_bf16_kernel<<<2048, 256, 0, stream>>>(W5, W5bf, 1024 * 512);
  transpose_bf16_kernel<<<dim3(16, 8, 16), 256, 0, stream>>>(Xcat, XS, 512, XbfT);
  conv_mfma_kernel<<<dim3(8, 8, 16), 256, 0, stream>>>(W5bf, XbfT, 512, H, HS, 0);
  bn_stats_kernel<<<1024, 256, 0, stream>>>(H, HS, 0, MEAN, RSTD);
  bn_pool_kernel<<<dim3(1024, 16), 256, 0, stream>>>(H, MEAN, RSTD, g5, b5, Z);

  // ---- MLP head ----
  fc_kernel<<<32, 256, 0, stream>>>(Z, l1W, nullptr, Z1, 2048, 512);
  bn_small_kernel<<<2, 256, 0, stream>>>(Z1, g6, b6, 512);
  fc_kernel<<<16, 256, 0, stream>>>(Z1, l2W, l2b, Z2, 512, 256);
  bn_small_kernel<<<1, 256, 0, stream>>>(Z2, g7, b7, 256);
  fc_kernel<<<3, 256, 0, stream>>>(Z2, l3W, l3b, (float*)d_out, 256, 40);
}

// Round 6
// 1375.324 us; speedup vs baseline: 3.3446x; 1.2506x over previous
//
#include <hip/hip_runtime.h>
#include <hip/hip_bf16.h>
#include <math.h>

#define NPTS 1024
#define BATCH 16
#define KNN 20

typedef __attribute__((ext_vector_type(8))) short short8;
typedef __attribute__((ext_vector_type(4))) float f32x4;

// ---------------------------------------------------------------------------
// per-point squared norms: sq[b][m] = sum_c X[b,c,m]^2
// ---------------------------------------------------------------------------
__global__ __launch_bounds__(256) void compute_sq_kernel(const float* __restrict__ X,
    long batchStride, int C, float* __restrict__ sq) {
  const int b = blockIdx.y;
  const int m = blockIdx.x * 256 + threadIdx.x;
  const float* Xb = X + (long)b * batchStride;
  float s = 0.f;
  for (int c = 0; c < C; ++c) { float v = Xb[(long)c * NPTS + m]; s += v * v; }
  sq[b * NPTS + m] = s;
}

// ---------------------------------------------------------------------------
// knn partial top-k: block = (64 queries, 256-candidate chunk, batch).
// Grid 16x4x16 = 1024 blocks. Register top-20, predicated carry-insert,
// 4 threads/query. Partial sorted (val, GLOBAL ushort idx) lists to global.
// ---------------------------------------------------------------------------
template<int C>
__global__ __launch_bounds__(256) void knn_kernel(const float* __restrict__ X,
    long batchStride, const float* __restrict__ sqg,
    float* __restrict__ PARTV, unsigned short* __restrict__ PARTI) {
  constexpr int CT = (C < 64) ? C : 64;
  constexpr int REGF = (2 * CT * 64 > 7680) ? 2 * CT * 64 : 7680;
  __shared__ float Dbuf[64][68];
  __shared__ float region[REGF];

  float* qbuf = region;
  float* pbuf = region + CT * 64;

  const int b     = blockIdx.z;
  const int q0    = blockIdx.x * 64;
  const int p0    = blockIdx.y * 256;
  const int chunk = blockIdx.y;
  const int tid = threadIdx.x;
  const int ty  = tid >> 4, tx = tid & 15;
  const int q   = tid & 63;
  const int sub = tid >> 6;
  const float* Xb = X + (long)b * batchStride;
  const float* sqb = sqg + b * NPTS;

  float topv[KNN];
  int   topi[KNN];
  #pragma unroll
  for (int j = 0; j < KNN; ++j) { topv[j] = -INFINITY; topi[j] = 0x7fffffff; }
  float vmin = -INFINITY;

  for (int pc = p0; pc < p0 + 256; pc += 64) {
    float acc[4][4] = {};
    for (int cc = 0; cc < C; cc += CT) {
      __syncthreads();
      for (int t = tid; t < 64 * CT; t += 256) {
        int c = t >> 6, m = t & 63;
        qbuf[c * 64 + m] = Xb[(long)(cc + c) * NPTS + q0 + m];
        pbuf[c * 64 + m] = Xb[(long)(cc + c) * NPTS + pc + m];
      }
      __syncthreads();
      #pragma unroll
      for (int c = 0; c < CT; ++c) {
        const float4 qv = *(const float4*)&qbuf[c * 64 + ty * 4];
        const float4 pv = *(const float4*)&pbuf[c * 64 + tx * 4];
        acc[0][0] += qv.x * pv.x; acc[0][1] += qv.x * pv.y; acc[0][2] += qv.x * pv.z; acc[0][3] += qv.x * pv.w;
        acc[1][0] += qv.y * pv.x; acc[1][1] += qv.y * pv.y; acc[1][2] += qv.y * pv.z; acc[1][3] += qv.y * pv.w;
        acc[2][0] += qv.z * pv.x; acc[2][1] += qv.z * pv.y; acc[2][2] += qv.z * pv.z; acc[2][3] += qv.z * pv.w;
        acc[3][0] += qv.w * pv.x; acc[3][1] += qv.w * pv.y; acc[3][2] += qv.w * pv.z; acc[3][3] += qv.w * pv.w;
      }
    }
    #pragma unroll
    for (int j = 0; j < 4; ++j) {
      const int p = pc + tx * 4 + j;
      const float sq = sqb[p];
      float4 dv;
      dv.x = 2.f * acc[0][j] - sq;
      dv.y = 2.f * acc[1][j] - sq;
      dv.z = 2.f * acc[2][j] - sq;
      dv.w = 2.f * acc[3][j] - sq;
      *(float4*)&Dbuf[tx * 4 + j][ty * 4] = dv;
    }
    __syncthreads();

    #pragma unroll 4
    for (int i = 0; i < 16; ++i) {
      const float v = Dbuf[sub * 16 + i][q];
      if (v > vmin) {
        float cv = v; int ci = pc + sub * 16 + i;   // GLOBAL candidate index
        bool ins = false;
        #pragma unroll
        for (int j = 0; j < KNN; ++j) {
          const float tv = topv[j]; const int ti = topi[j];
          const bool gt = ins || (cv > tv);
          topv[j] = gt ? cv : tv;
          topi[j] = gt ? ci : ti;
          cv = gt ? tv : cv;
          ci = gt ? ti : ci;
          ins = gt;
        }
        vmin = topv[KNN - 1];
      }
    }
  }

  __syncthreads();
  {
    float* mv = region;
    unsigned short* mi = (unsigned short*)(region + 5120);
    const int slot = q * 4 + sub;
    #pragma unroll
    for (int j = 0; j < KNN; ++j) { mv[j * 256 + slot] = topv[j]; mi[j * 256 + slot] = (unsigned short)topi[j]; }
  }
  __syncthreads();
  if (tid < 64) {
    const float* mv = region;
    const unsigned short* mi = (const unsigned short*)(region + 5120);
    int p0_ = 0, p1 = 0, p2 = 0, p3 = 0;
    float* opv = PARTV + (((long)(b * NPTS + q0 + tid)) * 4 + chunk) * KNN;
    unsigned short* opi = PARTI + (((long)(b * NPTS + q0 + tid)) * 4 + chunk) * KNN;
    for (int j = 0; j < KNN; ++j) {
      float bv = -INFINITY; int bi = 0x7fffffff; int bs = 0;
      if (p0_ < KNN) { float v = mv[p0_ * 256 + tid * 4 + 0]; int i = mi[p0_ * 256 + tid * 4 + 0];
        if (v > bv || (v == bv && i < bi)) { bv = v; bi = i; bs = 0; } }
      if (p1 < KNN) { float v = mv[p1 * 256 + tid * 4 + 1]; int i = mi[p1 * 256 + tid * 4 + 1];
        if (v > bv || (v == bv && i < bi)) { bv = v; bi = i; bs = 1; } }
      if (p2 < KNN) { float v = mv[p2 * 256 + tid * 4 + 2]; int i = mi[p2 * 256 + tid * 4 + 2];
        if (v > bv || (v == bv && i < bi)) { bv = v; bi = i; bs = 2; } }
      if (p3 < KNN) { float v = mv[p3 * 256 + tid * 4 + 3]; int i = mi[p3 * 256 + tid * 4 + 3];
        if (v > bv || (v == bv && i < bi)) { bv = v; bi = i; bs = 3; } }
      p0_ += (bs == 0); p1 += (bs == 1); p2 += (bs == 2); p3 += (bs == 3);
      opv[j] = bv; opi[j] = (unsigned short)bi;
    }
  }
}

// ---------------------------------------------------------------------------
// merge 4 sorted partial lists per query -> final top-20 indices.
// ---------------------------------------------------------------------------
__global__ __launch_bounds__(256) void knn_merge_kernel(const float* __restrict__ PARTV,
    const unsigned short* __restrict__ PARTI, int* __restrict__ idxOut) {
  const int idx = blockIdx.x * 256 + threadIdx.x;
  const float* pv = PARTV + (long)idx * 4 * KNN;
  const unsigned short* pi = PARTI + (long)idx * 4 * KNN;
  int p0 = 0, p1 = 0, p2 = 0, p3 = 0;
  int* op = idxOut + (long)idx * KNN;
  for (int j = 0; j < KNN; ++j) {
    float bv = -INFINITY; int bi = 0x7fffffff; int bs = 0;
    if (p0 < KNN) { float v = pv[0 * KNN + p0]; int i = pi[0 * KNN + p0];
      if (v > bv || (v == bv && i < bi)) { bv = v; bi = i; bs = 0; } }
    if (p1 < KNN) { float v = pv[1 * KNN + p1]; int i = pi[1 * KNN + p1];
      if (v > bv || (v == bv && i < bi)) { bv = v; bi = i; bs = 1; } }
    if (p2 < KNN) { float v = pv[2 * KNN + p2]; int i = pi[2 * KNN + p2];
      if (v > bv || (v == bv && i < bi)) { bv = v; bi = i; bs = 2; } }
    if (p3 < KNN) { float v = pv[3 * KNN + p3]; int i = pi[3 * KNN + p3];
      if (v > bv || (v == bv && i < bi)) { bv = v; bi = i; bs = 3; } }
    p0 += (bs == 0); p1 += (bs == 1); p2 += (bs == 2); p3 += (bs == 3);
    op[j] = bi;
  }
}

// ---------------------------------------------------------------------------
// gather + sum over k neighbors
// ---------------------------------------------------------------------------
__global__ __launch_bounds__(256) void gather_sum_kernel(const float* __restrict__ X,
    long batchStride, int C, const int* __restrict__ idx, float* __restrict__ agg) {
  __shared__ int sidx[256][KNN + 1];
  const int b   = blockIdx.y;
  const int n0  = blockIdx.x * 256;
  const int tid = threadIdx.x;
  const int* ib = idx + ((long)(b * NPTS + n0)) * KNN;
  for (int t = tid; t < 256 * KNN; t += 256) {
    sidx[t / KNN][t % KNN] = ib[t];
  }
  __syncthreads();
  const float* Xb = X + (long)b * batchStride;
  float* ab = agg + (long)b * C * NPTS;
  for (int c = 0; c < C; ++c) {
    const float* row = Xb + (long)c * NPTS;
    float s = 0.f;
    #pragma unroll
    for (int j = 0; j < KNN; ++j) s += row[sidx[tid][j]];
    ab[(long)c * NPTS + n0 + tid] = s;
  }
}

// ---------------------------------------------------------------------------
// fp32 conv (conv1-3: outputs feed knn, stay fp32)
// ---------------------------------------------------------------------------
__global__ __launch_bounds__(256) void conv_kernel(const float* __restrict__ Xin, long inBatchStride,
    const float* __restrict__ W, int C, int O,
    float* __restrict__ Yout, long outBatchStride, int outChanOffset) {
  __shared__ float Wt[32][68];
  __shared__ float Xt[32][68];
  const int b   = blockIdx.z;
  const int o0  = blockIdx.y * 64;
  const int n0  = blockIdx.x * 64;
  const int tid = threadIdx.x;
  const int ty  = tid >> 4, tx = tid & 15;
  const float* Xb = Xin + (long)b * inBatchStride;
  float acc[4][4] = {};
  for (int cc = 0; cc < C; cc += 32) {
    const int cw = min(32, C - cc);
    __syncthreads();
    for (int t = tid; t < 64 * 32; t += 256) {
      int oo = t >> 5, kk = t & 31;
      Wt[kk][oo] = (kk < cw) ? W[(long)(o0 + oo) * C + cc + kk] : 0.f;
    }
    for (int t = tid; t < 32 * 64; t += 256) {
      int kk = t >> 6, nn = t & 63;
      Xt[kk][nn] = (kk < cw) ? Xb[(long)(cc + kk) * NPTS + n0 + nn] : 0.f;
    }
    __syncthreads();
    #pragma unroll
    for (int kk = 0; kk < 32; ++kk) {
      const float4 wv = *(const float4*)&Wt[kk][ty * 4];
      const float4 xv = *(const float4*)&Xt[kk][tx * 4];
      acc[0][0] += wv.x * xv.x; acc[0][1] += wv.x * xv.y; acc[0][2] += wv.x * xv.z; acc[0][3] += wv.x * xv.w;
      acc[1][0] += wv.y * xv.x; acc[1][1] += wv.y * xv.y; acc[1][2] += wv.y * xv.z; acc[1][3] += wv.y * xv.w;
      acc[2][0] += wv.z * xv.x; acc[2][1] += wv.z * xv.y; acc[2][2] += wv.z * xv.z; acc[2][3] += wv.z * xv.w;
      acc[3][0] += wv.w * xv.x; acc[3][1] += wv.w * xv.y; acc[3][2] += wv.w * xv.z; acc[3][3] += wv.w * xv.w;
    }
  }
  #pragma unroll
  for (int i = 0; i < 4; ++i) {
    float4 v = make_float4(acc[i][0], acc[i][1], acc[i][2], acc[i][3]);
    *(float4*)&Yout[(long)b * outBatchStride + (long)(outChanOffset + o0 + ty * 4 + i) * NPTS + n0 + tx * 4] = v;
  }
}

// ---------------------------------------------------------------------------
// fp32 [b][C][1024] -> bf16 [b][1024][C] transpose (k-contiguous for MFMA B)
// ---------------------------------------------------------------------------
__global__ __launch_bounds__(256) void transpose_bf16_kernel(const float* __restrict__ in,
    long inBatchStride, int C, unsigned short* __restrict__ outT) {
  __shared__ float tile[64][65];
  const int b  = blockIdx.z;
  const int n0 = blockIdx.x * 64, c0 = blockIdx.y * 64;
  const int tid = threadIdx.x;
  const float* ib = in + (long)b * inBatchStride;
  for (int i = tid; i < 4096; i += 256) {
    int r = i >> 6, cn = i & 63;
    tile[r][cn] = ib[(long)(c0 + r) * NPTS + n0 + cn];
  }
  __syncthreads();
  unsigned short* ob = outT + (long)b * ((long)NPTS * C);
  for (int i = tid; i < 4096; i += 256) {
    int r = i >> 6, cc = i & 63;
    __hip_bfloat16 h = __float2bfloat16(tile[cc][r]);
    ob[(long)(n0 + r) * C + c0 + cc] = *(unsigned short*)&h;
  }
}

// ---------------------------------------------------------------------------
// fp32 -> bf16 elementwise (weights)
// ---------------------------------------------------------------------------
__global__ void convert_bf16_kernel(const float* __restrict__ in,
                                    unsigned short* __restrict__ out, int n) {
  int i = blockIdx.x * 256 + threadIdx.x;
  if (i < n) { __hip_bfloat16 h = __float2bfloat16(in[i]); out[i] = *(unsigned short*)&h; }
}

// ---------------------------------------------------------------------------
// bf16 MFMA conv (conv4/conv5: outputs never feed top-k)
// ---------------------------------------------------------------------------
__global__ __launch_bounds__(256) void conv_mfma_kernel(const unsigned short* __restrict__ Wbf,
    const unsigned short* __restrict__ XT, int C,
    float* __restrict__ Yout, long outBatchStride, int outChanOffset) {
  __shared__ unsigned short Wl[128][40];
  __shared__ unsigned short Xl[128][40];
  const int b  = blockIdx.z;
  const int o0 = blockIdx.y * 128;
  const int n0 = blockIdx.x * 128;
  const int tid  = threadIdx.x;
  const int lane = tid & 63, wid = tid >> 6;
  const int wo = (wid >> 1) * 64, wn = (wid & 1) * 64;
  const int l16 = lane & 15, quad = lane >> 4;
  const unsigned short* Wg = Wbf + (long)o0 * C;
  const unsigned short* Xg = XT + (long)b * ((long)NPTS * C) + (long)n0 * C;

  f32x4 acc[4][4];
  #pragma unroll
  for (int i = 0; i < 4; ++i)
    #pragma unroll
    for (int j = 0; j < 4; ++j) acc[i][j] = (f32x4){0.f, 0.f, 0.f, 0.f};

  for (int kk = 0; kk < C; kk += 32) {
    __syncthreads();
    #pragma unroll
    for (int it = 0; it < 2; ++it) {
      const int id = tid + it * 256;
      const int r = id >> 2, qq = id & 3;
      const float4 va = *(const float4*)&Wg[(long)r * C + kk + qq * 8];
      const float4 vb = *(const float4*)&Xg[(long)r * C + kk + qq * 8];
      *(float4*)&Wl[r][qq * 8] = va;
      *(float4*)&Xl[r][qq * 8] = vb;
    }
    __syncthreads();
    short8 af[4], bfr[4];
    #pragma unroll
    for (int i = 0; i < 4; ++i) af[i]  = *(const short8*)&Wl[wo + i * 16 + l16][quad * 8];
    #pragma unroll
    for (int j = 0; j < 4; ++j) bfr[j] = *(const short8*)&Xl[wn + j * 16 + l16][quad * 8];
    #pragma unroll
    for (int i = 0; i < 4; ++i)
      #pragma unroll
      for (int j = 0; j < 4; ++j)
        acc[i][j] = __builtin_amdgcn_mfma_f32_16x16x32_bf16(af[i], bfr[j], acc[i][j], 0, 0, 0);
  }

  float* Yb = Yout + (long)b * outBatchStride + (long)outChanOffset * NPTS;
  #pragma unroll
  for (int i = 0; i < 4; ++i) {
    #pragma unroll
    for (int r = 0; r < 4; ++r) {
      const int o = o0 + wo + i * 16 + quad * 4 + r;
      float* row = Yb + (long)o * NPTS + n0 + wn;
      #pragma unroll
      for (int j = 0; j < 4; ++j) row[j * 16 + l16] = acc[i][j][r];
    }
  }
}

// ---------------------------------------------------------------------------
// BN stats / apply / pool
// ---------------------------------------------------------------------------
__global__ __launch_bounds__(256) void bn_stats_kernel(const float* __restrict__ Y, long batchStride,
    int chanOffset, float* __restrict__ meanOut, float* __restrict__ rstdOut) {
  const int o   = blockIdx.x;
  const int tid = threadIdx.x;
  const float* base = Y + (long)(chanOffset + o) * NPTS;
  float s = 0.f, s2 = 0.f;
  for (int b = 0; b < BATCH; ++b) {
    const float* p = base + (long)b * batchStride;
    for (int t = tid; t < NPTS; t += 256) { float v = p[t]; s += v; s2 += v * v; }
  }
  for (int off = 32; off > 0; off >>= 1) { s += __shfl_down(s, off); s2 += __shfl_down(s2, off); }
  __shared__ float r1[4], r2[4];
  const int wid = tid >> 6;
  if ((tid & 63) == 0) { r1[wid] = s; r2[wid] = s2; }
  __syncthreads();
  if (tid == 0) {
    s  = r1[0] + r1[1] + r1[2] + r1[3];
    s2 = r2[0] + r2[1] + r2[2] + r2[3];
    float m   = s * (1.f / 16384.f);
    float var = s2 * (1.f / 16384.f) - m * m;
    meanOut[o] = m;
    rstdOut[o] = rsqrtf(var + 1e-5f);
  }
}

__global__ __launch_bounds__(256) void bn_apply_kernel(float* __restrict__ Y, long batchStride, int chanOffset,
    const float* __restrict__ meanB, const float* __restrict__ rstdB,
    const float* __restrict__ g, const float* __restrict__ beta) {
  const int n = blockIdx.x * 256 + threadIdx.x;
  const int o = blockIdx.y;
  const int b = blockIdx.z;
  float* p = Y + (long)b * batchStride + (long)(chanOffset + o) * NPTS;
  const float sc = rstdB[o] * g[o];
  float v = (p[n] - meanB[o]) * sc + beta[o];
  p[n] = (v > 0.f) ? v : 0.2f * v;
}

__global__ __launch_bounds__(256) void bn_pool_kernel(const float* __restrict__ H,
    const float* __restrict__ meanB, const float* __restrict__ rstdB,
    const float* __restrict__ g, const float* __restrict__ beta,
    float* __restrict__ Z) {
  const int o   = blockIdx.x;
  const int b   = blockIdx.y;
  const int tid = threadIdx.x;
  const float* p = H + (long)b * (1024L * NPTS) + (long)o * NPTS;
  const float sc = rstdB[o] * g[o], mu = meanB[o], bb = beta[o];
  float mx = -INFINITY, s = 0.f;
  for (int t = tid; t < NPTS; t += 256) {
    float v = (p[t] - mu) * sc + bb;
    v = (v > 0.f) ? v : 0.2f * v;
    mx = fmaxf(mx, v);
    s += v;
  }
  for (int off = 32; off > 0; off >>= 1) { mx = fmaxf(mx, __shfl_down(mx, off)); s += __shfl_down(s, off); }
  __shared__ float rm[4], rs[4];
  const int wid = tid >> 6;
  if ((tid & 63) == 0) { rm[wid] = mx; rs[wid] = s; }
  __syncthreads();
  if (tid == 0) {
    mx = fmaxf(fmaxf(rm[0], rm[1]), fmaxf(rm[2], rm[3]));
    s  = rs[0] + rs[1] + rs[2] + rs[3];
    Z[(long)b * 2048 + o]        = mx;
    Z[(long)b * 2048 + 1024 + o] = s * (1.f / 1024.f);
  }
}

// ---------------------------------------------------------------------------
// FC v2: one WAVE per output channel o, all 16 batches per wave.
// W row reads coalesced (lane strides c by 64); in[] rows are L2-resident.
// 16 accumulators/lane -> 16 butterfly reductions -> lane 0 writes 16 outs.
// ---------------------------------------------------------------------------
__global__ __launch_bounds__(256) void fc_wave_kernel(const float* __restrict__ in,
    const float* __restrict__ Wm, const float* __restrict__ bias,
    float* __restrict__ out, int Cin, int Oout) {
  const int wid  = threadIdx.x >> 6;
  const int lane = threadIdx.x & 63;
  const int o = blockIdx.x * 4 + wid;
  if (o >= Oout) return;
  const float* wp = Wm + (long)o * Cin;
  float acc[BATCH];
  #pragma unroll
  for (int b = 0; b < BATCH; ++b) acc[b] = 0.f;
  for (int c = lane; c < Cin; c += 64) {
    const float w = wp[c];
    #pragma unroll
    for (int b = 0; b < BATCH; ++b) acc[b] += w * in[b * Cin + c];
  }
  #pragma unroll
  for (int b = 0; b < BATCH; ++b) {
    #pragma unroll
    for (int off = 32; off > 0; off >>= 1) acc[b] += __shfl_down(acc[b], off);
  }
  if (lane == 0) {
    const float bs = bias ? bias[o] : 0.f;
    #pragma unroll
    for (int b = 0; b < BATCH; ++b) out[b * Oout + o] = acc[b] + bs;
  }
}

__global__ void bn_small_kernel(float* __restrict__ buf, const float* __restrict__ g,
    const float* __restrict__ beta, int O) {
  const int o = blockIdx.x * 256 + threadIdx.x;
  if (o >= O) return;
  float s = 0.f, s2 = 0.f;
  for (int b = 0; b < BATCH; ++b) { float v = buf[b * O + o]; s += v; s2 += v * v; }
  const float m   = s * (1.f / 16.f);
  const float var = s2 * (1.f / 16.f) - m * m;
  const float sc  = rsqrtf(var + 1e-5f) * g[o];
  const float bb  = beta[o];
  for (int b = 0; b < BATCH; ++b) {
    float v = (buf[b * O + o] - m) * sc + bb;
    buf[b * O + o] = (v > 0.f) ? v : 0.2f * v;
  }
}

extern "C" void kernel_launch(void* const* d_in, const int* in_sizes, int n_in,
                              void* d_out, int out_size, void* d_ws, size_t ws_size,
                              hipStream_t stream) {
  const float* x   = (const float*)d_in[0];
  const float* W1  = (const float*)d_in[1];
  const float* g1  = (const float*)d_in[2];
  const float* b1  = (const float*)d_in[3];
  const float* W2  = (const float*)d_in[4];
  const float* g2  = (const float*)d_in[5];
  const float* b2  = (const float*)d_in[6];
  const float* W3  = (const float*)d_in[7];
  const float* g3  = (const float*)d_in[8];
  const float* b3  = (const float*)d_in[9];
  const float* W4  = (const float*)d_in[10];
  const float* g4  = (const float*)d_in[11];
  const float* b4  = (const float*)d_in[12];
  const float* W5  = (const float*)d_in[13];
  const float* g5  = (const float*)d_in[14];
  const float* b5  = (const float*)d_in[15];
  const float* l1W = (const float*)d_in[16];
  const float* g6  = (const float*)d_in[17];
  const float* b6  = (const float*)d_in[18];
  const float* l2W = (const float*)d_in[19];
  const float* l2b = (const float*)d_in[20];
  const float* g7  = (const float*)d_in[21];
  const float* b7  = (const float*)d_in[22];
  const float* l3W = (const float*)d_in[23];
  const float* l3b = (const float*)d_in[24];

  float* ws   = (float*)d_ws;
  float* Xcat = ws;                        // (B,512,N)
  float* H    = Xcat + 8388608;            // (B,1024,N) (layer-5 only)
  float* REG  = H + 16777216;              // overlaid scratch
  float* AGG  = REG;
  unsigned short* AGGT = (unsigned short*)(REG + 2097152);
  unsigned short* XbfT = (unsigned short*)REG;
  int*   IDX  = (int*)(REG + 4194304);
  float* MEAN = (float*)(IDX + 327680);
  float* RSTD = MEAN + 1024;
  float* Z    = RSTD + 1024;
  float* Z1   = Z + 32768;
  float* Z2   = Z1 + 8192;
  unsigned short* W4bf = (unsigned short*)(Z2 + 4096);
  unsigned short* W5bf = W4bf + 32768;

  // knn scratch overlays H (dead until layer 5)
  float* SQ    = H;
  float* PARTV = H + 16384;
  unsigned short* PARTI = (unsigned short*)(PARTV + 1310720);

  const long XS = 512L * 1024;
  const long HS = 1024L * 1024;
  const dim3 knnGrid(16, 4, 16);

  // ---- edge block 1 (C=3) ----
  compute_sq_kernel<<<dim3(4, 16), 256, 0, stream>>>(x, 3L * 1024, 3, SQ);
  knn_kernel<3><<<knnGrid, 256, 0, stream>>>(x, 3L * 1024, SQ, PARTV, PARTI);
  knn_merge_kernel<<<64, 256, 0, stream>>>(PARTV, PARTI, IDX);
  gather_sum_kernel<<<dim3(4, 16), 256, 0, stream>>>(x, 3L * 1024, 3, IDX, AGG);
  conv_kernel<<<dim3(16, 1, 16), 256, 0, stream>>>(AGG, 3L * 1024, W1, 3, 64, Xcat, XS, 0);
  bn_stats_kernel<<<64, 256, 0, stream>>>(Xcat, XS, 0, MEAN, RSTD);
  bn_apply_kernel<<<dim3(4, 64, 16), 256, 0, stream>>>(Xcat, XS, 0, MEAN, RSTD, g1, b1);

  // ---- edge block 2 (C=64) ----
  compute_sq_kernel<<<dim3(4, 16), 256, 0, stream>>>(Xcat, XS, 64, SQ);
  knn_kernel<64><<<knnGrid, 256, 0, stream>>>(Xcat, XS, SQ, PARTV, PARTI);
  knn_merge_kernel<<<64, 256, 0, stream>>>(PARTV, PARTI, IDX);
  gather_sum_kernel<<<dim3(4, 16), 256, 0, stream>>>(Xcat, XS, 64, IDX, AGG);
  conv_kernel<<<dim3(16, 1, 16), 256, 0, stream>>>(AGG, 64L * 1024, W2, 64, 64, Xcat, XS, 64);
  bn_stats_kernel<<<64, 256, 0, stream>>>(Xcat, XS, 64, MEAN, RSTD);
  bn_apply_kernel<<<dim3(4, 64, 16), 256, 0, stream>>>(Xcat, XS, 64, MEAN, RSTD, g2, b2);

  // ---- edge block 3 (C=64 -> O=128) ----
  compute_sq_kernel<<<dim3(4, 16), 256, 0, stream>>>(Xcat + 64L * 1024, XS, 64, SQ);
  knn_kernel<64><<<knnGrid, 256, 0, stream>>>(Xcat + 64L * 1024, XS, SQ, PARTV, PARTI);
  knn_merge_kernel<<<64, 256, 0, stream>>>(PARTV, PARTI, IDX);
  gather_sum_kernel<<<dim3(4, 16), 256, 0, stream>>>(Xcat + 64L * 1024, XS, 64, IDX, AGG);
  conv_kernel<<<dim3(16, 2, 16), 256, 0, stream>>>(AGG, 64L * 1024, W3, 64, 128, Xcat, XS, 128);
  bn_stats_kernel<<<128, 256, 0, stream>>>(Xcat, XS, 128, MEAN, RSTD);
  bn_apply_kernel<<<dim3(4, 128, 16), 256, 0, stream>>>(Xcat, XS, 128, MEAN, RSTD, g3, b3);

  // ---- edge block 4 (C=128 -> O=256, bf16 MFMA conv) ----
  compute_sq_kernel<<<dim3(4, 16), 256, 0, stream>>>(Xcat + 128L * 1024, XS, 128, SQ);
  knn_kernel<128><<<knnGrid, 256, 0, stream>>>(Xcat + 128L * 1024, XS, SQ, PARTV, PARTI);
  knn_merge_kernel<<<64, 256, 0, stream>>>(PARTV, PARTI, IDX);
  gather_sum_kernel<<<dim3(4, 16), 256, 0, stream>>>(Xcat + 128L * 1024, XS, 128, IDX, AGG);
  convert_bf16_kernel<<<128, 256, 0, stream>>>(W4, W4bf, 256 * 128);
  transpose_bf16_kernel<<<dim3(16, 2, 16), 256, 0, stream>>>(AGG, 128L * 1024, 128, AGGT);
  conv_mfma_kernel<<<dim3(8, 2, 16), 256, 0, stream>>>(W4bf, AGGT, 128, Xcat, XS, 256);
  bn_stats_kernel<<<256, 256, 0, stream>>>(Xcat, XS, 256, MEAN, RSTD);
  bn_apply_kernel<<<dim3(4, 256, 16), 256, 0, stream>>>(Xcat, XS, 256, MEAN, RSTD, g4, b4);

  // ---- layer 5 (bf16 MFMA; overwrites H only after knn scratch is dead) ----
  convert_bf16_kernel<<<2048, 256, 0, stream>>>(W5, W5bf, 1024 * 512);
  transpose_bf16_kernel<<<dim3(16, 8, 16), 256, 0, stream>>>(Xcat, XS, 512, XbfT);
  conv_mfma_kernel<<<dim3(8, 8, 16), 256, 0, stream>>>(W5bf, XbfT, 512, H, HS, 0);
  bn_stats_kernel<<<1024, 256, 0, stream>>>(H, HS, 0, MEAN, RSTD);
  bn_pool_kernel<<<dim3(1024, 16), 256, 0, stream>>>(H, MEAN, RSTD, g5, b5, Z);

  // ---- MLP head (wave-per-output FC) ----
  fc_wave_kernel<<<128, 256, 0, stream>>>(Z, l1W, nullptr, Z1, 2048, 512);
  bn_small_kernel<<<2, 256, 0, stream>>>(Z1, g6, b6, 512);
  fc_wave_kernel<<<64, 256, 0, stream>>>(Z1, l2W, l2b, Z2, 512, 256);
  bn_small_kernel<<<1, 256, 0, stream>>>(Z2, g7, b7, 256);
  fc_wave_kernel<<<10, 256, 0, stream>>>(Z2, l3W, l3b, (float*)d_out, 256, 40);
}

// Round 7
// 1297.111 us; speedup vs baseline: 3.5462x; 1.0603x over previous
//
#include <hip/hip_runtime.h>
#include <hip/hip_bf16.h>
#include <math.h>

#define NPTS 1024
#define BATCH 16
#define KNN 20

typedef __attribute__((ext_vector_type(8))) short short8;
typedef __attribute__((ext_vector_type(4))) float f32x4;

// ---------------------------------------------------------------------------
// per-point squared norms: sq[b][m] = sum_c X[b,c,m]^2  (fp32, exact-ish)
// ---------------------------------------------------------------------------
__global__ __launch_bounds__(256) void compute_sq_kernel(const float* __restrict__ X,
    long batchStride, int C, float* __restrict__ sq) {
  const int b = blockIdx.y;
  const int m = blockIdx.x * 256 + threadIdx.x;
  const float* Xb = X + (long)b * batchStride;
  float s = 0.f;
  for (int c = 0; c < C; ++c) { float v = Xb[(long)c * NPTS + m]; s += v * v; }
  sq[b * NPTS + m] = s;
}

// ---------------------------------------------------------------------------
// fp32 [b][C][1024] -> three bf16 planes [b][1024][C]: x = hi + mid + lo
// (each residual subtraction exact in fp32; dropped remainder ~2^-27 |x|).
// k-contiguous rows for MFMA fragments.
// ---------------------------------------------------------------------------
__global__ __launch_bounds__(256) void transpose_split_kernel(const float* __restrict__ in,
    long inBatchStride, int C, unsigned short* __restrict__ XH,
    unsigned short* __restrict__ XM, unsigned short* __restrict__ XL) {
  __shared__ float tile[64][65];
  const int b  = blockIdx.z;
  const int n0 = blockIdx.x * 64, c0 = blockIdx.y * 64;
  const int tid = threadIdx.x;
  const float* ib = in + (long)b * inBatchStride;
  for (int i = tid; i < 4096; i += 256) {
    int r = i >> 6, cn = i & 63;
    tile[r][cn] = ib[(long)(c0 + r) * NPTS + n0 + cn];
  }
  __syncthreads();
  const long pb = (long)b * ((long)NPTS * C);
  for (int i = tid; i < 4096; i += 256) {
    int r = i >> 6, cc = i & 63;
    float f = tile[cc][r];
    __hip_bfloat16 h = __float2bfloat16(f);
    float r1 = f - __bfloat162float(h);
    __hip_bfloat16 m = __float2bfloat16(r1);
    float r2 = r1 - __bfloat162float(m);
    __hip_bfloat16 l = __float2bfloat16(r2);
    const long o = pb + (long)(n0 + r) * C + c0 + cc;
    XH[o] = *(unsigned short*)&h;
    XM[o] = *(unsigned short*)&m;
    XL[o] = *(unsigned short*)&l;
  }
}

// ---------------------------------------------------------------------------
// knn via split-bf16 MFMA (C=64/128): block = (64 queries, 256-cand chunk, b).
// inner = hh+hm+mh+mm+hl+lh (6 MFMA passes, fp32 acc) -> err ~1e-7 (below the
// fp32 GEMM's own deviation vs reference -> identical top-k behavior).
// Selection: register top-20, predicated carry-insert, 4 threads/query.
// ---------------------------------------------------------------------------
template<int C>
__global__ __launch_bounds__(256) void knn_mfma_kernel(
    const unsigned short* __restrict__ XH, const unsigned short* __restrict__ XM,
    const unsigned short* __restrict__ XL, const float* __restrict__ sqg,
    float* __restrict__ PARTV, unsigned short* __restrict__ PARTI) {
  __shared__ __align__(16) unsigned short QP[6][64][40];  // 30720 B: Q hi/mid/lo, P hi/mid/lo
  __shared__ __align__(16) float Dbuf[64][68];            // 17408 B
  __shared__ float sqs[256];
  float* region = (float*)&QP[0][0][0];                   // merge lists overlay (30720 B)

  const int b     = blockIdx.z;
  const int q0    = blockIdx.x * 64;
  const int p0    = blockIdx.y * 256;
  const int chunk = blockIdx.y;
  const int tid  = threadIdx.x;
  const int lane = tid & 63, w = tid >> 6;
  const int l16  = lane & 15, quad = lane >> 4;
  const int q = lane, sub = w;

  const long plane = (long)b * ((long)NPTS * C);
  const unsigned short* XHb = XH + plane;
  const unsigned short* XMb = XM + plane;
  const unsigned short* XLb = XL + plane;

  sqs[tid] = sqg[b * NPTS + p0 + tid];

  float topv[KNN];
  int   topi[KNN];
  #pragma unroll
  for (int j = 0; j < KNN; ++j) { topv[j] = -INFINITY; topi[j] = 0x7fffffff; }
  float vmin = -INFINITY;

  const int srow = tid >> 2, sseg = (tid & 3) * 8;

  for (int pc = 0; pc < 256; pc += 64) {
    f32x4 acc[4];
    #pragma unroll
    for (int t = 0; t < 4; ++t) acc[t] = (f32x4){0.f, 0.f, 0.f, 0.f};

    for (int kc = 0; kc < C; kc += 32) {
      __syncthreads();   // QP free (prev selection/staging done)
      const long qo = (long)(q0 + srow) * C + kc + sseg;
      const long po = (long)(p0 + pc + srow) * C + kc + sseg;
      *(float4*)&QP[0][srow][sseg] = *(const float4*)&XHb[qo];
      *(float4*)&QP[1][srow][sseg] = *(const float4*)&XMb[qo];
      *(float4*)&QP[2][srow][sseg] = *(const float4*)&XLb[qo];
      *(float4*)&QP[3][srow][sseg] = *(const float4*)&XHb[po];
      *(float4*)&QP[4][srow][sseg] = *(const float4*)&XMb[po];
      *(float4*)&QP[5][srow][sseg] = *(const float4*)&XLb[po];
      __syncthreads();
      const short8 ph = *(const short8*)&QP[3][w * 16 + l16][quad * 8];
      const short8 pm = *(const short8*)&QP[4][w * 16 + l16][quad * 8];
      const short8 pl = *(const short8*)&QP[5][w * 16 + l16][quad * 8];
      #pragma unroll
      for (int t = 0; t < 4; ++t) {
        const short8 qh = *(const short8*)&QP[0][t * 16 + l16][quad * 8];
        const short8 qm = *(const short8*)&QP[1][t * 16 + l16][quad * 8];
        const short8 ql = *(const short8*)&QP[2][t * 16 + l16][quad * 8];
        acc[t] = __builtin_amdgcn_mfma_f32_16x16x32_bf16(ph, qh, acc[t], 0, 0, 0);
        acc[t] = __builtin_amdgcn_mfma_f32_16x16x32_bf16(ph, qm, acc[t], 0, 0, 0);
        acc[t] = __builtin_amdgcn_mfma_f32_16x16x32_bf16(pm, qh, acc[t], 0, 0, 0);
        acc[t] = __builtin_amdgcn_mfma_f32_16x16x32_bf16(pm, qm, acc[t], 0, 0, 0);
        acc[t] = __builtin_amdgcn_mfma_f32_16x16x32_bf16(ph, ql, acc[t], 0, 0, 0);
        acc[t] = __builtin_amdgcn_mfma_f32_16x16x32_bf16(pl, qh, acc[t], 0, 0, 0);
      }
    }
    // D[p][q]: wave w owns p rows [w*16, w*16+16); q = col = lane&15 per tile
    #pragma unroll
    for (int t = 0; t < 4; ++t)
      #pragma unroll
      for (int r = 0; r < 4; ++r)
        Dbuf[w * 16 + quad * 4 + r][t * 16 + l16] = acc[t][r];
    __syncthreads();

    // selection: thread (q, sub) scans rows [sub*16, sub*16+16)
    #pragma unroll 4
    for (int i = 0; i < 16; ++i) {
      const float v = fmaf(2.f, Dbuf[sub * 16 + i][q], -sqs[pc + sub * 16 + i]);
      if (v > vmin) {
        float cv = v; int ci = p0 + pc + sub * 16 + i;
        bool ins = false;
        #pragma unroll
        for (int j = 0; j < KNN; ++j) {
          const float tv = topv[j]; const int ti = topi[j];
          const bool gt = ins || (cv > tv);
          topv[j] = gt ? cv : tv;
          topi[j] = gt ? ci : ti;
          cv = gt ? tv : cv;
          ci = gt ? ti : ci;
          ins = gt;
        }
        vmin = topv[KNN - 1];
      }
    }
  }

  // in-block 4-way merge -> sorted partial top-20 for this chunk
  __syncthreads();
  {
    float* mv = region;
    unsigned short* mi = (unsigned short*)(region + 5120);
    const int slot = q * 4 + sub;
    #pragma unroll
    for (int j = 0; j < KNN; ++j) { mv[j * 256 + slot] = topv[j]; mi[j * 256 + slot] = (unsigned short)topi[j]; }
  }
  __syncthreads();
  if (tid < 64) {
    const float* mv = region;
    const unsigned short* mi = (const unsigned short*)(region + 5120);
    int p0_ = 0, p1 = 0, p2 = 0, p3 = 0;
    float* opv = PARTV + (((long)(b * NPTS + q0 + tid)) * 4 + chunk) * KNN;
    unsigned short* opi = PARTI + (((long)(b * NPTS + q0 + tid)) * 4 + chunk) * KNN;
    for (int j = 0; j < KNN; ++j) {
      float bv = -INFINITY; int bi = 0x7fffffff; int bs = 0;
      if (p0_ < KNN) { float v = mv[p0_ * 256 + tid * 4 + 0]; int i = mi[p0_ * 256 + tid * 4 + 0];
        if (v > bv || (v == bv && i < bi)) { bv = v; bi = i; bs = 0; } }
      if (p1 < KNN) { float v = mv[p1 * 256 + tid * 4 + 1]; int i = mi[p1 * 256 + tid * 4 + 1];
        if (v > bv || (v == bv && i < bi)) { bv = v; bi = i; bs = 1; } }
      if (p2 < KNN) { float v = mv[p2 * 256 + tid * 4 + 2]; int i = mi[p2 * 256 + tid * 4 + 2];
        if (v > bv || (v == bv && i < bi)) { bv = v; bi = i; bs = 2; } }
      if (p3 < KNN) { float v = mv[p3 * 256 + tid * 4 + 3]; int i = mi[p3 * 256 + tid * 4 + 3];
        if (v > bv || (v == bv && i < bi)) { bv = v; bi = i; bs = 3; } }
      p0_ += (bs == 0); p1 += (bs == 1); p2 += (bs == 2); p3 += (bs == 3);
      opv[j] = bv; opi[j] = (unsigned short)bi;
    }
  }
}

// ---------------------------------------------------------------------------
// fp32 knn (C=3 only: tiny GEMM, tight 3D distance gaps -> keep exact fp32)
// ---------------------------------------------------------------------------
template<int C>
__global__ __launch_bounds__(256) void knn_kernel(const float* __restrict__ X,
    long batchStride, const float* __restrict__ sqg,
    float* __restrict__ PARTV, unsigned short* __restrict__ PARTI) {
  constexpr int CT = (C < 64) ? C : 64;
  constexpr int REGF = (2 * CT * 64 > 7680) ? 2 * CT * 64 : 7680;
  __shared__ float Dbuf[64][68];
  __shared__ float region[REGF];

  float* qbuf = region;
  float* pbuf = region + CT * 64;

  const int b     = blockIdx.z;
  const int q0    = blockIdx.x * 64;
  const int p0    = blockIdx.y * 256;
  const int chunk = blockIdx.y;
  const int tid = threadIdx.x;
  const int ty  = tid >> 4, tx = tid & 15;
  const int q   = tid & 63;
  const int sub = tid >> 6;
  const float* Xb = X + (long)b * batchStride;
  const float* sqb = sqg + b * NPTS;

  float topv[KNN];
  int   topi[KNN];
  #pragma unroll
  for (int j = 0; j < KNN; ++j) { topv[j] = -INFINITY; topi[j] = 0x7fffffff; }
  float vmin = -INFINITY;

  for (int pc = p0; pc < p0 + 256; pc += 64) {
    float acc[4][4] = {};
    for (int cc = 0; cc < C; cc += CT) {
      __syncthreads();
      for (int t = tid; t < 64 * CT; t += 256) {
        int c = t >> 6, m = t & 63;
        qbuf[c * 64 + m] = Xb[(long)(cc + c) * NPTS + q0 + m];
        pbuf[c * 64 + m] = Xb[(long)(cc + c) * NPTS + pc + m];
      }
      __syncthreads();
      #pragma unroll
      for (int c = 0; c < CT; ++c) {
        const float4 qv = *(const float4*)&qbuf[c * 64 + ty * 4];
        const float4 pv = *(const float4*)&pbuf[c * 64 + tx * 4];
        acc[0][0] += qv.x * pv.x; acc[0][1] += qv.x * pv.y; acc[0][2] += qv.x * pv.z; acc[0][3] += qv.x * pv.w;
        acc[1][0] += qv.y * pv.x; acc[1][1] += qv.y * pv.y; acc[1][2] += qv.y * pv.z; acc[1][3] += qv.y * pv.w;
        acc[2][0] += qv.z * pv.x; acc[2][1] += qv.z * pv.y; acc[2][2] += qv.z * pv.z; acc[2][3] += qv.z * pv.w;
        acc[3][0] += qv.w * pv.x; acc[3][1] += qv.w * pv.y; acc[3][2] += qv.w * pv.z; acc[3][3] += qv.w * pv.w;
      }
    }
    #pragma unroll
    for (int j = 0; j < 4; ++j) {
      const int p = pc + tx * 4 + j;
      const float sq = sqb[p];
      float4 dv;
      dv.x = 2.f * acc[0][j] - sq;
      dv.y = 2.f * acc[1][j] - sq;
      dv.z = 2.f * acc[2][j] - sq;
      dv.w = 2.f * acc[3][j] - sq;
      *(float4*)&Dbuf[tx * 4 + j][ty * 4] = dv;
    }
    __syncthreads();

    #pragma unroll 4
    for (int i = 0; i < 16; ++i) {
      const float v = Dbuf[sub * 16 + i][q];
      if (v > vmin) {
        float cv = v; int ci = pc + sub * 16 + i;
        bool ins = false;
        #pragma unroll
        for (int j = 0; j < KNN; ++j) {
          const float tv = topv[j]; const int ti = topi[j];
          const bool gt = ins || (cv > tv);
          topv[j] = gt ? cv : tv;
          topi[j] = gt ? ci : ti;
          cv = gt ? tv : cv;
          ci = gt ? ti : ci;
          ins = gt;
        }
        vmin = topv[KNN - 1];
      }
    }
  }

  __syncthreads();
  {
    float* mv = region;
    unsigned short* mi = (unsigned short*)(region + 5120);
    const int slot = q * 4 + sub;
    #pragma unroll
    for (int j = 0; j < KNN; ++j) { mv[j * 256 + slot] = topv[j]; mi[j * 256 + slot] = (unsigned short)topi[j]; }
  }
  __syncthreads();
  if (tid < 64) {
    const float* mv = region;
    const unsigned short* mi = (const unsigned short*)(region + 5120);
    int p0_ = 0, p1 = 0, p2 = 0, p3 = 0;
    float* opv = PARTV + (((long)(b * NPTS + q0 + tid)) * 4 + chunk) * KNN;
    unsigned short* opi = PARTI + (((long)(b * NPTS + q0 + tid)) * 4 + chunk) * KNN;
    for (int j = 0; j < KNN; ++j) {
      float bv = -INFINITY; int bi = 0x7fffffff; int bs = 0;
      if (p0_ < KNN) { float v = mv[p0_ * 256 + tid * 4 + 0]; int i = mi[p0_ * 256 + tid * 4 + 0];
        if (v > bv || (v == bv && i < bi)) { bv = v; bi = i; bs = 0; } }
      if (p1 < KNN) { float v = mv[p1 * 256 + tid * 4 + 1]; int i = mi[p1 * 256 + tid * 4 + 1];
        if (v > bv || (v == bv && i < bi)) { bv = v; bi = i; bs = 1; } }
      if (p2 < KNN) { float v = mv[p2 * 256 + tid * 4 + 2]; int i = mi[p2 * 256 + tid * 4 + 2];
        if (v > bv || (v == bv && i < bi)) { bv = v; bi = i; bs = 2; } }
      if (p3 < KNN) { float v = mv[p3 * 256 + tid * 4 + 3]; int i = mi[p3 * 256 + tid * 4 + 3];
        if (v > bv || (v == bv && i < bi)) { bv = v; bi = i; bs = 3; } }
      p0_ += (bs == 0); p1 += (bs == 1); p2 += (bs == 2); p3 += (bs == 3);
      opv[j] = bv; opi[j] = (unsigned short)bi;
    }
  }
}

// ---------------------------------------------------------------------------
// merge 4 sorted partial lists per query -> final top-20 indices.
// ---------------------------------------------------------------------------
__global__ __launch_bounds__(256) void knn_merge_kernel(const float* __restrict__ PARTV,
    const unsigned short* __restrict__ PARTI, int* __restrict__ idxOut) {
  const int idx = blockIdx.x * 256 + threadIdx.x;
  const float* pv = PARTV + (long)idx * 4 * KNN;
  const unsigned short* pi = PARTI + (long)idx * 4 * KNN;
  int p0 = 0, p1 = 0, p2 = 0, p3 = 0;
  int* op = idxOut + (long)idx * KNN;
  for (int j = 0; j < KNN; ++j) {
    float bv = -INFINITY; int bi = 0x7fffffff; int bs = 0;
    if (p0 < KNN) { float v = pv[0 * KNN + p0]; int i = pi[0 * KNN + p0];
      if (v > bv || (v == bv && i < bi)) { bv = v; bi = i; bs = 0; } }
    if (p1 < KNN) { float v = pv[1 * KNN + p1]; int i = pi[1 * KNN + p1];
      if (v > bv || (v == bv && i < bi)) { bv = v; bi = i; bs = 1; } }
    if (p2 < KNN) { float v = pv[2 * KNN + p2]; int i = pi[2 * KNN + p2];
      if (v > bv || (v == bv && i < bi)) { bv = v; bi = i; bs = 2; } }
    if (p3 < KNN) { float v = pv[3 * KNN + p3]; int i = pi[3 * KNN + p3];
      if (v > bv || (v == bv && i < bi)) { bv = v; bi = i; bs = 3; } }
    p0 += (bs == 0); p1 += (bs == 1); p2 += (bs == 2); p3 += (bs == 3);
    op[j] = bi;
  }
}

// ---------------------------------------------------------------------------
// gather + sum over k neighbors
// ---------------------------------------------------------------------------
__global__ __launch_bounds__(256) void gather_sum_kernel(const float* __restrict__ X,
    long batchStride, int C, const int* __restrict__ idx, float* __restrict__ agg) {
  __shared__ int sidx[256][KNN + 1];
  const int b   = blockIdx.y;
  const int n0  = blockIdx.x * 256;
  const int tid = threadIdx.x;
  const int* ib = idx + ((long)(b * NPTS + n0)) * KNN;
  for (int t = tid; t < 256 * KNN; t += 256) {
    sidx[t / KNN][t % KNN] = ib[t];
  }
  __syncthreads();
  const float* Xb = X + (long)b * batchStride;
  float* ab = agg + (long)b * C * NPTS;
  for (int c = 0; c < C; ++c) {
    const float* row = Xb + (long)c * NPTS;
    float s = 0.f;
    #pragma unroll
    for (int j = 0; j < KNN; ++j) s += row[sidx[tid][j]];
    ab[(long)c * NPTS + n0 + tid] = s;
  }
}

// ---------------------------------------------------------------------------
// fp32 conv (conv1-3: outputs feed knn, stay fp32)
// ---------------------------------------------------------------------------
__global__ __launch_bounds__(256) void conv_kernel(const float* __restrict__ Xin, long inBatchStride,
    const float* __restrict__ W, int C, int O,
    float* __restrict__ Yout, long outBatchStride, int outChanOffset) {
  __shared__ float Wt[32][68];
  __shared__ float Xt[32][68];
  const int b   = blockIdx.z;
  const int o0  = blockIdx.y * 64;
  const int n0  = blockIdx.x * 64;
  const int tid = threadIdx.x;
  const int ty  = tid >> 4, tx = tid & 15;
  const float* Xb = Xin + (long)b * inBatchStride;
  float acc[4][4] = {};
  for (int cc = 0; cc < C; cc += 32) {
    const int cw = min(32, C - cc);
    __syncthreads();
    for (int t = tid; t < 64 * 32; t += 256) {
      int oo = t >> 5, kk = t & 31;
      Wt[kk][oo] = (kk < cw) ? W[(long)(o0 + oo) * C + cc + kk] : 0.f;
    }
    for (int t = tid; t < 32 * 64; t += 256) {
      int kk = t >> 6, nn = t & 63;
      Xt[kk][nn] = (kk < cw) ? Xb[(long)(cc + kk) * NPTS + n0 + nn] : 0.f;
    }
    __syncthreads();
    #pragma unroll
    for (int kk = 0; kk < 32; ++kk) {
      const float4 wv = *(const float4*)&Wt[kk][ty * 4];
      const float4 xv = *(const float4*)&Xt[kk][tx * 4];
      acc[0][0] += wv.x * xv.x; acc[0][1] += wv.x * xv.y; acc[0][2] += wv.x * xv.z; acc[0][3] += wv.x * xv.w;
      acc[1][0] += wv.y * xv.x; acc[1][1] += wv.y * xv.y; acc[1][2] += wv.y * xv.z; acc[1][3] += wv.y * xv.w;
      acc[2][0] += wv.z * xv.x; acc[2][1] += wv.z * xv.y; acc[2][2] += wv.z * xv.z; acc[2][3] += wv.z * xv.w;
      acc[3][0] += wv.w * xv.x; acc[3][1] += wv.w * xv.y; acc[3][2] += wv.w * xv.z; acc[3][3] += wv.w * xv.w;
    }
  }
  #pragma unroll
  for (int i = 0; i < 4; ++i) {
    float4 v = make_float4(acc[i][0], acc[i][1], acc[i][2], acc[i][3]);
    *(float4*)&Yout[(long)b * outBatchStride + (long)(outChanOffset + o0 + ty * 4 + i) * NPTS + n0 + tx * 4] = v;
  }
}

// ---------------------------------------------------------------------------
// fp32 [b][C][1024] -> bf16 [b][1024][C] transpose (for MFMA conv B operand)
// ---------------------------------------------------------------------------
__global__ __launch_bounds__(256) void transpose_bf16_kernel(const float* __restrict__ in,
    long inBatchStride, int C, unsigned short* __restrict__ outT) {
  __shared__ float tile[64][65];
  const int b  = blockIdx.z;
  const int n0 = blockIdx.x * 64, c0 = blockIdx.y * 64;
  const int tid = threadIdx.x;
  const float* ib = in + (long)b * inBatchStride;
  for (int i = tid; i < 4096; i += 256) {
    int r = i >> 6, cn = i & 63;
    tile[r][cn] = ib[(long)(c0 + r) * NPTS + n0 + cn];
  }
  __syncthreads();
  unsigned short* ob = outT + (long)b * ((long)NPTS * C);
  for (int i = tid; i < 4096; i += 256) {
    int r = i >> 6, cc = i & 63;
    __hip_bfloat16 h = __float2bfloat16(tile[cc][r]);
    ob[(long)(n0 + r) * C + c0 + cc] = *(unsigned short*)&h;
  }
}

// ---------------------------------------------------------------------------
// fp32 -> bf16 elementwise (weights)
// ---------------------------------------------------------------------------
__global__ void convert_bf16_kernel(const float* __restrict__ in,
                                    unsigned short* __restrict__ out, int n) {
  int i = blockIdx.x * 256 + threadIdx.x;
  if (i < n) { __hip_bfloat16 h = __float2bfloat16(in[i]); out[i] = *(unsigned short*)&h; }
}

// ---------------------------------------------------------------------------
// bf16 MFMA conv (conv4/conv5: outputs never feed top-k)
// ---------------------------------------------------------------------------
__global__ __launch_bounds__(256) void conv_mfma_kernel(const unsigned short* __restrict__ Wbf,
    const unsigned short* __restrict__ XT, int C,
    float* __restrict__ Yout, long outBatchStride, int outChanOffset) {
  __shared__ unsigned short Wl[128][40];
  __shared__ unsigned short Xl[128][40];
  const int b  = blockIdx.z;
  const int o0 = blockIdx.y * 128;
  const int n0 = blockIdx.x * 128;
  const int tid  = threadIdx.x;
  const int lane = tid & 63, wid = tid >> 6;
  const int wo = (wid >> 1) * 64, wn = (wid & 1) * 64;
  const int l16 = lane & 15, quad = lane >> 4;
  const unsigned short* Wg = Wbf + (long)o0 * C;
  const unsigned short* Xg = XT + (long)b * ((long)NPTS * C) + (long)n0 * C;

  f32x4 acc[4][4];
  #pragma unroll
  for (int i = 0; i < 4; ++i)
    #pragma unroll
    for (int j = 0; j < 4; ++j) acc[i][j] = (f32x4){0.f, 0.f, 0.f, 0.f};

  for (int kk = 0; kk < C; kk += 32) {
    __syncthreads();
    #pragma unroll
    for (int it = 0; it < 2; ++it) {
      const int id = tid + it * 256;
      const int r = id >> 2, qq = id & 3;
      const float4 va = *(const float4*)&Wg[(long)r * C + kk + qq * 8];
      const float4 vb = *(const float4*)&Xg[(long)r * C + kk + qq * 8];
      *(float4*)&Wl[r][qq * 8] = va;
      *(float4*)&Xl[r][qq * 8] = vb;
    }
    __syncthreads();
    short8 af[4], bfr[4];
    #pragma unroll
    for (int i = 0; i < 4; ++i) af[i]  = *(const short8*)&Wl[wo + i * 16 + l16][quad * 8];
    #pragma unroll
    for (int j = 0; j < 4; ++j) bfr[j] = *(const short8*)&Xl[wn + j * 16 + l16][quad * 8];
    #pragma unroll
    for (int i = 0; i < 4; ++i)
      #pragma unroll
      for (int j = 0; j < 4; ++j)
        acc[i][j] = __builtin_amdgcn_mfma_f32_16x16x32_bf16(af[i], bfr[j], acc[i][j], 0, 0, 0);
  }

  float* Yb = Yout + (long)b * outBatchStride + (long)outChanOffset * NPTS;
  #pragma unroll
  for (int i = 0; i < 4; ++i) {
    #pragma unroll
    for (int r = 0; r < 4; ++r) {
      const int o = o0 + wo + i * 16 + quad * 4 + r;
      float* row = Yb + (long)o * NPTS + n0 + wn;
      #pragma unroll
      for (int j = 0; j < 4; ++j) row[j * 16 + l16] = acc[i][j][r];
    }
  }
}

// ---------------------------------------------------------------------------
// BN stats / apply / pool
// ---------------------------------------------------------------------------
__global__ __launch_bounds__(256) void bn_stats_kernel(const float* __restrict__ Y, long batchStride,
    int chanOffset, float* __restrict__ meanOut, float* __restrict__ rstdOut) {
  const int o   = blockIdx.x;
  const int tid = threadIdx.x;
  const float* base = Y + (long)(chanOffset + o) * NPTS;
  float s = 0.f, s2 = 0.f;
  for (int b = 0; b < BATCH; ++b) {
    const float* p = base + (long)b * batchStride;
    for (int t = tid; t < NPTS; t += 256) { float v = p[t]; s += v; s2 += v * v; }
  }
  for (int off = 32; off > 0; off >>= 1) { s += __shfl_down(s, off); s2 += __shfl_down(s2, off); }
  __shared__ float r1[4], r2[4];
  const int wid = tid >> 6;
  if ((tid & 63) == 0) { r1[wid] = s; r2[wid] = s2; }
  __syncthreads();
  if (tid == 0) {
    s  = r1[0] + r1[1] + r1[2] + r1[3];
    s2 = r2[0] + r2[1] + r2[2] + r2[3];
    float m   = s * (1.f / 16384.f);
    float var = s2 * (1.f / 16384.f) - m * m;
    meanOut[o] = m;
    rstdOut[o] = rsqrtf(var + 1e-5f);
  }
}

__global__ __launch_bounds__(256) void bn_apply_kernel(float* __restrict__ Y, long batchStride, int chanOffset,
    const float* __restrict__ meanB, const float* __restrict__ rstdB,
    const float* __restrict__ g, const float* __restrict__ beta) {
  const int n = blockIdx.x * 256 + threadIdx.x;
  const int o = blockIdx.y;
  const int b = blockIdx.z;
  float* p = Y + (long)b * batchStride + (long)(chanOffset + o) * NPTS;
  const float sc = rstdB[o] * g[o];
  float v = (p[n] - meanB[o]) * sc + beta[o];
  p[n] = (v > 0.f) ? v : 0.2f * v;
}

__global__ __launch_bounds__(256) void bn_pool_kernel(const float* __restrict__ H,
    const float* __restrict__ meanB, const float* __restrict__ rstdB,
    const float* __restrict__ g, const float* __restrict__ beta,
    float* __restrict__ Z) {
  const int o   = blockIdx.x;
  const int b   = blockIdx.y;
  const int tid = threadIdx.x;
  const float* p = H + (long)b * (1024L * NPTS) + (long)o * NPTS;
  const float sc = rstdB[o] * g[o], mu = meanB[o], bb = beta[o];
  float mx = -INFINITY, s = 0.f;
  for (int t = tid; t < NPTS; t += 256) {
    float v = (p[t] - mu) * sc + bb;
    v = (v > 0.f) ? v : 0.2f * v;
    mx = fmaxf(mx, v);
    s += v;
  }
  for (int off = 32; off > 0; off >>= 1) { mx = fmaxf(mx, __shfl_down(mx, off)); s += __shfl_down(s, off); }
  __shared__ float rm[4], rs[4];
  const int wid = tid >> 6;
  if ((tid & 63) == 0) { rm[wid] = mx; rs[wid] = s; }
  __syncthreads();
  if (tid == 0) {
    mx = fmaxf(fmaxf(rm[0], rm[1]), fmaxf(rm[2], rm[3]));
    s  = rs[0] + rs[1] + rs[2] + rs[3];
    Z[(long)b * 2048 + o]        = mx;
    Z[(long)b * 2048 + 1024 + o] = s * (1.f / 1024.f);
  }
}

// ---------------------------------------------------------------------------
// FC: one wave per output channel, all 16 batches per wave
// ---------------------------------------------------------------------------
__global__ __launch_bounds__(256) void fc_wave_kernel(const float* __restrict__ in,
    const float* __restrict__ Wm, const float* __restrict__ bias,
    float* __restrict__ out, int Cin, int Oout) {
  const int wid  = threadIdx.x >> 6;
  const int lane = threadIdx.x & 63;
  const int o = blockIdx.x * 4 + wid;
  if (o >= Oout) return;
  const float* wp = Wm + (long)o * Cin;
  float acc[BATCH];
  #pragma unroll
  for (int b = 0; b < BATCH; ++b) acc[b] = 0.f;
  for (int c = lane; c < Cin; c += 64) {
    const float w = wp[c];
    #pragma unroll
    for (int b = 0; b < BATCH; ++b) acc[b] += w * in[b * Cin + c];
  }
  #pragma unroll
  for (int b = 0; b < BATCH; ++b) {
    #pragma unroll
    for (int off = 32; off > 0; off >>= 1) acc[b] += __shfl_down(acc[b], off);
  }
  if (lane == 0) {
    const float bs = bias ? bias[o] : 0.f;
    #pragma unroll
    for (int b = 0; b < BATCH; ++b) out[b * Oout + o] = acc[b] + bs;
  }
}

__global__ void bn_small_kernel(float* __restrict__ buf, const float* __restrict__ g,
    const float* __restrict__ beta, int O) {
  const int o = blockIdx.x * 256 + threadIdx.x;
  if (o >= O) return;
  float s = 0.f, s2 = 0.f;
  for (int b = 0; b < BATCH; ++b) { float v = buf[b * O + o]; s += v; s2 += v * v; }
  const float m   = s * (1.f / 16.f);
  const float var = s2 * (1.f / 16.f) - m * m;
  const float sc  = rsqrtf(var + 1e-5f) * g[o];
  const float bb  = beta[o];
  for (int b = 0; b < BATCH; ++b) {
    float v = (buf[b * O + o] - m) * sc + bb;
    buf[b * O + o] = (v > 0.f) ? v : 0.2f * v;
  }
}

extern "C" void kernel_launch(void* const* d_in, const int* in_sizes, int n_in,
                              void* d_out, int out_size, void* d_ws, size_t ws_size,
                              hipStream_t stream) {
  const float* x   = (const float*)d_in[0];
  const float* W1  = (const float*)d_in[1];
  const float* g1  = (const float*)d_in[2];
  const float* b1  = (const float*)d_in[3];
  const float* W2  = (const float*)d_in[4];
  const float* g2  = (const float*)d_in[5];
  const float* b2  = (const float*)d_in[6];
  const float* W3  = (const float*)d_in[7];
  const float* g3  = (const float*)d_in[8];
  const float* b3  = (const float*)d_in[9];
  const float* W4  = (const float*)d_in[10];
  const float* g4  = (const float*)d_in[11];
  const float* b4  = (const float*)d_in[12];
  const float* W5  = (const float*)d_in[13];
  const float* g5  = (const float*)d_in[14];
  const float* b5  = (const float*)d_in[15];
  const float* l1W = (const float*)d_in[16];
  const float* g6  = (const float*)d_in[17];
  const float* b6  = (const float*)d_in[18];
  const float* l2W = (const float*)d_in[19];
  const float* l2b = (const float*)d_in[20];
  const float* g7  = (const float*)d_in[21];
  const float* b7  = (const float*)d_in[22];
  const float* l3W = (const float*)d_in[23];
  const float* l3b = (const float*)d_in[24];

  float* ws   = (float*)d_ws;
  float* Xcat = ws;                        // (B,512,N)
  float* H    = Xcat + 8388608;            // (B,1024,N) (layer-5 only)
  float* REG  = H + 16777216;              // overlaid scratch
  float* AGG  = REG;
  unsigned short* AGGT = (unsigned short*)(REG + 2097152);
  unsigned short* XbfT = (unsigned short*)REG;
  int*   IDX  = (int*)(REG + 4194304);
  float* MEAN = (float*)(IDX + 327680);
  float* RSTD = MEAN + 1024;
  float* Z    = RSTD + 1024;
  float* Z1   = Z + 32768;
  float* Z2   = Z1 + 8192;
  unsigned short* W4bf = (unsigned short*)(Z2 + 4096);
  unsigned short* W5bf = W4bf + 32768;

  // knn scratch overlays H (dead until layer 5)
  float* SQ    = H;                                      // 16,384 f
  float* PARTV = H + 16384;                              // 1,310,720 f
  unsigned short* PARTI = (unsigned short*)(PARTV + 1310720); // 1,310,720 u16 (= 655,360 f)
  // split bf16 planes (max 16*1024*128 = 2,097,152 u16 each = 1,048,576 f)
  unsigned short* XH = (unsigned short*)(H + 1982464);
  unsigned short* XM = (unsigned short*)(H + 1982464 + 1048576);
  unsigned short* XL = (unsigned short*)(H + 1982464 + 2097152);

  const long XS = 512L * 1024;
  const long HS = 1024L * 1024;
  const dim3 knnGrid(16, 4, 16);

  // ---- edge block 1 (C=3, fp32 knn) ----
  compute_sq_kernel<<<dim3(4, 16), 256, 0, stream>>>(x, 3L * 1024, 3, SQ);
  knn_kernel<3><<<knnGrid, 256, 0, stream>>>(x, 3L * 1024, SQ, PARTV, PARTI);
  knn_merge_kernel<<<64, 256, 0, stream>>>(PARTV, PARTI, IDX);
  gather_sum_kernel<<<dim3(4, 16), 256, 0, stream>>>(x, 3L * 1024, 3, IDX, AGG);
  conv_kernel<<<dim3(16, 1, 16), 256, 0, stream>>>(AGG, 3L * 1024, W1, 3, 64, Xcat, XS, 0);
  bn_stats_kernel<<<64, 256, 0, stream>>>(Xcat, XS, 0, MEAN, RSTD);
  bn_apply_kernel<<<dim3(4, 64, 16), 256, 0, stream>>>(Xcat, XS, 0, MEAN, RSTD, g1, b1);

  // ---- edge block 2 (C=64, split-bf16 MFMA knn) ----
  compute_sq_kernel<<<dim3(4, 16), 256, 0, stream>>>(Xcat, XS, 64, SQ);
  transpose_split_kernel<<<dim3(16, 1, 16), 256, 0, stream>>>(Xcat, XS, 64, XH, XM, XL);
  knn_mfma_kernel<64><<<knnGrid, 256, 0, stream>>>(XH, XM, XL, SQ, PARTV, PARTI);
  knn_merge_kernel<<<64, 256, 0, stream>>>(PARTV, PARTI, IDX);
  gather_sum_kernel<<<dim3(4, 16), 256, 0, stream>>>(Xcat, XS, 64, IDX, AGG);
  conv_kernel<<<dim3(16, 1, 16), 256, 0, stream>>>(AGG, 64L * 1024, W2, 64, 64, Xcat, XS, 64);
  bn_stats_kernel<<<64, 256, 0, stream>>>(Xcat, XS, 64, MEAN, RSTD);
  bn_apply_kernel<<<dim3(4, 64, 16), 256, 0, stream>>>(Xcat, XS, 64, MEAN, RSTD, g2, b2);

  // ---- edge block 3 (C=64 -> O=128, split-bf16 MFMA knn) ----
  compute_sq_kernel<<<dim3(4, 16), 256, 0, stream>>>(Xcat + 64L * 1024, XS, 64, SQ);
  transpose_split_kernel<<<dim3(16, 1, 16), 256, 0, stream>>>(Xcat + 64L * 1024, XS, 64, XH, XM, XL);
  knn_mfma_kernel<64><<<knnGrid, 256, 0, stream>>>(XH, XM, XL, SQ, PARTV, PARTI);
  knn_merge_kernel<<<64, 256, 0, stream>>>(PARTV, PARTI, IDX);
  gather_sum_kernel<<<dim3(4, 16), 256, 0, stream>>>(Xcat + 64L * 1024, XS, 64, IDX, AGG);
  conv_kernel<<<dim3(16, 2, 16), 256, 0, stream>>>(AGG, 64L * 1024, W3, 64, 128, Xcat, XS, 128);
  bn_stats_kernel<<<128, 256, 0, stream>>>(Xcat, XS, 128, MEAN, RSTD);
  bn_apply_kernel<<<dim3(4, 128, 16), 256, 0, stream>>>(Xcat, XS, 128, MEAN, RSTD, g3, b3);

  // ---- edge block 4 (C=128 -> O=256, split-bf16 MFMA knn + MFMA conv) ----
  compute_sq_kernel<<<dim3(4, 16), 256, 0, stream>>>(Xcat + 128L * 1024, XS, 128, SQ);
  transpose_split_kernel<<<dim3(16, 2, 16), 256, 0, stream>>>(Xcat + 128L * 1024, XS, 128, XH, XM, XL);
  knn_mfma_kernel<128><<<knnGrid, 256, 0, stream>>>(XH, XM, XL, SQ, PARTV, PARTI);
  knn_merge_kernel<<<64, 256, 0, stream>>>(PARTV, PARTI, IDX);
  gather_sum_kernel<<<dim3(4, 16), 256, 0, stream>>>(Xcat + 128L * 1024, XS, 128, IDX, AGG);
  convert_bf16_kernel<<<128, 256, 0, stream>>>(W4, W4bf, 256 * 128);
  transpose_bf16_kernel<<<dim3(16, 2, 16), 256, 0, stream>>>(AGG, 128L * 1024, 128, AGGT);
  conv_mfma_kernel<<<dim3(8, 2, 16), 256, 0, stream>>>(W4bf, AGGT, 128, Xcat, XS, 256);
  bn_stats_kernel<<<256, 256, 0, stream>>>(Xcat, XS, 256, MEAN, RSTD);
  bn_apply_kernel<<<dim3(4, 256, 16), 256, 0, stream>>>(Xcat, XS, 256, MEAN, RSTD, g4, b4);

  // ---- layer 5 (bf16 MFMA; H written only after knn scratch is dead) ----
  convert_bf16_kernel<<<2048, 256, 0, stream>>>(W5, W5bf, 1024 * 512);
  transpose_bf16_kernel<<<dim3(16, 8, 16), 256, 0, stream>>>(Xcat, XS, 512, XbfT);
  conv_mfma_kernel<<<dim3(8, 8, 16), 256, 0, stream>>>(W5bf, XbfT, 512, H, HS, 0);
  bn_stats_kernel<<<1024, 256, 0, stream>>>(H, HS, 0, MEAN, RSTD);
  bn_pool_kernel<<<dim3(1024, 16), 256, 0, stream>>>(H, MEAN, RSTD, g5, b5, Z);

  // ---- MLP head ----
  fc_wave_kernel<<<128, 256, 0, stream>>>(Z, l1W, nullptr, Z1, 2048, 512);
  bn_small_kernel<<<2, 256, 0, stream>>>(Z1, g6, b6, 512);
  fc_wave_kernel<<<64, 256, 0, stream>>>(Z1, l2W, l2b, Z2, 512, 256);
  bn_small_kernel<<<1, 256, 0, stream>>>(Z2, g7, b7, 256);
  fc_wave_kernel<<<10, 256, 0, stream>>>(Z2, l3W, l3b, (float*)d_out, 256, 40);
}

// Round 8
// 1053.823 us; speedup vs baseline: 4.3649x; 1.2309x over previous
//
#include <hip/hip_runtime.h>
#include <hip/hip_bf16.h>
#include <math.h>

#define NPTS 1024
#define BATCH 16
#define KNN 20

typedef __attribute__((ext_vector_type(8))) short short8;
typedef __attribute__((ext_vector_type(4))) float f32x4;

// ---------------------------------------------------------------------------
// per-point squared norms: sq[b][m] = sum_c X[b,c,m]^2  (fp32, exact-ish)
// ---------------------------------------------------------------------------
__global__ __launch_bounds__(256) void compute_sq_kernel(const float* __restrict__ X,
    long batchStride, int C, float* __restrict__ sq) {
  const int b = blockIdx.y;
  const int m = blockIdx.x * 256 + threadIdx.x;
  const float* Xb = X + (long)b * batchStride;
  float s = 0.f;
  for (int c = 0; c < C; ++c) { float v = Xb[(long)c * NPTS + m]; s += v * v; }
  sq[b * NPTS + m] = s;
}

// ---------------------------------------------------------------------------
// fp32 [b][C][1024] -> three bf16 planes [b][1024][C]: x = hi + mid + lo
// ---------------------------------------------------------------------------
__global__ __launch_bounds__(256) void transpose_split_kernel(const float* __restrict__ in,
    long inBatchStride, int C, unsigned short* __restrict__ XH,
    unsigned short* __restrict__ XM, unsigned short* __restrict__ XL) {
  __shared__ float tile[64][65];
  const int b  = blockIdx.z;
  const int n0 = blockIdx.x * 64, c0 = blockIdx.y * 64;
  const int tid = threadIdx.x;
  const float* ib = in + (long)b * inBatchStride;
  for (int i = tid; i < 4096; i += 256) {
    int r = i >> 6, cn = i & 63;
    tile[r][cn] = ib[(long)(c0 + r) * NPTS + n0 + cn];
  }
  __syncthreads();
  const long pb = (long)b * ((long)NPTS * C);
  for (int i = tid; i < 4096; i += 256) {
    int r = i >> 6, cc = i & 63;
    float f = tile[cc][r];
    __hip_bfloat16 h = __float2bfloat16(f);
    float r1 = f - __bfloat162float(h);
    __hip_bfloat16 m = __float2bfloat16(r1);
    float r2 = r1 - __bfloat162float(m);
    __hip_bfloat16 l = __float2bfloat16(r2);
    const long o = pb + (long)(n0 + r) * C + c0 + cc;
    XH[o] = *(unsigned short*)&h;
    XM[o] = *(unsigned short*)&m;
    XL[o] = *(unsigned short*)&l;
  }
}

// ---------------------------------------------------------------------------
// knn via split-bf16 MFMA (C=64/128): block = (64 queries, 256-cand chunk, b).
// inner = hh+hm+mh+mm+hl+lh (6 MFMA passes, fp32 acc).
// ---------------------------------------------------------------------------
template<int C>
__global__ __launch_bounds__(256) void knn_mfma_kernel(
    const unsigned short* __restrict__ XH, const unsigned short* __restrict__ XM,
    const unsigned short* __restrict__ XL, const float* __restrict__ sqg,
    float* __restrict__ PARTV, unsigned short* __restrict__ PARTI) {
  __shared__ __align__(16) unsigned short QP[6][64][40];
  __shared__ __align__(16) float Dbuf[64][68];
  __shared__ float sqs[256];
  float* region = (float*)&QP[0][0][0];

  const int b     = blockIdx.z;
  const int q0    = blockIdx.x * 64;
  const int p0    = blockIdx.y * 256;
  const int chunk = blockIdx.y;
  const int tid  = threadIdx.x;
  const int lane = tid & 63, w = tid >> 6;
  const int l16  = lane & 15, quad = lane >> 4;
  const int q = lane, sub = w;

  const long plane = (long)b * ((long)NPTS * C);
  const unsigned short* XHb = XH + plane;
  const unsigned short* XMb = XM + plane;
  const unsigned short* XLb = XL + plane;

  sqs[tid] = sqg[b * NPTS + p0 + tid];

  float topv[KNN];
  int   topi[KNN];
  #pragma unroll
  for (int j = 0; j < KNN; ++j) { topv[j] = -INFINITY; topi[j] = 0x7fffffff; }
  float vmin = -INFINITY;

  const int srow = tid >> 2, sseg = (tid & 3) * 8;

  for (int pc = 0; pc < 256; pc += 64) {
    f32x4 acc[4];
    #pragma unroll
    for (int t = 0; t < 4; ++t) acc[t] = (f32x4){0.f, 0.f, 0.f, 0.f};

    for (int kc = 0; kc < C; kc += 32) {
      __syncthreads();
      const long qo = (long)(q0 + srow) * C + kc + sseg;
      const long po = (long)(p0 + pc + srow) * C + kc + sseg;
      *(float4*)&QP[0][srow][sseg] = *(const float4*)&XHb[qo];
      *(float4*)&QP[1][srow][sseg] = *(const float4*)&XMb[qo];
      *(float4*)&QP[2][srow][sseg] = *(const float4*)&XLb[qo];
      *(float4*)&QP[3][srow][sseg] = *(const float4*)&XHb[po];
      *(float4*)&QP[4][srow][sseg] = *(const float4*)&XMb[po];
      *(float4*)&QP[5][srow][sseg] = *(const float4*)&XLb[po];
      __syncthreads();
      const short8 ph = *(const short8*)&QP[3][w * 16 + l16][quad * 8];
      const short8 pm = *(const short8*)&QP[4][w * 16 + l16][quad * 8];
      const short8 pl = *(const short8*)&QP[5][w * 16 + l16][quad * 8];
      #pragma unroll
      for (int t = 0; t < 4; ++t) {
        const short8 qh = *(const short8*)&QP[0][t * 16 + l16][quad * 8];
        const short8 qm = *(const short8*)&QP[1][t * 16 + l16][quad * 8];
        const short8 ql = *(const short8*)&QP[2][t * 16 + l16][quad * 8];
        acc[t] = __builtin_amdgcn_mfma_f32_16x16x32_bf16(ph, qh, acc[t], 0, 0, 0);
        acc[t] = __builtin_amdgcn_mfma_f32_16x16x32_bf16(ph, qm, acc[t], 0, 0, 0);
        acc[t] = __builtin_amdgcn_mfma_f32_16x16x32_bf16(pm, qh, acc[t], 0, 0, 0);
        acc[t] = __builtin_amdgcn_mfma_f32_16x16x32_bf16(pm, qm, acc[t], 0, 0, 0);
        acc[t] = __builtin_amdgcn_mfma_f32_16x16x32_bf16(ph, ql, acc[t], 0, 0, 0);
        acc[t] = __builtin_amdgcn_mfma_f32_16x16x32_bf16(pl, qh, acc[t], 0, 0, 0);
      }
    }
    #pragma unroll
    for (int t = 0; t < 4; ++t)
      #pragma unroll
      for (int r = 0; r < 4; ++r)
        Dbuf[w * 16 + quad * 4 + r][t * 16 + l16] = acc[t][r];
    __syncthreads();

    #pragma unroll 4
    for (int i = 0; i < 16; ++i) {
      const float v = fmaf(2.f, Dbuf[sub * 16 + i][q], -sqs[pc + sub * 16 + i]);
      if (v > vmin) {
        float cv = v; int ci = p0 + pc + sub * 16 + i;
        bool ins = false;
        #pragma unroll
        for (int j = 0; j < KNN; ++j) {
          const float tv = topv[j]; const int ti = topi[j];
          const bool gt = ins || (cv > tv);
          topv[j] = gt ? cv : tv;
          topi[j] = gt ? ci : ti;
          cv = gt ? tv : cv;
          ci = gt ? ti : ci;
          ins = gt;
        }
        vmin = topv[KNN - 1];
      }
    }
  }

  __syncthreads();
  {
    float* mv = region;
    unsigned short* mi = (unsigned short*)(region + 5120);
    const int slot = q * 4 + sub;
    #pragma unroll
    for (int j = 0; j < KNN; ++j) { mv[j * 256 + slot] = topv[j]; mi[j * 256 + slot] = (unsigned short)topi[j]; }
  }
  __syncthreads();
  if (tid < 64) {
    const float* mv = region;
    const unsigned short* mi = (const unsigned short*)(region + 5120);
    int p0_ = 0, p1 = 0, p2 = 0, p3 = 0;
    float* opv = PARTV + (((long)(b * NPTS + q0 + tid)) * 4 + chunk) * KNN;
    unsigned short* opi = PARTI + (((long)(b * NPTS + q0 + tid)) * 4 + chunk) * KNN;
    for (int j = 0; j < KNN; ++j) {
      float bv = -INFINITY; int bi = 0x7fffffff; int bs = 0;
      if (p0_ < KNN) { float v = mv[p0_ * 256 + tid * 4 + 0]; int i = mi[p0_ * 256 + tid * 4 + 0];
        if (v > bv || (v == bv && i < bi)) { bv = v; bi = i; bs = 0; } }
      if (p1 < KNN) { float v = mv[p1 * 256 + tid * 4 + 1]; int i = mi[p1 * 256 + tid * 4 + 1];
        if (v > bv || (v == bv && i < bi)) { bv = v; bi = i; bs = 1; } }
      if (p2 < KNN) { float v = mv[p2 * 256 + tid * 4 + 2]; int i = mi[p2 * 256 + tid * 4 + 2];
        if (v > bv || (v == bv && i < bi)) { bv = v; bi = i; bs = 2; } }
      if (p3 < KNN) { float v = mv[p3 * 256 + tid * 4 + 3]; int i = mi[p3 * 256 + tid * 4 + 3];
        if (v > bv || (v == bv && i < bi)) { bv = v; bi = i; bs = 3; } }
      p0_ += (bs == 0); p1 += (bs == 1); p2 += (bs == 2); p3 += (bs == 3);
      opv[j] = bv; opi[j] = (unsigned short)bi;
    }
  }
}

// ---------------------------------------------------------------------------
// fp32 knn (C=3 only)
// ---------------------------------------------------------------------------
template<int C>
__global__ __launch_bounds__(256) void knn_kernel(const float* __restrict__ X,
    long batchStride, const float* __restrict__ sqg,
    float* __restrict__ PARTV, unsigned short* __restrict__ PARTI) {
  constexpr int CT = (C < 64) ? C : 64;
  constexpr int REGF = (2 * CT * 64 > 7680) ? 2 * CT * 64 : 7680;
  __shared__ float Dbuf[64][68];
  __shared__ float region[REGF];

  float* qbuf = region;
  float* pbuf = region + CT * 64;

  const int b     = blockIdx.z;
  const int q0    = blockIdx.x * 64;
  const int p0    = blockIdx.y * 256;
  const int chunk = blockIdx.y;
  const int tid = threadIdx.x;
  const int ty  = tid >> 4, tx = tid & 15;
  const int q   = tid & 63;
  const int sub = tid >> 6;
  const float* Xb = X + (long)b * batchStride;
  const float* sqb = sqg + b * NPTS;

  float topv[KNN];
  int   topi[KNN];
  #pragma unroll
  for (int j = 0; j < KNN; ++j) { topv[j] = -INFINITY; topi[j] = 0x7fffffff; }
  float vmin = -INFINITY;

  for (int pc = p0; pc < p0 + 256; pc += 64) {
    float acc[4][4] = {};
    for (int cc = 0; cc < C; cc += CT) {
      __syncthreads();
      for (int t = tid; t < 64 * CT; t += 256) {
        int c = t >> 6, m = t & 63;
        qbuf[c * 64 + m] = Xb[(long)(cc + c) * NPTS + q0 + m];
        pbuf[c * 64 + m] = Xb[(long)(cc + c) * NPTS + pc + m];
      }
      __syncthreads();
      #pragma unroll
      for (int c = 0; c < CT; ++c) {
        const float4 qv = *(const float4*)&qbuf[c * 64 + ty * 4];
        const float4 pv = *(const float4*)&pbuf[c * 64 + tx * 4];
        acc[0][0] += qv.x * pv.x; acc[0][1] += qv.x * pv.y; acc[0][2] += qv.x * pv.z; acc[0][3] += qv.x * pv.w;
        acc[1][0] += qv.y * pv.x; acc[1][1] += qv.y * pv.y; acc[1][2] += qv.y * pv.z; acc[1][3] += qv.y * pv.w;
        acc[2][0] += qv.z * pv.x; acc[2][1] += qv.z * pv.y; acc[2][2] += qv.z * pv.z; acc[2][3] += qv.z * pv.w;
        acc[3][0] += qv.w * pv.x; acc[3][1] += qv.w * pv.y; acc[3][2] += qv.w * pv.z; acc[3][3] += qv.w * pv.w;
      }
    }
    #pragma unroll
    for (int j = 0; j < 4; ++j) {
      const int p = pc + tx * 4 + j;
      const float sq = sqb[p];
      float4 dv;
      dv.x = 2.f * acc[0][j] - sq;
      dv.y = 2.f * acc[1][j] - sq;
      dv.z = 2.f * acc[2][j] - sq;
      dv.w = 2.f * acc[3][j] - sq;
      *(float4*)&Dbuf[tx * 4 + j][ty * 4] = dv;
    }
    __syncthreads();

    #pragma unroll 4
    for (int i = 0; i < 16; ++i) {
      const float v = Dbuf[sub * 16 + i][q];
      if (v > vmin) {
        float cv = v; int ci = pc + sub * 16 + i;
        bool ins = false;
        #pragma unroll
        for (int j = 0; j < KNN; ++j) {
          const float tv = topv[j]; const int ti = topi[j];
          const bool gt = ins || (cv > tv);
          topv[j] = gt ? cv : tv;
          topi[j] = gt ? ci : ti;
          cv = gt ? tv : cv;
          ci = gt ? ti : ci;
          ins = gt;
        }
        vmin = topv[KNN - 1];
      }
    }
  }

  __syncthreads();
  {
    float* mv = region;
    unsigned short* mi = (unsigned short*)(region + 5120);
    const int slot = q * 4 + sub;
    #pragma unroll
    for (int j = 0; j < KNN; ++j) { mv[j * 256 + slot] = topv[j]; mi[j * 256 + slot] = (unsigned short)topi[j]; }
  }
  __syncthreads();
  if (tid < 64) {
    const float* mv = region;
    const unsigned short* mi = (const unsigned short*)(region + 5120);
    int p0_ = 0, p1 = 0, p2 = 0, p3 = 0;
    float* opv = PARTV + (((long)(b * NPTS + q0 + tid)) * 4 + chunk) * KNN;
    unsigned short* opi = PARTI + (((long)(b * NPTS + q0 + tid)) * 4 + chunk) * KNN;
    for (int j = 0; j < KNN; ++j) {
      float bv = -INFINITY; int bi = 0x7fffffff; int bs = 0;
      if (p0_ < KNN) { float v = mv[p0_ * 256 + tid * 4 + 0]; int i = mi[p0_ * 256 + tid * 4 + 0];
        if (v > bv || (v == bv && i < bi)) { bv = v; bi = i; bs = 0; } }
      if (p1 < KNN) { float v = mv[p1 * 256 + tid * 4 + 1]; int i = mi[p1 * 256 + tid * 4 + 1];
        if (v > bv || (v == bv && i < bi)) { bv = v; bi = i; bs = 1; } }
      if (p2 < KNN) { float v = mv[p2 * 256 + tid * 4 + 2]; int i = mi[p2 * 256 + tid * 4 + 2];
        if (v > bv || (v == bv && i < bi)) { bv = v; bi = i; bs = 2; } }
      if (p3 < KNN) { float v = mv[p3 * 256 + tid * 4 + 3]; int i = mi[p3 * 256 + tid * 4 + 3];
        if (v > bv || (v == bv && i < bi)) { bv = v; bi = i; bs = 3; } }
      p0_ += (bs == 0); p1 += (bs == 1); p2 += (bs == 2); p3 += (bs == 3);
      opv[j] = bv; opi[j] = (unsigned short)bi;
    }
  }
}

// ---------------------------------------------------------------------------
// merge 4 sorted partial lists per query -> final top-20 indices.
// ---------------------------------------------------------------------------
__global__ __launch_bounds__(256) void knn_merge_kernel(const float* __restrict__ PARTV,
    const unsigned short* __restrict__ PARTI, int* __restrict__ idxOut) {
  const int idx = blockIdx.x * 256 + threadIdx.x;
  const float* pv = PARTV + (long)idx * 4 * KNN;
  const unsigned short* pi = PARTI + (long)idx * 4 * KNN;
  int p0 = 0, p1 = 0, p2 = 0, p3 = 0;
  int* op = idxOut + (long)idx * KNN;
  for (int j = 0; j < KNN; ++j) {
    float bv = -INFINITY; int bi = 0x7fffffff; int bs = 0;
    if (p0 < KNN) { float v = pv[0 * KNN + p0]; int i = pi[0 * KNN + p0];
      if (v > bv || (v == bv && i < bi)) { bv = v; bi = i; bs = 0; } }
    if (p1 < KNN) { float v = pv[1 * KNN + p1]; int i = pi[1 * KNN + p1];
      if (v > bv || (v == bv && i < bi)) { bv = v; bi = i; bs = 1; } }
    if (p2 < KNN) { float v = pv[2 * KNN + p2]; int i = pi[2 * KNN + p2];
      if (v > bv || (v == bv && i < bi)) { bv = v; bi = i; bs = 2; } }
    if (p3 < KNN) { float v = pv[3 * KNN + p3]; int i = pi[3 * KNN + p3];
      if (v > bv || (v == bv && i < bi)) { bv = v; bi = i; bs = 3; } }
    p0 += (bs == 0); p1 += (bs == 1); p2 += (bs == 2); p3 += (bs == 3);
    op[j] = bi;
  }
}

// ---------------------------------------------------------------------------
// gather + sum over k neighbors, channel-parallel: block = (256 queries,
// 8-channel chunk, batch). Grid (4, ceil(C/8), 16) -> up to 1024 blocks,
// fixes the 64-block latency-bound version (occupancy 2.9%, VALU 1%).
// ---------------------------------------------------------------------------
__global__ __launch_bounds__(256) void gather_sum_kernel(const float* __restrict__ X,
    long batchStride, int C, const int* __restrict__ idx, float* __restrict__ agg) {
  __shared__ int sidx[256][KNN + 1];
  const int b     = blockIdx.z;
  const int n0    = blockIdx.x * 256;
  const int cbase = blockIdx.y * 8;
  const int tid   = threadIdx.x;
  const int* ib = idx + ((long)(b * NPTS + n0)) * KNN;
  for (int t = tid; t < 256 * KNN; t += 256) {
    sidx[t / KNN][t % KNN] = ib[t];
  }
  __syncthreads();
  const float* Xb = X + (long)b * batchStride;
  float* ab = agg + (long)b * C * NPTS;
  const int cend = min(cbase + 8, C);
  for (int c = cbase; c < cend; ++c) {
    const float* row = Xb + (long)c * NPTS;
    float s = 0.f;
    #pragma unroll
    for (int j = 0; j < KNN; ++j) s += row[sidx[tid][j]];
    ab[(long)c * NPTS + n0 + tid] = s;
  }
}

// ---------------------------------------------------------------------------
// fp32 conv (conv1-3: outputs feed knn, stay fp32)
// ---------------------------------------------------------------------------
__global__ __launch_bounds__(256) void conv_kernel(const float* __restrict__ Xin, long inBatchStride,
    const float* __restrict__ W, int C, int O,
    float* __restrict__ Yout, long outBatchStride, int outChanOffset) {
  __shared__ float Wt[32][68];
  __shared__ float Xt[32][68];
  const int b   = blockIdx.z;
  const int o0  = blockIdx.y * 64;
  const int n0  = blockIdx.x * 64;
  const int tid = threadIdx.x;
  const int ty  = tid >> 4, tx = tid & 15;
  const float* Xb = Xin + (long)b * inBatchStride;
  float acc[4][4] = {};
  for (int cc = 0; cc < C; cc += 32) {
    const int cw = min(32, C - cc);
    __syncthreads();
    for (int t = tid; t < 64 * 32; t += 256) {
      int oo = t >> 5, kk = t & 31;
      Wt[kk][oo] = (kk < cw) ? W[(long)(o0 + oo) * C + cc + kk] : 0.f;
    }
    for (int t = tid; t < 32 * 64; t += 256) {
      int kk = t >> 6, nn = t & 63;
      Xt[kk][nn] = (kk < cw) ? Xb[(long)(cc + kk) * NPTS + n0 + nn] : 0.f;
    }
    __syncthreads();
    #pragma unroll
    for (int kk = 0; kk < 32; ++kk) {
      const float4 wv = *(const float4*)&Wt[kk][ty * 4];
      const float4 xv = *(const float4*)&Xt[kk][tx * 4];
      acc[0][0] += wv.x * xv.x; acc[0][1] += wv.x * xv.y; acc[0][2] += wv.x * xv.z; acc[0][3] += wv.x * xv.w;
      acc[1][0] += wv.y * xv.x; acc[1][1] += wv.y * xv.y; acc[1][2] += wv.y * xv.z; acc[1][3] += wv.y * xv.w;
      acc[2][0] += wv.z * xv.x; acc[2][1] += wv.z * xv.y; acc[2][2] += wv.z * xv.z; acc[2][3] += wv.z * xv.w;
      acc[3][0] += wv.w * xv.x; acc[3][1] += wv.w * xv.y; acc[3][2] += wv.w * xv.z; acc[3][3] += wv.w * xv.w;
    }
  }
  #pragma unroll
  for (int i = 0; i < 4; ++i) {
    float4 v = make_float4(acc[i][0], acc[i][1], acc[i][2], acc[i][3]);
    *(float4*)&Yout[(long)b * outBatchStride + (long)(outChanOffset + o0 + ty * 4 + i) * NPTS + n0 + tx * 4] = v;
  }
}

// ---------------------------------------------------------------------------
// fp32 [b][C][1024] -> bf16 [b][1024][C] transpose (for MFMA conv B operand)
// ---------------------------------------------------------------------------
__global__ __launch_bounds__(256) void transpose_bf16_kernel(const float* __restrict__ in,
    long inBatchStride, int C, unsigned short* __restrict__ outT) {
  __shared__ float tile[64][65];
  const int b  = blockIdx.z;
  const int n0 = blockIdx.x * 64, c0 = blockIdx.y * 64;
  const int tid = threadIdx.x;
  const float* ib = in + (long)b * inBatchStride;
  for (int i = tid; i < 4096; i += 256) {
    int r = i >> 6, cn = i & 63;
    tile[r][cn] = ib[(long)(c0 + r) * NPTS + n0 + cn];
  }
  __syncthreads();
  unsigned short* ob = outT + (long)b * ((long)NPTS * C);
  for (int i = tid; i < 4096; i += 256) {
    int r = i >> 6, cc = i & 63;
    __hip_bfloat16 h = __float2bfloat16(tile[cc][r]);
    ob[(long)(n0 + r) * C + c0 + cc] = *(unsigned short*)&h;
  }
}

// ---------------------------------------------------------------------------
// fp32 -> bf16 elementwise (weights)
// ---------------------------------------------------------------------------
__global__ void convert_bf16_kernel(const float* __restrict__ in,
                                    unsigned short* __restrict__ out, int n) {
  int i = blockIdx.x * 256 + threadIdx.x;
  if (i < n) { __hip_bfloat16 h = __float2bfloat16(in[i]); out[i] = *(unsigned short*)&h; }
}

// ---------------------------------------------------------------------------
// bf16 MFMA conv (conv4/conv5: outputs never feed top-k)
// ---------------------------------------------------------------------------
__global__ __launch_bounds__(256) void conv_mfma_kernel(const unsigned short* __restrict__ Wbf,
    const unsigned short* __restrict__ XT, int C,
    float* __restrict__ Yout, long outBatchStride, int outChanOffset) {
  __shared__ unsigned short Wl[128][40];
  __shared__ unsigned short Xl[128][40];
  const int b  = blockIdx.z;
  const int o0 = blockIdx.y * 128;
  const int n0 = blockIdx.x * 128;
  const int tid  = threadIdx.x;
  const int lane = tid & 63, wid = tid >> 6;
  const int wo = (wid >> 1) * 64, wn = (wid & 1) * 64;
  const int l16 = lane & 15, quad = lane >> 4;
  const unsigned short* Wg = Wbf + (long)o0 * C;
  const unsigned short* Xg = XT + (long)b * ((long)NPTS * C) + (long)n0 * C;

  f32x4 acc[4][4];
  #pragma unroll
  for (int i = 0; i < 4; ++i)
    #pragma unroll
    for (int j = 0; j < 4; ++j) acc[i][j] = (f32x4){0.f, 0.f, 0.f, 0.f};

  for (int kk = 0; kk < C; kk += 32) {
    __syncthreads();
    #pragma unroll
    for (int it = 0; it < 2; ++it) {
      const int id = tid + it * 256;
      const int r = id >> 2, qq = id & 3;
      const float4 va = *(const float4*)&Wg[(long)r * C + kk + qq * 8];
      const float4 vb = *(const float4*)&Xg[(long)r * C + kk + qq * 8];
      *(float4*)&Wl[r][qq * 8] = va;
      *(float4*)&Xl[r][qq * 8] = vb;
    }
    __syncthreads();
    short8 af[4], bfr[4];
    #pragma unroll
    for (int i = 0; i < 4; ++i) af[i]  = *(const short8*)&Wl[wo + i * 16 + l16][quad * 8];
    #pragma unroll
    for (int j = 0; j < 4; ++j) bfr[j] = *(const short8*)&Xl[wn + j * 16 + l16][quad * 8];
    #pragma unroll
    for (int i = 0; i < 4; ++i)
      #pragma unroll
      for (int j = 0; j < 4; ++j)
        acc[i][j] = __builtin_amdgcn_mfma_f32_16x16x32_bf16(af[i], bfr[j], acc[i][j], 0, 0, 0);
  }

  float* Yb = Yout + (long)b * outBatchStride + (long)outChanOffset * NPTS;
  #pragma unroll
  for (int i = 0; i < 4; ++i) {
    #pragma unroll
    for (int r = 0; r < 4; ++r) {
      const int o = o0 + wo + i * 16 + quad * 4 + r;
      float* row = Yb + (long)o * NPTS + n0 + wn;
      #pragma unroll
      for (int j = 0; j < 4; ++j) row[j * 16 + l16] = acc[i][j][r];
    }
  }
}

// ---------------------------------------------------------------------------
// BN stats / apply / pool
// ---------------------------------------------------------------------------
__global__ __launch_bounds__(256) void bn_stats_kernel(const float* __restrict__ Y, long batchStride,
    int chanOffset, float* __restrict__ meanOut, float* __restrict__ rstdOut) {
  const int o   = blockIdx.x;
  const int tid = threadIdx.x;
  const float* base = Y + (long)(chanOffset + o) * NPTS;
  float s = 0.f, s2 = 0.f;
  for (int b = 0; b < BATCH; ++b) {
    const float* p = base + (long)b * batchStride;
    for (int t = tid; t < NPTS; t += 256) { float v = p[t]; s += v; s2 += v * v; }
  }
  for (int off = 32; off > 0; off >>= 1) { s += __shfl_down(s, off); s2 += __shfl_down(s2, off); }
  __shared__ float r1[4], r2[4];
  const int wid = tid >> 6;
  if ((tid & 63) == 0) { r1[wid] = s; r2[wid] = s2; }
  __syncthreads();
  if (tid == 0) {
    s  = r1[0] + r1[1] + r1[2] + r1[3];
    s2 = r2[0] + r2[1] + r2[2] + r2[3];
    float m   = s * (1.f / 16384.f);
    float var = s2 * (1.f / 16384.f) - m * m;
    meanOut[o] = m;
    rstdOut[o] = rsqrtf(var + 1e-5f);
  }
}

__global__ __launch_bounds__(256) void bn_apply_kernel(float* __restrict__ Y, long batchStride, int chanOffset,
    const float* __restrict__ meanB, const float* __restrict__ rstdB,
    const float* __restrict__ g, const float* __restrict__ beta) {
  const int n = blockIdx.x * 256 + threadIdx.x;
  const int o = blockIdx.y;
  const int b = blockIdx.z;
  float* p = Y + (long)b * batchStride + (long)(chanOffset + o) * NPTS;
  const float sc = rstdB[o] * g[o];
  float v = (p[n] - meanB[o]) * sc + beta[o];
  p[n] = (v > 0.f) ? v : 0.2f * v;
}

__global__ __launch_bounds__(256) void bn_pool_kernel(const float* __restrict__ H,
    const float* __restrict__ meanB, const float* __restrict__ rstdB,
    const float* __restrict__ g, const float* __restrict__ beta,
    float* __restrict__ Z) {
  const int o   = blockIdx.x;
  const int b   = blockIdx.y;
  const int tid = threadIdx.x;
  const float* p = H + (long)b * (1024L * NPTS) + (long)o * NPTS;
  const float sc = rstdB[o] * g[o], mu = meanB[o], bb = beta[o];
  float mx = -INFINITY, s = 0.f;
  for (int t = tid; t < NPTS; t += 256) {
    float v = (p[t] - mu) * sc + bb;
    v = (v > 0.f) ? v : 0.2f * v;
    mx = fmaxf(mx, v);
    s += v;
  }
  for (int off = 32; off > 0; off >>= 1) { mx = fmaxf(mx, __shfl_down(mx, off)); s += __shfl_down(s, off); }
  __shared__ float rm[4], rs[4];
  const int wid = tid >> 6;
  if ((tid & 63) == 0) { rm[wid] = mx; rs[wid] = s; }
  __syncthreads();
  if (tid == 0) {
    mx = fmaxf(fmaxf(rm[0], rm[1]), fmaxf(rm[2], rm[3]));
    s  = rs[0] + rs[1] + rs[2] + rs[3];
    Z[(long)b * 2048 + o]        = mx;
    Z[(long)b * 2048 + 1024 + o] = s * (1.f / 1024.f);
  }
}

// ---------------------------------------------------------------------------
// FC: one wave per output channel, all 16 batches per wave
// ---------------------------------------------------------------------------
__global__ __launch_bounds__(256) void fc_wave_kernel(const float* __restrict__ in,
    const float* __restrict__ Wm, const float* __restrict__ bias,
    float* __restrict__ out, int Cin, int Oout) {
  const int wid  = threadIdx.x >> 6;
  const int lane = threadIdx.x & 63;
  const int o = blockIdx.x * 4 + wid;
  if (o >= Oout) return;
  const float* wp = Wm + (long)o * Cin;
  float acc[BATCH];
  #pragma unroll
  for (int b = 0; b < BATCH; ++b) acc[b] = 0.f;
  for (int c = lane; c < Cin; c += 64) {
    const float w = wp[c];
    #pragma unroll
    for (int b = 0; b < BATCH; ++b) acc[b] += w * in[b * Cin + c];
  }
  #pragma unroll
  for (int b = 0; b < BATCH; ++b) {
    #pragma unroll
    for (int off = 32; off > 0; off >>= 1) acc[b] += __shfl_down(acc[b], off);
  }
  if (lane == 0) {
    const float bs = bias ? bias[o] : 0.f;
    #pragma unroll
    for (int b = 0; b < BATCH; ++b) out[b * Oout + o] = acc[b] + bs;
  }
}

__global__ void bn_small_kernel(float* __restrict__ buf, const float* __restrict__ g,
    const float* __restrict__ beta, int O) {
  const int o = blockIdx.x * 256 + threadIdx.x;
  if (o >= O) return;
  float s = 0.f, s2 = 0.f;
  for (int b = 0; b < BATCH; ++b) { float v = buf[b * O + o]; s += v; s2 += v * v; }
  const float m   = s * (1.f / 16.f);
  const float var = s2 * (1.f / 16.f) - m * m;
  const float sc  = rsqrtf(var + 1e-5f) * g[o];
  const float bb  = beta[o];
  for (int b = 0; b < BATCH; ++b) {
    float v = (buf[b * O + o] - m) * sc + bb;
    buf[b * O + o] = (v > 0.f) ? v : 0.2f * v;
  }
}

extern "C" void kernel_launch(void* const* d_in, const int* in_sizes, int n_in,
                              void* d_out, int out_size, void* d_ws, size_t ws_size,
                              hipStream_t stream) {
  const float* x   = (const float*)d_in[0];
  const float* W1  = (const float*)d_in[1];
  const float* g1  = (const float*)d_in[2];
  const float* b1  = (const float*)d_in[3];
  const float* W2  = (const float*)d_in[4];
  const float* g2  = (const float*)d_in[5];
  const float* b2  = (const float*)d_in[6];
  const float* W3  = (const float*)d_in[7];
  const float* g3  = (const float*)d_in[8];
  const float* b3  = (const float*)d_in[9];
  const float* W4  = (const float*)d_in[10];
  const float* g4  = (const float*)d_in[11];
  const float* b4  = (const float*)d_in[12];
  const float* W5  = (const float*)d_in[13];
  const float* g5  = (const float*)d_in[14];
  const float* b5  = (const float*)d_in[15];
  const float* l1W = (const float*)d_in[16];
  const float* g6  = (const float*)d_in[17];
  const float* b6  = (const float*)d_in[18];
  const float* l2W = (const float*)d_in[19];
  const float* l2b = (const float*)d_in[20];
  const float* g7  = (const float*)d_in[21];
  const float* b7  = (const float*)d_in[22];
  const float* l3W = (const float*)d_in[23];
  const float* l3b = (const float*)d_in[24];

  float* ws   = (float*)d_ws;
  float* Xcat = ws;                        // (B,512,N)
  float* H    = Xcat + 8388608;            // (B,1024,N) (layer-5 only)
  float* REG  = H + 16777216;              // overlaid scratch
  float* AGG  = REG;
  unsigned short* AGGT = (unsigned short*)(REG + 2097152);
  unsigned short* XbfT = (unsigned short*)REG;
  int*   IDX  = (int*)(REG + 4194304);
  float* MEAN = (float*)(IDX + 327680);
  float* RSTD = MEAN + 1024;
  float* Z    = RSTD + 1024;
  float* Z1   = Z + 32768;
  float* Z2   = Z1 + 8192;
  unsigned short* W4bf = (unsigned short*)(Z2 + 4096);
  unsigned short* W5bf = W4bf + 32768;

  // knn scratch overlays H (dead until layer 5)
  float* SQ    = H;
  float* PARTV = H + 16384;
  unsigned short* PARTI = (unsigned short*)(PARTV + 1310720);
  unsigned short* XH = (unsigned short*)(H + 1982464);
  unsigned short* XM = (unsigned short*)(H + 1982464 + 1048576);
  unsigned short* XL = (unsigned short*)(H + 1982464 + 2097152);

  const long XS = 512L * 1024;
  const long HS = 1024L * 1024;
  const dim3 knnGrid(16, 4, 16);

  // ---- edge block 1 (C=3, fp32 knn) ----
  compute_sq_kernel<<<dim3(4, 16), 256, 0, stream>>>(x, 3L * 1024, 3, SQ);
  knn_kernel<3><<<knnGrid, 256, 0, stream>>>(x, 3L * 1024, SQ, PARTV, PARTI);
  knn_merge_kernel<<<64, 256, 0, stream>>>(PARTV, PARTI, IDX);
  gather_sum_kernel<<<dim3(4, 1, 16), 256, 0, stream>>>(x, 3L * 1024, 3, IDX, AGG);
  conv_kernel<<<dim3(16, 1, 16), 256, 0, stream>>>(AGG, 3L * 1024, W1, 3, 64, Xcat, XS, 0);
  bn_stats_kernel<<<64, 256, 0, stream>>>(Xcat, XS, 0, MEAN, RSTD);
  bn_apply_kernel<<<dim3(4, 64, 16), 256, 0, stream>>>(Xcat, XS, 0, MEAN, RSTD, g1, b1);

  // ---- edge block 2 (C=64, split-bf16 MFMA knn) ----
  compute_sq_kernel<<<dim3(4, 16), 256, 0, stream>>>(Xcat, XS, 64, SQ);
  transpose_split_kernel<<<dim3(16, 1, 16), 256, 0, stream>>>(Xcat, XS, 64, XH, XM, XL);
  knn_mfma_kernel<64><<<knnGrid, 256, 0, stream>>>(XH, XM, XL, SQ, PARTV, PARTI);
  knn_merge_kernel<<<64, 256, 0, stream>>>(PARTV, PARTI, IDX);
  gather_sum_kernel<<<dim3(4, 8, 16), 256, 0, stream>>>(Xcat, XS, 64, IDX, AGG);
  conv_kernel<<<dim3(16, 1, 16), 256, 0, stream>>>(AGG, 64L * 1024, W2, 64, 64, Xcat, XS, 64);
  bn_stats_kernel<<<64, 256, 0, stream>>>(Xcat, XS, 64, MEAN, RSTD);
  bn_apply_kernel<<<dim3(4, 64, 16), 256, 0, stream>>>(Xcat, XS, 64, MEAN, RSTD, g2, b2);

  // ---- edge block 3 (C=64 -> O=128, split-bf16 MFMA knn) ----
  compute_sq_kernel<<<dim3(4, 16), 256, 0, stream>>>(Xcat + 64L * 1024, XS, 64, SQ);
  transpose_split_kernel<<<dim3(16, 1, 16), 256, 0, stream>>>(Xcat + 64L * 1024, XS, 64, XH, XM, XL);
  knn_mfma_kernel<64><<<knnGrid, 256, 0, stream>>>(XH, XM, XL, SQ, PARTV, PARTI);
  knn_merge_kernel<<<64, 256, 0, stream>>>(PARTV, PARTI, IDX);
  gather_sum_kernel<<<dim3(4, 8, 16), 256, 0, stream>>>(Xcat + 64L * 1024, XS, 64, IDX, AGG);
  conv_kernel<<<dim3(16, 2, 16), 256, 0, stream>>>(AGG, 64L * 1024, W3, 64, 128, Xcat, XS, 128);
  bn_stats_kernel<<<128, 256, 0, stream>>>(Xcat, XS, 128, MEAN, RSTD);
  bn_apply_kernel<<<dim3(4, 128, 16), 256, 0, stream>>>(Xcat, XS, 128, MEAN, RSTD, g3, b3);

  // ---- edge block 4 (C=128 -> O=256, split-bf16 MFMA knn + MFMA conv) ----
  compute_sq_kernel<<<dim3(4, 16), 256, 0, stream>>>(Xcat + 128L * 1024, XS, 128, SQ);
  transpose_split_kernel<<<dim3(16, 2, 16), 256, 0, stream>>>(Xcat + 128L * 1024, XS, 128, XH, XM, XL);
  knn_mfma_kernel<128><<<knnGrid, 256, 0, stream>>>(XH, XM, XL, SQ, PARTV, PARTI);
  knn_merge_kernel<<<64, 256, 0, stream>>>(PARTV, PARTI, IDX);
  gather_sum_kernel<<<dim3(4, 16, 16), 256, 0, stream>>>(Xcat + 128L * 1024, XS, 128, IDX, AGG);
  convert_bf16_kernel<<<128, 256, 0, stream>>>(W4, W4bf, 256 * 128);
  transpose_bf16_kernel<<<dim3(16, 2, 16), 256, 0, stream>>>(AGG, 128L * 1024, 128, AGGT);
  conv_mfma_kernel<<<dim3(8, 2, 16), 256, 0, stream>>>(W4bf, AGGT, 128, Xcat, XS, 256);
  bn_stats_kernel<<<256, 256, 0, stream>>>(Xcat, XS, 256, MEAN, RSTD);
  bn_apply_kernel<<<dim3(4, 256, 16), 256, 0, stream>>>(Xcat, XS, 256, MEAN, RSTD, g4, b4);

  // ---- layer 5 (bf16 MFMA; H written only after knn scratch is dead) ----
  convert_bf16_kernel<<<2048, 256, 0, stream>>>(W5, W5bf, 1024 * 512);
  transpose_bf16_kernel<<<dim3(16, 8, 16), 256, 0, stream>>>(Xcat, XS, 512, XbfT);
  conv_mfma_kernel<<<dim3(8, 8, 16), 256, 0, stream>>>(W5bf, XbfT, 512, H, HS, 0);
  bn_stats_kernel<<<1024, 256, 0, stream>>>(H, HS, 0, MEAN, RSTD);
  bn_pool_kernel<<<dim3(1024, 16), 256, 0, stream>>>(H, MEAN, RSTD, g5, b5, Z);

  // ---- MLP head ----
  fc_wave_kernel<<<128, 256, 0, stream>>>(Z, l1W, nullptr, Z1, 2048, 512);
  bn_small_kernel<<<2, 256, 0, stream>>>(Z1, g6, b6, 512);
  fc_wave_kernel<<<64, 256, 0, stream>>>(Z1, l2W, l2b, Z2, 512, 256);
  bn_small_kernel<<<1, 256, 0, stream>>>(Z2, g7, b7, 256);
  fc_wave_kernel<<<10, 256, 0, stream>>>(Z2, l3W, l3b, (float*)d_out, 256, 40);
}

// Round 9
// 1021.105 us; speedup vs baseline: 4.5048x; 1.0320x over previous
//
#include <hip/hip_runtime.h>
#include <hip/hip_bf16.h>
#include <math.h>

#define NPTS 1024
#define BATCH 16
#define KNN 20

typedef __attribute__((ext_vector_type(8))) short short8;
typedef __attribute__((ext_vector_type(4))) float f32x4;

// ---------------------------------------------------------------------------
// per-point squared norms: sq[b][m] = sum_c X[b,c,m]^2  (fp32, exact-ish)
// ---------------------------------------------------------------------------
__global__ __launch_bounds__(256) void compute_sq_kernel(const float* __restrict__ X,
    long batchStride, int C, float* __restrict__ sq) {
  const int b = blockIdx.y;
  const int m = blockIdx.x * 256 + threadIdx.x;
  const float* Xb = X + (long)b * batchStride;
  float s = 0.f;
  for (int c = 0; c < C; ++c) { float v = Xb[(long)c * NPTS + m]; s += v * v; }
  sq[b * NPTS + m] = s;
}

// ---------------------------------------------------------------------------
// fp32 [b][C][1024] -> three bf16 planes [b][1024][C] (x = hi+mid+lo) PLUS an
// exact fp32 transposed copy XT [b][1024][C] (for vectorized gather).
// ---------------------------------------------------------------------------
__global__ __launch_bounds__(256) void transpose_split_kernel(const float* __restrict__ in,
    long inBatchStride, int C, unsigned short* __restrict__ XH,
    unsigned short* __restrict__ XM, unsigned short* __restrict__ XL,
    float* __restrict__ XT) {
  __shared__ float tile[64][65];
  const int b  = blockIdx.z;
  const int n0 = blockIdx.x * 64, c0 = blockIdx.y * 64;
  const int tid = threadIdx.x;
  const float* ib = in + (long)b * inBatchStride;
  for (int i = tid; i < 4096; i += 256) {
    int r = i >> 6, cn = i & 63;
    tile[r][cn] = ib[(long)(c0 + r) * NPTS + n0 + cn];
  }
  __syncthreads();
  const long pb = (long)b * ((long)NPTS * C);
  for (int i = tid; i < 4096; i += 256) {
    int r = i >> 6, cc = i & 63;
    float f = tile[cc][r];
    __hip_bfloat16 h = __float2bfloat16(f);
    float r1 = f - __bfloat162float(h);
    __hip_bfloat16 m = __float2bfloat16(r1);
    float r2 = r1 - __bfloat162float(m);
    __hip_bfloat16 l = __float2bfloat16(r2);
    const long o = pb + (long)(n0 + r) * C + c0 + cc;
    XH[o] = *(unsigned short*)&h;
    XM[o] = *(unsigned short*)&m;
    XL[o] = *(unsigned short*)&l;
    XT[o] = f;
  }
}

// ---------------------------------------------------------------------------
// knn via split-bf16 MFMA with register-prefetched staging.
// block = (64 queries, 256-cand chunk, batch). inner = hh+hm+mh+mm+hl+lh.
// Staging for stage s+1 is loaded into VGPRs while MFMA/selection run on s;
// barriers only wait on ds_write (lgkm), not global latency.
// ---------------------------------------------------------------------------
template<int C>
__global__ __launch_bounds__(256) void knn_mfma_kernel(
    const unsigned short* __restrict__ XH, const unsigned short* __restrict__ XM,
    const unsigned short* __restrict__ XL, const float* __restrict__ sqg,
    float* __restrict__ PARTV, unsigned short* __restrict__ PARTI) {
  __shared__ __align__(16) unsigned short QP[6][64][40];  // 30720 B
  __shared__ __align__(16) float Dbuf[64][68];            // 17408 B
  float* region = (float*)&QP[0][0][0];                   // merge overlay

  const int b     = blockIdx.z;
  const int q0    = blockIdx.x * 64;
  const int p0    = blockIdx.y * 256;
  const int chunk = blockIdx.y;
  const int tid  = threadIdx.x;
  const int lane = tid & 63, w = tid >> 6;
  const int l16  = lane & 15, quad = lane >> 4;
  const int q = lane, sub = w;

  const long plane = (long)b * ((long)NPTS * C);
  const unsigned short* XHb = XH + plane;
  const unsigned short* XMb = XM + plane;
  const unsigned short* XLb = XL + plane;

  // sq for the Dbuf rows this thread writes: p = p0 + pc*64 + w*16 + quad*4 + r
  float sqw[4][4];
  #pragma unroll
  for (int pci = 0; pci < 4; ++pci)
    #pragma unroll
    for (int r = 0; r < 4; ++r)
      sqw[pci][r] = sqg[b * NPTS + p0 + pci * 64 + w * 16 + quad * 4 + r];

  float topv[KNN];
  int   topi[KNN];
  #pragma unroll
  for (int j = 0; j < KNN; ++j) { topv[j] = -INFINITY; topi[j] = 0x7fffffff; }
  float vmin = -INFINITY;

  const int srow = tid >> 2, sseg = (tid & 3) * 8;
  constexpr int KCN = C / 32;

  // prefetch stage 0
  float4 rg0, rg1, rg2, rg3, rg4, rg5;
  {
    const long qo = (long)(q0 + srow) * C + sseg;
    const long po = (long)(p0 + srow) * C + sseg;
    rg0 = *(const float4*)&XHb[qo];
    rg1 = *(const float4*)&XMb[qo];
    rg2 = *(const float4*)&XLb[qo];
    rg3 = *(const float4*)&XHb[po];
    rg4 = *(const float4*)&XMb[po];
    rg5 = *(const float4*)&XLb[po];
  }

  for (int pci = 0; pci < 4; ++pci) {
    f32x4 acc[4];
    #pragma unroll
    for (int t = 0; t < 4; ++t) acc[t] = (f32x4){0.f, 0.f, 0.f, 0.f};

    for (int kci = 0; kci < KCN; ++kci) {
      __syncthreads();   // prev consumers of QP / Dbuf-selection done
      *(float4*)&QP[0][srow][sseg] = rg0;
      *(float4*)&QP[1][srow][sseg] = rg1;
      *(float4*)&QP[2][srow][sseg] = rg2;
      *(float4*)&QP[3][srow][sseg] = rg3;
      *(float4*)&QP[4][srow][sseg] = rg4;
      *(float4*)&QP[5][srow][sseg] = rg5;
      __syncthreads();
      // issue prefetch for next stage (overlaps with MFMA below)
      const int ns = pci * KCN + kci + 1;
      if (ns < 4 * KCN) {
        const int npc = ns / KCN, nkc = (ns % KCN) * 32;
        const long qo = (long)(q0 + srow) * C + nkc + sseg;
        const long po = (long)(p0 + npc * 64 + srow) * C + nkc + sseg;
        rg0 = *(const float4*)&XHb[qo];
        rg1 = *(const float4*)&XMb[qo];
        rg2 = *(const float4*)&XLb[qo];
        rg3 = *(const float4*)&XHb[po];
        rg4 = *(const float4*)&XMb[po];
        rg5 = *(const float4*)&XLb[po];
      }
      const short8 ph = *(const short8*)&QP[3][w * 16 + l16][quad * 8];
      const short8 pm = *(const short8*)&QP[4][w * 16 + l16][quad * 8];
      const short8 pl = *(const short8*)&QP[5][w * 16 + l16][quad * 8];
      #pragma unroll
      for (int t = 0; t < 4; ++t) {
        const short8 qh = *(const short8*)&QP[0][t * 16 + l16][quad * 8];
        const short8 qm = *(const short8*)&QP[1][t * 16 + l16][quad * 8];
        const short8 ql = *(const short8*)&QP[2][t * 16 + l16][quad * 8];
        acc[t] = __builtin_amdgcn_mfma_f32_16x16x32_bf16(ph, qh, acc[t], 0, 0, 0);
        acc[t] = __builtin_amdgcn_mfma_f32_16x16x32_bf16(ph, qm, acc[t], 0, 0, 0);
        acc[t] = __builtin_amdgcn_mfma_f32_16x16x32_bf16(pm, qh, acc[t], 0, 0, 0);
        acc[t] = __builtin_amdgcn_mfma_f32_16x16x32_bf16(pm, qm, acc[t], 0, 0, 0);
        acc[t] = __builtin_amdgcn_mfma_f32_16x16x32_bf16(ph, ql, acc[t], 0, 0, 0);
        acc[t] = __builtin_amdgcn_mfma_f32_16x16x32_bf16(pl, qh, acc[t], 0, 0, 0);
      }
    }
    // Dbuf write with folded -sq: Dbuf holds final ranking value
    #pragma unroll
    for (int t = 0; t < 4; ++t)
      #pragma unroll
      for (int r = 0; r < 4; ++r)
        Dbuf[w * 16 + quad * 4 + r][t * 16 + l16] = fmaf(2.f, acc[t][r], -sqw[pci][r]);
    __syncthreads();

    // selection: thread (q, sub) scans rows [sub*16, sub*16+16)
    #pragma unroll 4
    for (int i = 0; i < 16; ++i) {
      const float v = Dbuf[sub * 16 + i][q];
      if (v > vmin) {
        float cv = v; int ci = p0 + pci * 64 + sub * 16 + i;
        bool ins = false;
        #pragma unroll
        for (int j = 0; j < KNN; ++j) {
          const float tv = topv[j]; const int ti = topi[j];
          const bool gt = ins || (cv > tv);
          topv[j] = gt ? cv : tv;
          topi[j] = gt ? ci : ti;
          cv = gt ? tv : cv;
          ci = gt ? ti : ci;
          ins = gt;
        }
        vmin = topv[KNN - 1];
      }
    }
  }

  // in-block 4-way merge -> sorted partial top-20 for this chunk
  __syncthreads();
  {
    float* mv = region;
    unsigned short* mi = (unsigned short*)(region + 5120);
    const int slot = q * 4 + sub;
    #pragma unroll
    for (int j = 0; j < KNN; ++j) { mv[j * 256 + slot] = topv[j]; mi[j * 256 + slot] = (unsigned short)topi[j]; }
  }
  __syncthreads();
  if (tid < 64) {
    const float* mv = region;
    const unsigned short* mi = (const unsigned short*)(region + 5120);
    int p0_ = 0, p1 = 0, p2 = 0, p3 = 0;
    float* opv = PARTV + (((long)(b * NPTS + q0 + tid)) * 4 + chunk) * KNN;
    unsigned short* opi = PARTI + (((long)(b * NPTS + q0 + tid)) * 4 + chunk) * KNN;
    for (int j = 0; j < KNN; ++j) {
      float bv = -INFINITY; int bi = 0x7fffffff; int bs = 0;
      if (p0_ < KNN) { float v = mv[p0_ * 256 + tid * 4 + 0]; int i = mi[p0_ * 256 + tid * 4 + 0];
        if (v > bv || (v == bv && i < bi)) { bv = v; bi = i; bs = 0; } }
      if (p1 < KNN) { float v = mv[p1 * 256 + tid * 4 + 1]; int i = mi[p1 * 256 + tid * 4 + 1];
        if (v > bv || (v == bv && i < bi)) { bv = v; bi = i; bs = 1; } }
      if (p2 < KNN) { float v = mv[p2 * 256 + tid * 4 + 2]; int i = mi[p2 * 256 + tid * 4 + 2];
        if (v > bv || (v == bv && i < bi)) { bv = v; bi = i; bs = 2; } }
      if (p3 < KNN) { float v = mv[p3 * 256 + tid * 4 + 3]; int i = mi[p3 * 256 + tid * 4 + 3];
        if (v > bv || (v == bv && i < bi)) { bv = v; bi = i; bs = 3; } }
      p0_ += (bs == 0); p1 += (bs == 1); p2 += (bs == 2); p3 += (bs == 3);
      opv[j] = bv; opi[j] = (unsigned short)bi;
    }
  }
}

// ---------------------------------------------------------------------------
// fp32 knn (C=3 only)
// ---------------------------------------------------------------------------
template<int C>
__global__ __launch_bounds__(256) void knn_kernel(const float* __restrict__ X,
    long batchStride, const float* __restrict__ sqg,
    float* __restrict__ PARTV, unsigned short* __restrict__ PARTI) {
  constexpr int CT = (C < 64) ? C : 64;
  constexpr int REGF = (2 * CT * 64 > 7680) ? 2 * CT * 64 : 7680;
  __shared__ float Dbuf[64][68];
  __shared__ float region[REGF];

  float* qbuf = region;
  float* pbuf = region + CT * 64;

  const int b     = blockIdx.z;
  const int q0    = blockIdx.x * 64;
  const int p0    = blockIdx.y * 256;
  const int chunk = blockIdx.y;
  const int tid = threadIdx.x;
  const int ty  = tid >> 4, tx = tid & 15;
  const int q   = tid & 63;
  const int sub = tid >> 6;
  const float* Xb = X + (long)b * batchStride;
  const float* sqb = sqg + b * NPTS;

  float topv[KNN];
  int   topi[KNN];
  #pragma unroll
  for (int j = 0; j < KNN; ++j) { topv[j] = -INFINITY; topi[j] = 0x7fffffff; }
  float vmin = -INFINITY;

  for (int pc = p0; pc < p0 + 256; pc += 64) {
    float acc[4][4] = {};
    for (int cc = 0; cc < C; cc += CT) {
      __syncthreads();
      for (int t = tid; t < 64 * CT; t += 256) {
        int c = t >> 6, m = t & 63;
        qbuf[c * 64 + m] = Xb[(long)(cc + c) * NPTS + q0 + m];
        pbuf[c * 64 + m] = Xb[(long)(cc + c) * NPTS + pc + m];
      }
      __syncthreads();
      #pragma unroll
      for (int c = 0; c < CT; ++c) {
        const float4 qv = *(const float4*)&qbuf[c * 64 + ty * 4];
        const float4 pv = *(const float4*)&pbuf[c * 64 + tx * 4];
        acc[0][0] += qv.x * pv.x; acc[0][1] += qv.x * pv.y; acc[0][2] += qv.x * pv.z; acc[0][3] += qv.x * pv.w;
        acc[1][0] += qv.y * pv.x; acc[1][1] += qv.y * pv.y; acc[1][2] += qv.y * pv.z; acc[1][3] += qv.y * pv.w;
        acc[2][0] += qv.z * pv.x; acc[2][1] += qv.z * pv.y; acc[2][2] += qv.z * pv.z; acc[2][3] += qv.z * pv.w;
        acc[3][0] += qv.w * pv.x; acc[3][1] += qv.w * pv.y; acc[3][2] += qv.w * pv.z; acc[3][3] += qv.w * pv.w;
      }
    }
    #pragma unroll
    for (int j = 0; j < 4; ++j) {
      const int p = pc + tx * 4 + j;
      const float sq = sqb[p];
      float4 dv;
      dv.x = 2.f * acc[0][j] - sq;
      dv.y = 2.f * acc[1][j] - sq;
      dv.z = 2.f * acc[2][j] - sq;
      dv.w = 2.f * acc[3][j] - sq;
      *(float4*)&Dbuf[tx * 4 + j][ty * 4] = dv;
    }
    __syncthreads();

    #pragma unroll 4
    for (int i = 0; i < 16; ++i) {
      const float v = Dbuf[sub * 16 + i][q];
      if (v > vmin) {
        float cv = v; int ci = pc + sub * 16 + i;
        bool ins = false;
        #pragma unroll
        for (int j = 0; j < KNN; ++j) {
          const float tv = topv[j]; const int ti = topi[j];
          const bool gt = ins || (cv > tv);
          topv[j] = gt ? cv : tv;
          topi[j] = gt ? ci : ti;
          cv = gt ? tv : cv;
          ci = gt ? ti : ci;
          ins = gt;
        }
        vmin = topv[KNN - 1];
      }
    }
  }

  __syncthreads();
  {
    float* mv = region;
    unsigned short* mi = (unsigned short*)(region + 5120);
    const int slot = q * 4 + sub;
    #pragma unroll
    for (int j = 0; j < KNN; ++j) { mv[j * 256 + slot] = topv[j]; mi[j * 256 + slot] = (unsigned short)topi[j]; }
  }
  __syncthreads();
  if (tid < 64) {
    const float* mv = region;
    const unsigned short* mi = (const unsigned short*)(region + 5120);
    int p0_ = 0, p1 = 0, p2 = 0, p3 = 0;
    float* opv = PARTV + (((long)(b * NPTS + q0 + tid)) * 4 + chunk) * KNN;
    unsigned short* opi = PARTI + (((long)(b * NPTS + q0 + tid)) * 4 + chunk) * KNN;
    for (int j = 0; j < KNN; ++j) {
      float bv = -INFINITY; int bi = 0x7fffffff; int bs = 0;
      if (p0_ < KNN) { float v = mv[p0_ * 256 + tid * 4 + 0]; int i = mi[p0_ * 256 + tid * 4 + 0];
        if (v > bv || (v == bv && i < bi)) { bv = v; bi = i; bs = 0; } }
      if (p1 < KNN) { float v = mv[p1 * 256 + tid * 4 + 1]; int i = mi[p1 * 256 + tid * 4 + 1];
        if (v > bv || (v == bv && i < bi)) { bv = v; bi = i; bs = 1; } }
      if (p2 < KNN) { float v = mv[p2 * 256 + tid * 4 + 2]; int i = mi[p2 * 256 + tid * 4 + 2];
        if (v > bv || (v == bv && i < bi)) { bv = v; bi = i; bs = 2; } }
      if (p3 < KNN) { float v = mv[p3 * 256 + tid * 4 + 3]; int i = mi[p3 * 256 + tid * 4 + 3];
        if (v > bv || (v == bv && i < bi)) { bv = v; bi = i; bs = 3; } }
      p0_ += (bs == 0); p1 += (bs == 1); p2 += (bs == 2); p3 += (bs == 3);
      opv[j] = bv; opi[j] = (unsigned short)bi;
    }
  }
}

// ---------------------------------------------------------------------------
// merge 4 sorted partial lists per query -> final top-20 indices.
// ---------------------------------------------------------------------------
__global__ __launch_bounds__(256) void knn_merge_kernel(const float* __restrict__ PARTV,
    const unsigned short* __restrict__ PARTI, int* __restrict__ idxOut) {
  const int idx = blockIdx.x * 256 + threadIdx.x;
  const float* pv = PARTV + (long)idx * 4 * KNN;
  const unsigned short* pi = PARTI + (long)idx * 4 * KNN;
  int p0 = 0, p1 = 0, p2 = 0, p3 = 0;
  int* op = idxOut + (long)idx * KNN;
  for (int j = 0; j < KNN; ++j) {
    float bv = -INFINITY; int bi = 0x7fffffff; int bs = 0;
    if (p0 < KNN) { float v = pv[0 * KNN + p0]; int i = pi[0 * KNN + p0];
      if (v > bv || (v == bv && i < bi)) { bv = v; bi = i; bs = 0; } }
    if (p1 < KNN) { float v = pv[1 * KNN + p1]; int i = pi[1 * KNN + p1];
      if (v > bv || (v == bv && i < bi)) { bv = v; bi = i; bs = 1; } }
    if (p2 < KNN) { float v = pv[2 * KNN + p2]; int i = pi[2 * KNN + p2];
      if (v > bv || (v == bv && i < bi)) { bv = v; bi = i; bs = 2; } }
    if (p3 < KNN) { float v = pv[3 * KNN + p3]; int i = pi[3 * KNN + p3];
      if (v > bv || (v == bv && i < bi)) { bv = v; bi = i; bs = 3; } }
    p0 += (bs == 0); p1 += (bs == 1); p2 += (bs == 2); p3 += (bs == 3);
    op[j] = bi;
  }
}

// ---------------------------------------------------------------------------
// gather + sum (scalar path, C=3 only)
// ---------------------------------------------------------------------------
__global__ __launch_bounds__(256) void gather_sum_kernel(const float* __restrict__ X,
    long batchStride, int C, const int* __restrict__ idx, float* __restrict__ agg) {
  __shared__ int sidx[256][KNN + 1];
  const int b     = blockIdx.z;
  const int n0    = blockIdx.x * 256;
  const int cbase = blockIdx.y * 8;
  const int tid   = threadIdx.x;
  const int* ib = idx + ((long)(b * NPTS + n0)) * KNN;
  for (int t = tid; t < 256 * KNN; t += 256) {
    sidx[t / KNN][t % KNN] = ib[t];
  }
  __syncthreads();
  const float* Xb = X + (long)b * batchStride;
  float* ab = agg + (long)b * C * NPTS;
  const int cend = min(cbase + 8, C);
  for (int c = cbase; c < cend; ++c) {
    const float* row = Xb + (long)c * NPTS;
    float s = 0.f;
    #pragma unroll
    for (int j = 0; j < KNN; ++j) s += row[sidx[tid][j]];
    ab[(long)c * NPTS + n0 + tid] = s;
  }
}

// ---------------------------------------------------------------------------
// vectorized gather from fp32 transposed XT [b][n][c]: 8 channels per
// neighbor via two float4 loads. Exact same fp32 sums as scalar path.
// Grid (4 n-chunks, C/16, batch); each block covers 16 channels.
// ---------------------------------------------------------------------------
__global__ __launch_bounds__(256) void gather_sum_vec_kernel(const float* __restrict__ XT,
    int C, const int* __restrict__ idx, float* __restrict__ agg) {
  __shared__ int sidx[256][KNN + 1];
  const int b     = blockIdx.z;
  const int n0    = blockIdx.x * 256;
  const int cbase = blockIdx.y * 16;
  const int tid   = threadIdx.x;
  const int* ib = idx + ((long)(b * NPTS + n0)) * KNN;
  for (int t = tid; t < 256 * KNN; t += 256) {
    sidx[t / KNN][t % KNN] = ib[t];
  }
  __syncthreads();
  const float* Xb = XT + (long)b * ((long)NPTS * C);
  float* ab = agg + (long)b * C * NPTS;
  const int cend = min(cbase + 16, C);
  for (int c = cbase; c < cend; c += 8) {
    float a0 = 0.f, a1 = 0.f, a2 = 0.f, a3 = 0.f, a4 = 0.f, a5 = 0.f, a6 = 0.f, a7 = 0.f;
    #pragma unroll
    for (int j = 0; j < KNN; ++j) {
      const float* rp = Xb + (long)sidx[tid][j] * C + c;
      const float4 v0 = *(const float4*)rp;
      const float4 v1 = *(const float4*)(rp + 4);
      a0 += v0.x; a1 += v0.y; a2 += v0.z; a3 += v0.w;
      a4 += v1.x; a5 += v1.y; a6 += v1.z; a7 += v1.w;
    }
    float* op = ab + (long)c * NPTS + n0 + tid;
    op[0 * NPTS] = a0; op[1 * NPTS] = a1; op[2 * NPTS] = a2; op[3 * NPTS] = a3;
    op[4 * NPTS] = a4; op[5 * NPTS] = a5; op[6 * NPTS] = a6; op[7 * NPTS] = a7;
  }
}

// ---------------------------------------------------------------------------
// fp32 conv (conv1-3: outputs feed knn, stay fp32)
// ---------------------------------------------------------------------------
__global__ __launch_bounds__(256) void conv_kernel(const float* __restrict__ Xin, long inBatchStride,
    const float* __restrict__ W, int C, int O,
    float* __restrict__ Yout, long outBatchStride, int outChanOffset) {
  __shared__ float Wt[32][68];
  __shared__ float Xt[32][68];
  const int b   = blockIdx.z;
  const int o0  = blockIdx.y * 64;
  const int n0  = blockIdx.x * 64;
  const int tid = threadIdx.x;
  const int ty  = tid >> 4, tx = tid & 15;
  const float* Xb = Xin + (long)b * inBatchStride;
  float acc[4][4] = {};
  for (int cc = 0; cc < C; cc += 32) {
    const int cw = min(32, C - cc);
    __syncthreads();
    for (int t = tid; t < 64 * 32; t += 256) {
      int oo = t >> 5, kk = t & 31;
      Wt[kk][oo] = (kk < cw) ? W[(long)(o0 + oo) * C + cc + kk] : 0.f;
    }
    for (int t = tid; t < 32 * 64; t += 256) {
      int kk = t >> 6, nn = t & 63;
      Xt[kk][nn] = (kk < cw) ? Xb[(long)(cc + kk) * NPTS + n0 + nn] : 0.f;
    }
    __syncthreads();
    #pragma unroll
    for (int kk = 0; kk < 32; ++kk) {
      const float4 wv = *(const float4*)&Wt[kk][ty * 4];
      const float4 xv = *(const float4*)&Xt[kk][tx * 4];
      acc[0][0] += wv.x * xv.x; acc[0][1] += wv.x * xv.y; acc[0][2] += wv.x * xv.z; acc[0][3] += wv.x * xv.w;
      acc[1][0] += wv.y * xv.x; acc[1][1] += wv.y * xv.y; acc[1][2] += wv.y * xv.z; acc[1][3] += wv.y * xv.w;
      acc[2][0] += wv.z * xv.x; acc[2][1] += wv.z * xv.y; acc[2][2] += wv.z * xv.z; acc[2][3] += wv.z * xv.w;
      acc[3][0] += wv.w * xv.x; acc[3][1] += wv.w * xv.y; acc[3][2] += wv.w * xv.z; acc[3][3] += wv.w * xv.w;
    }
  }
  #pragma unroll
  for (int i = 0; i < 4; ++i) {
    float4 v = make_float4(acc[i][0], acc[i][1], acc[i][2], acc[i][3]);
    *(float4*)&Yout[(long)b * outBatchStride + (long)(outChanOffset + o0 + ty * 4 + i) * NPTS + n0 + tx * 4] = v;
  }
}

// ---------------------------------------------------------------------------
// fp32 [b][C][1024] -> bf16 [b][1024][C] transpose (for MFMA conv B operand)
// ---------------------------------------------------------------------------
__global__ __launch_bounds__(256) void transpose_bf16_kernel(const float* __restrict__ in,
    long inBatchStride, int C, unsigned short* __restrict__ outT) {
  __shared__ float tile[64][65];
  const int b  = blockIdx.z;
  const int n0 = blockIdx.x * 64, c0 = blockIdx.y * 64;
  const int tid = threadIdx.x;
  const float* ib = in + (long)b * inBatchStride;
  for (int i = tid; i < 4096; i += 256) {
    int r = i >> 6, cn = i & 63;
    tile[r][cn] = ib[(long)(c0 + r) * NPTS + n0 + cn];
  }
  __syncthreads();
  unsigned short* ob = outT + (long)b * ((long)NPTS * C);
  for (int i = tid; i < 4096; i += 256) {
    int r = i >> 6, cc = i & 63;
    __hip_bfloat16 h = __float2bfloat16(tile[cc][r]);
    ob[(long)(n0 + r) * C + c0 + cc] = *(unsigned short*)&h;
  }
}

// ---------------------------------------------------------------------------
// fp32 -> bf16 elementwise (weights)
// ---------------------------------------------------------------------------
__global__ void convert_bf16_kernel(const float* __restrict__ in,
                                    unsigned short* __restrict__ out, int n) {
  int i = blockIdx.x * 256 + threadIdx.x;
  if (i < n) { __hip_bfloat16 h = __float2bfloat16(in[i]); out[i] = *(unsigned short*)&h; }
}

// ---------------------------------------------------------------------------
// bf16 MFMA conv (conv4/conv5: outputs never feed top-k)
// ---------------------------------------------------------------------------
__global__ __launch_bounds__(256) void conv_mfma_kernel(const unsigned short* __restrict__ Wbf,
    const unsigned short* __restrict__ XT, int C,
    float* __restrict__ Yout, long outBatchStride, int outChanOffset) {
  __shared__ unsigned short Wl[128][40];
  __shared__ unsigned short Xl[128][40];
  const int b  = blockIdx.z;
  const int o0 = blockIdx.y * 128;
  const int n0 = blockIdx.x * 128;
  const int tid  = threadIdx.x;
  const int lane = tid & 63, wid = tid >> 6;
  const int wo = (wid >> 1) * 64, wn = (wid & 1) * 64;
  const int l16 = lane & 15, quad = lane >> 4;
  const unsigned short* Wg = Wbf + (long)o0 * C;
  const unsigned short* Xg = XT + (long)b * ((long)NPTS * C) + (long)n0 * C;

  f32x4 acc[4][4];
  #pragma unroll
  for (int i = 0; i < 4; ++i)
    #pragma unroll
    for (int j = 0; j < 4; ++j) acc[i][j] = (f32x4){0.f, 0.f, 0.f, 0.f};

  for (int kk = 0; kk < C; kk += 32) {
    __syncthreads();
    #pragma unroll
    for (int it = 0; it < 2; ++it) {
      const int id = tid + it * 256;
      const int r = id >> 2, qq = id & 3;
      const float4 va = *(const float4*)&Wg[(long)r * C + kk + qq * 8];
      const float4 vb = *(const float4*)&Xg[(long)r * C + kk + qq * 8];
      *(float4*)&Wl[r][qq * 8] = va;
      *(float4*)&Xl[r][qq * 8] = vb;
    }
    __syncthreads();
    short8 af[4], bfr[4];
    #pragma unroll
    for (int i = 0; i < 4; ++i) af[i]  = *(const short8*)&Wl[wo + i * 16 + l16][quad * 8];
    #pragma unroll
    for (int j = 0; j < 4; ++j) bfr[j] = *(const short8*)&Xl[wn + j * 16 + l16][quad * 8];
    #pragma unroll
    for (int i = 0; i < 4; ++i)
      #pragma unroll
      for (int j = 0; j < 4; ++j)
        acc[i][j] = __builtin_amdgcn_mfma_f32_16x16x32_bf16(af[i], bfr[j], acc[i][j], 0, 0, 0);
  }

  float* Yb = Yout + (long)b * outBatchStride + (long)outChanOffset * NPTS;
  #pragma unroll
  for (int i = 0; i < 4; ++i) {
    #pragma unroll
    for (int r = 0; r < 4; ++r) {
      const int o = o0 + wo + i * 16 + quad * 4 + r;
      float* row = Yb + (long)o * NPTS + n0 + wn;
      #pragma unroll
      for (int j = 0; j < 4; ++j) row[j * 16 + l16] = acc[i][j][r];
    }
  }
}

// ---------------------------------------------------------------------------
// BN stats / apply / pool
// ---------------------------------------------------------------------------
__global__ __launch_bounds__(256) void bn_stats_kernel(const float* __restrict__ Y, long batchStride,
    int chanOffset, float* __restrict__ meanOut, float* __restrict__ rstdOut) {
  const int o   = blockIdx.x;
  const int tid = threadIdx.x;
  const float* base = Y + (long)(chanOffset + o) * NPTS;
  float s = 0.f, s2 = 0.f;
  for (int b = 0; b < BATCH; ++b) {
    const float* p = base + (long)b * batchStride;
    for (int t = tid; t < NPTS; t += 256) { float v = p[t]; s += v; s2 += v * v; }
  }
  for (int off = 32; off > 0; off >>= 1) { s += __shfl_down(s, off); s2 += __shfl_down(s2, off); }
  __shared__ float r1[4], r2[4];
  const int wid = tid >> 6;
  if ((tid & 63) == 0) { r1[wid] = s; r2[wid] = s2; }
  __syncthreads();
  if (tid == 0) {
    s  = r1[0] + r1[1] + r1[2] + r1[3];
    s2 = r2[0] + r2[1] + r2[2] + r2[3];
    float m   = s * (1.f / 16384.f);
    float var = s2 * (1.f / 16384.f) - m * m;
    meanOut[o] = m;
    rstdOut[o] = rsqrtf(var + 1e-5f);
  }
}

__global__ __launch_bounds__(256) void bn_apply_kernel(float* __restrict__ Y, long batchStride, int chanOffset,
    const float* __restrict__ meanB, const float* __restrict__ rstdB,
    const float* __restrict__ g, const float* __restrict__ beta) {
  const int n = blockIdx.x * 256 + threadIdx.x;
  const int o = blockIdx.y;
  const int b = blockIdx.z;
  float* p = Y + (long)b * batchStride + (long)(chanOffset + o) * NPTS;
  const float sc = rstdB[o] * g[o];
  float v = (p[n] - meanB[o]) * sc + beta[o];
  p[n] = (v > 0.f) ? v : 0.2f * v;
}

__global__ __launch_bounds__(256) void bn_pool_kernel(const float* __restrict__ H,
    const float* __restrict__ meanB, const float* __restrict__ rstdB,
    const float* __restrict__ g, const float* __restrict__ beta,
    float* __restrict__ Z) {
  const int o   = blockIdx.x;
  const int b   = blockIdx.y;
  const int tid = threadIdx.x;
  const float* p = H + (long)b * (1024L * NPTS) + (long)o * NPTS;
  const float sc = rstdB[o] * g[o], mu = meanB[o], bb = beta[o];
  float mx = -INFINITY, s = 0.f;
  for (int t = tid; t < NPTS; t += 256) {
    float v = (p[t] - mu) * sc + bb;
    v = (v > 0.f) ? v : 0.2f * v;
    mx = fmaxf(mx, v);
    s += v;
  }
  for (int off = 32; off > 0; off >>= 1) { mx = fmaxf(mx, __shfl_down(mx, off)); s += __shfl_down(s, off); }
  __shared__ float rm[4], rs[4];
  const int wid = tid >> 6;
  if ((tid & 63) == 0) { rm[wid] = mx; rs[wid] = s; }
  __syncthreads();
  if (tid == 0) {
    mx = fmaxf(fmaxf(rm[0], rm[1]), fmaxf(rm[2], rm[3]));
    s  = rs[0] + rs[1] + rs[2] + rs[3];
    Z[(long)b * 2048 + o]        = mx;
    Z[(long)b * 2048 + 1024 + o] = s * (1.f / 1024.f);
  }
}

// ---------------------------------------------------------------------------
// FC: one wave per output channel, all 16 batches per wave
// ---------------------------------------------------------------------------
__global__ __launch_bounds__(256) void fc_wave_kernel(const float* __restrict__ in,
    const float* __restrict__ Wm, const float* __restrict__ bias,
    float* __restrict__ out, int Cin, int Oout) {
  const int wid  = threadIdx.x >> 6;
  const int lane = threadIdx.x & 63;
  const int o = blockIdx.x * 4 + wid;
  if (o >= Oout) return;
  const float* wp = Wm + (long)o * Cin;
  float acc[BATCH];
  #pragma unroll
  for (int b = 0; b < BATCH; ++b) acc[b] = 0.f;
  for (int c = lane; c < Cin; c += 64) {
    const float w = wp[c];
    #pragma unroll
    for (int b = 0; b < BATCH; ++b) acc[b] += w * in[b * Cin + c];
  }
  #pragma unroll
  for (int b = 0; b < BATCH; ++b) {
    #pragma unroll
    for (int off = 32; off > 0; off >>= 1) acc[b] += __shfl_down(acc[b], off);
  }
  if (lane == 0) {
    const float bs = bias ? bias[o] : 0.f;
    #pragma unroll
    for (int b = 0; b < BATCH; ++b) out[b * Oout + o] = acc[b] + bs;
  }
}

__global__ void bn_small_kernel(float* __restrict__ buf, const float* __restrict__ g,
    const float* __restrict__ beta, int O) {
  const int o = blockIdx.x * 256 + threadIdx.x;
  if (o >= O) return;
  float s = 0.f, s2 = 0.f;
  for (int b = 0; b < BATCH; ++b) { float v = buf[b * O + o]; s += v; s2 += v * v; }
  const float m   = s * (1.f / 16.f);
  const float var = s2 * (1.f / 16.f) - m * m;
  const float sc  = rsqrtf(var + 1e-5f) * g[o];
  const float bb  = beta[o];
  for (int b = 0; b < BATCH; ++b) {
    float v = (buf[b * O + o] - m) * sc + bb;
    buf[b * O + o] = (v > 0.f) ? v : 0.2f * v;
  }
}

extern "C" void kernel_launch(void* const* d_in, const int* in_sizes, int n_in,
                              void* d_out, int out_size, void* d_ws, size_t ws_size,
                              hipStream_t stream) {
  const float* x   = (const float*)d_in[0];
  const float* W1  = (const float*)d_in[1];
  const float* g1  = (const float*)d_in[2];
  const float* b1  = (const float*)d_in[3];
  const float* W2  = (const float*)d_in[4];
  const float* g2  = (const float*)d_in[5];
  const float* b2  = (const float*)d_in[6];
  const float* W3  = (const float*)d_in[7];
  const float* g3  = (const float*)d_in[8];
  const float* b3  = (const float*)d_in[9];
  const float* W4  = (const float*)d_in[10];
  const float* g4  = (const float*)d_in[11];
  const float* b4  = (const float*)d_in[12];
  const float* W5  = (const float*)d_in[13];
  const float* g5  = (const float*)d_in[14];
  const float* b5  = (const float*)d_in[15];
  const float* l1W = (const float*)d_in[16];
  const float* g6  = (const float*)d_in[17];
  const float* b6  = (const float*)d_in[18];
  const float* l2W = (const float*)d_in[19];
  const float* l2b = (const float*)d_in[20];
  const float* g7  = (const float*)d_in[21];
  const float* b7  = (const float*)d_in[22];
  const float* l3W = (const float*)d_in[23];
  const float* l3b = (const float*)d_in[24];

  float* ws   = (float*)d_ws;
  float* Xcat = ws;                        // (B,512,N)
  float* H    = Xcat + 8388608;            // (B,1024,N) (layer-5 only)
  float* REG  = H + 16777216;              // overlaid scratch
  float* AGG  = REG;
  unsigned short* AGGT = (unsigned short*)(REG + 2097152);
  unsigned short* XbfT = (unsigned short*)REG;
  int*   IDX  = (int*)(REG + 4194304);
  float* MEAN = (float*)(IDX + 327680);
  float* RSTD = MEAN + 1024;
  float* Z    = RSTD + 1024;
  float* Z1   = Z + 32768;
  float* Z2   = Z1 + 8192;
  unsigned short* W4bf = (unsigned short*)(Z2 + 4096);
  unsigned short* W5bf = W4bf + 32768;

  // knn scratch overlays H (dead until layer 5)
  float* SQ    = H;                                      // 16,384 f
  float* PARTV = H + 16384;                              // 1,310,720 f
  unsigned short* PARTI = (unsigned short*)(PARTV + 1310720); // 655,360 f worth
  unsigned short* XH = (unsigned short*)(H + 1982464);   // 1,048,576 f each plane
  unsigned short* XM = (unsigned short*)(H + 1982464 + 1048576);
  unsigned short* XL = (unsigned short*)(H + 1982464 + 2097152);
  float* XTf = H + 1982464 + 3145728;                    // fp32 transposed, 2,097,152 f

  const long XS = 512L * 1024;
  const long HS = 1024L * 1024;
  const dim3 knnGrid(16, 4, 16);

  // ---- edge block 1 (C=3, fp32 knn) ----
  compute_sq_kernel<<<dim3(4, 16), 256, 0, stream>>>(x, 3L * 1024, 3, SQ);
  knn_kernel<3><<<knnGrid, 256, 0, stream>>>(x, 3L * 1024, SQ, PARTV, PARTI);
  knn_merge_kernel<<<64, 256, 0, stream>>>(PARTV, PARTI, IDX);
  gather_sum_kernel<<<dim3(4, 1, 16), 256, 0, stream>>>(x, 3L * 1024, 3, IDX, AGG);
  conv_kernel<<<dim3(16, 1, 16), 256, 0, stream>>>(AGG, 3L * 1024, W1, 3, 64, Xcat, XS, 0);
  bn_stats_kernel<<<64, 256, 0, stream>>>(Xcat, XS, 0, MEAN, RSTD);
  bn_apply_kernel<<<dim3(4, 64, 16), 256, 0, stream>>>(Xcat, XS, 0, MEAN, RSTD, g1, b1);

  // ---- edge block 2 (C=64, split-bf16 MFMA knn) ----
  compute_sq_kernel<<<dim3(4, 16), 256, 0, stream>>>(Xcat, XS, 64, SQ);
  transpose_split_kernel<<<dim3(16, 1, 16), 256, 0, stream>>>(Xcat, XS, 64, XH, XM, XL, XTf);
  knn_mfma_kernel<64><<<knnGrid, 256, 0, stream>>>(XH, XM, XL, SQ, PARTV, PARTI);
  knn_merge_kernel<<<64, 256, 0, stream>>>(PARTV, PARTI, IDX);
  gather_sum_vec_kernel<<<dim3(4, 4, 16), 256, 0, stream>>>(XTf, 64, IDX, AGG);
  conv_kernel<<<dim3(16, 1, 16), 256, 0, stream>>>(AGG, 64L * 1024, W2, 64, 64, Xcat, XS, 64);
  bn_stats_kernel<<<64, 256, 0, stream>>>(Xcat, XS, 64, MEAN, RSTD);
  bn_apply_kernel<<<dim3(4, 64, 16), 256, 0, stream>>>(Xcat, XS, 64, MEAN, RSTD, g2, b2);

  // ---- edge block 3 (C=64 -> O=128, split-bf16 MFMA knn) ----
  compute_sq_kernel<<<dim3(4, 16), 256, 0, stream>>>(Xcat + 64L * 1024, XS, 64, SQ);
  transpose_split_kernel<<<dim3(16, 1, 16), 256, 0, stream>>>(Xcat + 64L * 1024, XS, 64, XH, XM, XL, XTf);
  knn_mfma_kernel<64><<<knnGrid, 256, 0, stream>>>(XH, XM, XL, SQ, PARTV, PARTI);
  knn_merge_kernel<<<64, 256, 0, stream>>>(PARTV, PARTI, IDX);
  gather_sum_vec_kernel<<<dim3(4, 4, 16), 256, 0, stream>>>(XTf, 64, IDX, AGG);
  conv_kernel<<<dim3(16, 2, 16), 256, 0, stream>>>(AGG, 64L * 1024, W3, 64, 128, Xcat, XS, 128);
  bn_stats_kernel<<<128, 256, 0, stream>>>(Xcat, XS, 128, MEAN, RSTD);
  bn_apply_kernel<<<dim3(4, 128, 16), 256, 0, stream>>>(Xcat, XS, 128, MEAN, RSTD, g3, b3);

  // ---- edge block 4 (C=128 -> O=256, split-bf16 MFMA knn + MFMA conv) ----
  compute_sq_kernel<<<dim3(4, 16), 256, 0, stream>>>(Xcat + 128L * 1024, XS, 128, SQ);
  transpose_split_kernel<<<dim3(16, 2, 16), 256, 0, stream>>>(Xcat + 128L * 1024, XS, 128, XH, XM, XL, XTf);
  knn_mfma_kernel<128><<<knnGrid, 256, 0, stream>>>(XH, XM, XL, SQ, PARTV, PARTI);
  knn_merge_kernel<<<64, 256, 0, stream>>>(PARTV, PARTI, IDX);
  gather_sum_vec_kernel<<<dim3(4, 8, 16), 256, 0, stream>>>(XTf, 128, IDX, AGG);
  convert_bf16_kernel<<<128, 256, 0, stream>>>(W4, W4bf, 256 * 128);
  transpose_bf16_kernel<<<dim3(16, 2, 16), 256, 0, stream>>>(AGG, 128L * 1024, 128, AGGT);
  conv_mfma_kernel<<<dim3(8, 2, 16), 256, 0, stream>>>(W4bf, AGGT, 128, Xcat, XS, 256);
  bn_stats_kernel<<<256, 256, 0, stream>>>(Xcat, XS, 256, MEAN, RSTD);
  bn_apply_kernel<<<dim3(4, 256, 16), 256, 0, stream>>>(Xcat, XS, 256, MEAN, RSTD, g4, b4);

  // ---- layer 5 (bf16 MFMA; H written only after knn scratch is dead) ----
  convert_bf16_kernel<<<2048, 256, 0, stream>>>(W5, W5bf, 1024 * 512);
  transpose_bf16_kernel<<<dim3(16, 8, 16), 256, 0, stream>>>(Xcat, XS, 512, XbfT);
  conv_mfma_kernel<<<dim3(8, 8, 16), 256, 0, stream>>>(W5bf, XbfT, 512, H, HS, 0);
  bn_stats_kernel<<<1024, 256, 0, stream>>>(H, HS, 0, MEAN, RSTD);
  bn_pool_kernel<<<dim3(1024, 16), 256, 0, stream>>>(H, MEAN, RSTD, g5, b5, Z);

  // ---- MLP head ----
  fc_wave_kernel<<<128, 256, 0, stream>>>(Z, l1W, nullptr, Z1, 2048, 512);
  bn_small_kernel<<<2, 256, 0, stream>>>(Z1, g6, b6, 512);
  fc_wave_kernel<<<64, 256, 0, stream>>>(Z1, l2W, l2b, Z2, 512, 256);
  bn_small_kernel<<<1, 256, 0, stream>>>(Z2, g7, b7, 256);
  fc_wave_kernel<<<10, 256, 0, stream>>>(Z2, l3W, l3b, (float*)d_out, 256, 40);
}